// Round 2
// baseline (2799.142 us; speedup 1.0000x reference)
//
#include <hip/hip_runtime.h>
#include <math.h>

#define B_ 512
#define S_ 150
#define FIN_ 75
#define E_ 128
#define D_ 256
#define FF_ 192
#define ROWS_ (B_*S_)

typedef _Float16 h4_t __attribute__((ext_vector_type(4)));

__device__ __forceinline__ float wsum(float v){
#pragma unroll
  for (int o=32;o;o>>=1) v += __shfl_xor(v,o,64);
  return v;
}
__device__ __forceinline__ float wmax(float v){
#pragma unroll
  for (int o=32;o;o>>=1) v = fmaxf(v,__shfl_xor(v,o,64));
  return v;
}
__device__ __forceinline__ float sigmoidf_(float x){ return 1.f/(1.f+expf(-x)); }
__device__ __forceinline__ float siluf_(float x){ return x/(1.f+expf(-x)); }
__device__ __forceinline__ float logsigf_(float x){ return fminf(x,0.f)-log1pf(expf(-fabsf(x))); }
__device__ __forceinline__ float dot4(float4 a, float4 b){ return a.x*b.x+a.y*b.y+a.z*b.z+a.w*b.w; }
__device__ __forceinline__ float hdot(float4 w, h4_t x){
  return w.x*(float)x[0] + w.y*(float)x[1] + w.z*(float)x[2] + w.w*(float)x[3];
}
__device__ __forceinline__ float4 h4f(h4_t v){
  return make_float4((float)v[0],(float)v[1],(float)v[2],(float)v[3]);
}
__device__ __forceinline__ float bsum128(float v, float* red2){
  v = wsum(v);
  __syncthreads();
  if ((threadIdx.x&63)==0) red2[threadIdx.x>>6]=v;
  __syncthreads();
  return red2[0]+red2[1];
}

// ---------------- K1: h = x @ w_in + b_in (f32 -> f32) ----------------
__global__ __launch_bounds__(256) void k_inproj(const float* __restrict__ x, const float* __restrict__ w,
    const float* __restrict__ b, float* __restrict__ h){
  __shared__ float xl[16*FIN_];
  int row0 = blockIdx.x*16;
  int tid = threadIdx.x;
  for (int i=tid;i<16*FIN_;i+=256) xl[i] = x[(size_t)row0*FIN_ + i];
  __syncthreads();
  int o = tid & 127, rh = tid >> 7;
  float acc[8];
#pragma unroll
  for (int r=0;r<8;r++) acc[r]=0.f;
  for (int i=0;i<FIN_;i++){
    float wv = w[i*E_ + o];
#pragma unroll
    for (int r=0;r<8;r++) acc[r] += xl[(rh + 2*r)*FIN_ + i]*wv;
  }
  float bv = b[o];
#pragma unroll
  for (int r=0;r<8;r++) h[(size_t)(row0 + rh + 2*r)*E_ + o] = acc[r] + bv;
}

// ---------------- K2: xn=LN(h); [x_m|z] = xn @ m_up_w + b (out fp16) ----------------
__global__ __launch_bounds__(256) void k_ln_up(const float* __restrict__ h, const float* __restrict__ lnw,
     const float* __restrict__ w, const float* __restrict__ bb,
     _Float16* __restrict__ xm, _Float16* __restrict__ z){
  __shared__ float xl[8*E_];
  int row0 = blockIdx.x*8; int tid = threadIdx.x;
  for (int i=tid;i<8*E_;i+=256) xl[i] = h[(size_t)row0*E_ + i];
  __syncthreads();
  int wave = tid>>6, lane = tid&63;
  for (int rr = wave; rr < 8; rr += 4){
    float x0 = xl[rr*E_+lane], x1 = xl[rr*E_+lane+64];
    float mu = wsum(x0+x1) * (1.f/E_);
    float d0=x0-mu, d1=x1-mu;
    float var = wsum(d0*d0+d1*d1)*(1.f/E_);
    float rs = rsqrtf(var+1e-5f);
    xl[rr*E_+lane] = d0*rs*lnw[lane];
    xl[rr*E_+lane+64] = d1*rs*lnw[lane+64];
  }
  __syncthreads();
  float a0[8], a1[8];
#pragma unroll
  for (int r=0;r<8;r++){a0[r]=0.f;a1[r]=0.f;}
  int o = tid;
  for (int i=0;i<E_;i+=4){
    float w0v[4], w1v[4];
#pragma unroll
    for (int ii=0;ii<4;ii++){ w0v[ii] = w[(i+ii)*512+o]; w1v[ii]=w[(i+ii)*512+o+256]; }
#pragma unroll
    for (int r=0;r<8;r++){
      float4 xr = *(const float4*)&xl[r*E_+i];
      a0[r] += xr.x*w0v[0] + xr.y*w0v[1] + xr.z*w0v[2] + xr.w*w0v[3];
      a1[r] += xr.x*w1v[0] + xr.y*w1v[1] + xr.z*w1v[2] + xr.w*w1v[3];
    }
  }
  float b0 = bb[o], b1 = bb[o+256];
#pragma unroll
  for (int r=0;r<8;r++){
    xm[(size_t)(row0+r)*D_ + o] = (_Float16)(a0[r]+b0);
    z [(size_t)(row0+r)*D_ + o] = (_Float16)(a1[r]+b1);
  }
}

// ---------------- K3: conv+silu -> xc (fp16); ig/fg (f32) ----------------
__global__ __launch_bounds__(256) void k_conv_qkv(const _Float16* __restrict__ xm,
    const float* __restrict__ cw, const float* __restrict__ cb,
    const float* __restrict__ qw, const float* __restrict__ qb2,
    const float* __restrict__ kw, const float* __restrict__ kb2,
    const float* __restrict__ vw, const float* __restrict__ vb2,
    const float* __restrict__ igw, const float* __restrict__ igb,
    const float* __restrict__ fgw, const float* __restrict__ fgb,
    _Float16* __restrict__ xc, float* __restrict__ ig, float* __restrict__ fg){
  __shared__ float xml[4][D_];
  __shared__ float xcl[D_];
  __shared__ float part[4][8];
  int row = blockIdx.x; int b = row/S_; int s = row - b*S_;
  int c = threadIdx.x;
#pragma unroll
  for (int j=0;j<4;j++){
    int sj = s-3+j;
    xml[j][c] = (sj>=0)? (float)xm[(size_t)(row-3+j)*D_ + c] : 0.f;
  }
  __syncthreads();
  float4 wc = *(const float4*)&cw[c*4];
  float cv = cb[c] + wc.x*xml[0][c] + wc.y*xml[1][c] + wc.z*xml[2][c] + wc.w*xml[3][c];
  cv = siluf_(cv);
  xcl[c] = cv;
  xc[(size_t)row*D_ + c] = (_Float16)cv;
  int nb = c>>2, rr = c&3;
  float4 vw4 = *(const float4*)&vw[nb*16 + rr*4];
  float4 xv4 = *(const float4*)&xml[3][nb*4];
  float vv = vb2[c] + dot4(vw4, xv4);
  __syncthreads();
  float4 qw4 = *(const float4*)&qw[nb*16 + rr*4];
  float4 kw4 = *(const float4*)&kw[nb*16 + rr*4];
  float4 xc4 = *(const float4*)&xcl[nb*4];
  float qv = qb2[c] + dot4(qw4, xc4);
  float kv = kb2[c] + dot4(kw4, xc4);
  float4 wiq = *(const float4*)&igw[c*4];
  float4 wik = *(const float4*)&igw[(256+c)*4];
  float4 wiv = *(const float4*)&igw[(512+c)*4];
  float4 wfq = *(const float4*)&fgw[c*4];
  float4 wfk = *(const float4*)&fgw[(256+c)*4];
  float4 wfv = *(const float4*)&fgw[(512+c)*4];
  float p[8];
  p[0] = qv*wiq.x + kv*wik.x + vv*wiv.x;
  p[1] = qv*wiq.y + kv*wik.y + vv*wiv.y;
  p[2] = qv*wiq.z + kv*wik.z + vv*wiv.z;
  p[3] = qv*wiq.w + kv*wik.w + vv*wiv.w;
  p[4] = qv*wfq.x + kv*wfk.x + vv*wfv.x;
  p[5] = qv*wfq.y + kv*wfk.y + vv*wfv.y;
  p[6] = qv*wfq.z + kv*wfk.z + vv*wfv.z;
  p[7] = qv*wfq.w + kv*wfk.w + vv*wfv.w;
#pragma unroll
  for (int j=0;j<8;j++) p[j] = wsum(p[j]);
  int wave = c>>6, lane = c&63;
  if (lane==0){
#pragma unroll
    for (int j=0;j<8;j++) part[wave][j]=p[j];
  }
  __syncthreads();
  if (c < 8){
    float t4 = part[0][c]+part[1][c]+part[2][c]+part[3][c];
    int g = c&3;
    if (c<4) ig[(size_t)(b*4+g)*S_ + s] = t4 + igb[g];
    else     fg[(size_t)(b*4+g)*S_ + s] = t4 + fgb[g];
  }
}

// ---------------- K4: mLSTM + fused per-head LN + skip + gate; hs in-place into xc ----------------
__global__ __launch_bounds__(256) void k_mlstm(_Float16* xcio,
    const _Float16* __restrict__ xm, const _Float16* __restrict__ z,
    const float* __restrict__ qw, const float* __restrict__ qb2,
    const float* __restrict__ kw, const float* __restrict__ kb2,
    const float* __restrict__ vw, const float* __restrict__ vb2,
    const float* __restrict__ ig, const float* __restrict__ fg,
    const float* __restrict__ nw, const float* __restrict__ skip){
  __shared__ _Float16 kl[S_*68];
  __shared__ _Float16 vl[S_*68];
  __shared__ float ql[4][4][64];
  __shared__ float coef[4][4][152];
  __shared__ float lfc[S_+1];
  __shared__ float igl[S_];
  int bh = blockIdx.x; int b = bh>>2; int hh = bh&3;
  int tid = threadIdx.x; int wave = tid>>6, lane = tid&63;
  _Float16* xcg = xcio + (size_t)b*S_*D_ + hh*64;
  const _Float16* xmg = xm + (size_t)b*S_*D_ + hh*64;
  const _Float16* zg  = z  + (size_t)b*S_*D_ + hh*64;
  for (int i=tid;i<S_*64;i+=256){
    int t=i>>6, d=i&63; int nb=d>>2, dd=d&3;
    h4_t xk = *(const h4_t*)&xcg[(size_t)t*D_ + (nb<<2)];
    h4_t xv = *(const h4_t*)&xmg[(size_t)t*D_ + (nb<<2)];
    float4 wk = *(const float4*)&kw[((hh*16+nb)<<4) + (dd<<2)];
    float4 wv = *(const float4*)&vw[((hh*16+nb)<<4) + (dd<<2)];
    kl[t*68+d] = (_Float16)(kb2[hh*64+d] + hdot(wk,xk));
    vl[t*68+d] = (_Float16)(vb2[hh*64+d] + hdot(wv,xv));
  }
  if (tid < S_) igl[tid] = ig[(size_t)bh*S_ + tid];
  if (tid == 0){
    float run=0.f; lfc[0]=0.f;
    for (int t=0;t<S_;t++){ run += logsigf_(fg[(size_t)bh*S_+t]); lfc[t+1]=run; }
  }
  float nwv = nw[hh*64+lane], skv = skip[hh*64+lane];
  int qnb = lane>>2, qdd = lane&3;
  float4 wq = *(const float4*)&qw[((hh*16+qnb)<<4) + (qdd<<2)];
  float qbv = qb2[hh*64+lane];
  __syncthreads();
  for (int g = wave; g < 38; g += 4){
    int s0 = g*4;
    int smax = s0+3 < S_-1 ? s0+3 : S_-1;
    // stage q rows for the group
#pragma unroll
    for (int r=0;r<4;r++){
      int s = s0+r; if (s > S_-1) s = S_-1;
      h4_t x4 = *(const h4_t*)&xcg[(size_t)s*D_ + (qnb<<2)];
      ql[wave][r][lane] = qbv + hdot(wq,x4);
    }
    __builtin_amdgcn_wave_barrier();
    int t0 = lane, t1 = lane+64, t2 = lane+128;
    bool v0 = t0<=smax, v1 = t1<=smax, v2 = t2<=smax;
    float qk0[4], qk1[4], qk2[4];
#pragma unroll
    for (int r=0;r<4;r++){ qk0[r]=0.f; qk1[r]=0.f; qk2[r]=0.f; }
    h4_t kz = {(_Float16)0,(_Float16)0,(_Float16)0,(_Float16)0};
    for (int d=0; d<64; d+=4){
      h4_t k0 = v0 ? *(const h4_t*)&kl[t0*68+d] : kz;
      h4_t k1 = v1 ? *(const h4_t*)&kl[t1*68+d] : kz;
      h4_t k2 = v2 ? *(const h4_t*)&kl[t2*68+d] : kz;
      float4 kf0=h4f(k0), kf1=h4f(k1), kf2=h4f(k2);
#pragma unroll
      for (int r=0;r<4;r++){
        float4 q4 = *(const float4*)&ql[wave][r][d];
        qk0[r] += dot4(q4,kf0);
        qk1[r] += dot4(q4,kf1);
        qk2[r] += dot4(q4,kf2);
      }
    }
    float nrm4[4];
#pragma unroll
    for (int r=0;r<4;r++){
      int s = s0+r; int sc = (s < S_)? s : S_-1;
      float lf = lfc[sc+1];
      float l0 = (t0<=sc)? lf - lfc[t0+1] + igl[t0] : -3.4e38f;
      float l1 = (t1<=sc)? lf - lfc[t1+1] + igl[t1] : -3.4e38f;
      float l2 = (t2<=sc)? lf - lfc[t2+1] + igl[t2] : -3.4e38f;
      float mx = wmax(fmaxf(l0,fmaxf(l1,l2)));
      float c0 = qk0[r]*0.125f*expf(l0-mx);
      float c1 = qk1[r]*0.125f*expf(l1-mx);
      float c2 = qk2[r]*0.125f*expf(l2-mx);
      float rs_ = wsum(c0+c1+c2);
      nrm4[r] = fmaxf(fabsf(rs_), expf(-mx)) + 1e-6f;
      if (v0) coef[wave][r][t0]=c0;
      if (v1) coef[wave][r][t1]=c1;
      if (v2) coef[wave][r][t2]=c2;
    }
    __builtin_amdgcn_wave_barrier();
    float av[4]={0.f,0.f,0.f,0.f};
    for (int t=0;t<=smax;t++){
      float vv = (float)vl[t*68+lane];
      av[0] += coef[wave][0][t]*vv;
      av[1] += coef[wave][1][t]*vv;
      av[2] += coef[wave][2][t]*vv;
      av[3] += coef[wave][3][t]*vv;
    }
    __builtin_amdgcn_wave_barrier();
    // fused epilogue: per-head LN + learnable skip + silu(z) gate, write hs in-place
#pragma unroll
    for (int r=0;r<4;r++){
      int s = s0+r;
      if (s < S_){
        float hval = av[r]/nrm4[r];
        float mu = wsum(hval)*(1.f/64.f);
        float dd = hval-mu;
        float var = wsum(dd*dd)*(1.f/64.f);
        float hn = dd*rsqrtf(var+1e-5f)*nwv;
        float xcv = (float)xcg[(size_t)s*D_+lane];
        float zv  = (float)zg [(size_t)s*D_+lane];
        xcg[(size_t)s*D_+lane] = (_Float16)((hn + skv*xcv)*siluf_(zv));
      }
    }
  }
}

// ---------------- K5: h += hs @ m_down_w + b ----------------
__global__ __launch_bounds__(256) void k_down(const _Float16* __restrict__ hs, const float* __restrict__ w,
    const float* __restrict__ bb, float* __restrict__ h){
  __shared__ float hl[8*D_];
  int row0 = blockIdx.x*8; int tid = threadIdx.x;
  for (int i=tid;i<8*D_;i+=256) hl[i] = (float)hs[(size_t)row0*D_ + i];
  __syncthreads();
  int o = tid&127, rh = tid>>7;
  float acc[4]={0.f,0.f,0.f,0.f};
  for (int i=0;i<D_;i+=4){
    float wv[4];
#pragma unroll
    for (int ii=0;ii<4;ii++) wv[ii] = w[(i+ii)*E_ + o];
#pragma unroll
    for (int r=0;r<4;r++){
      float4 xv = *(const float4*)&hl[(rh+2*r)*D_ + i];
      acc[r] += xv.x*wv[0]+xv.y*wv[1]+xv.z*wv[2]+xv.w*wv[3];
    }
  }
  float bv = bb[o];
#pragma unroll
  for (int r=0;r<4;r++){
    size_t idx = (size_t)(row0+rh+2*r)*E_ + o;
    h[idx] += acc[r] + bv;
  }
}

// ---------------- K6: fused LN(h) + causal conv + silu -> xcs (fp16) ----------------
__global__ __launch_bounds__(256) void k_lnconv(const float* __restrict__ h, const float* __restrict__ lnw,
    const float* __restrict__ cw, const float* __restrict__ cb, _Float16* __restrict__ xcs){
  __shared__ float xn[19][E_];
  int b = blockIdx.x/10, chunk = blockIdx.x - b*10;
  int s0 = chunk*16;
  int tid=threadIdx.x, wave=tid>>6, lane=tid&63;
  for (int ii=wave; ii<19; ii+=4){
    int sg = s0-3+ii;
    if (sg>=0 && sg<S_){
      size_t off = (size_t)(b*S_+sg)*E_;
      float x0=h[off+lane], x1=h[off+lane+64];
      float mu=wsum(x0+x1)*(1.f/E_);
      float d0=x0-mu,d1=x1-mu;
      float var=wsum(d0*d0+d1*d1)*(1.f/E_);
      float rs=rsqrtf(var+1e-5f);
      xn[ii][lane]=d0*rs*lnw[lane];
      xn[ii][lane+64]=d1*rs*lnw[lane+64];
    } else { xn[ii][lane]=0.f; xn[ii][lane+64]=0.f; }
  }
  __syncthreads();
  int ch=tid&127, rh=tid>>7;
  float4 w4 = *(const float4*)&cw[ch*4];
  float bv = cb[ch];
  for (int r=rh; r<16; r+=2){
    int s=s0+r;
    if (s<S_){
      float acc = bv + w4.x*xn[r][ch] + w4.y*xn[r+1][ch] + w4.z*xn[r+2][ch] + w4.w*xn[r+3][ch];
      xcs[(size_t)(b*S_+s)*E_+ch] = (_Float16)siluf_(acc);
    }
  }
}

// ---------------- K7: sLSTM gates (fused LN(h) for gz/go), fp16 out ----------------
__global__ __launch_bounds__(128) void k_gates(const _Float16* __restrict__ xcs, const float* __restrict__ h,
    const float* __restrict__ lnw, const float* __restrict__ gw,
    _Float16* __restrict__ gi, _Float16* __restrict__ gf,
    _Float16* __restrict__ gz, _Float16* __restrict__ go){
  __shared__ float xcl[E_], xnl[E_], red2[2];
  int row = blockIdx.x; int b = row/S_; int s = row - b*S_;
  int t = threadIdx.x;
  float hv = h[(size_t)row*E_+t];
  float mu = bsum128(hv, red2)*(1.f/E_);
  float dd = hv-mu;
  float var = bsum128(dd*dd, red2)*(1.f/E_);
  xnl[t] = dd*rsqrtf(var+1e-5f)*lnw[t];
  xcl[t] = (float)xcs[(size_t)row*E_+t];
  __syncthreads();
  int hh = t>>5, o = t&31;
  float a0=0.f,a1=0.f,a2=0.f,a3=0.f;
  const float* w0 = gw + (((0*4+hh)*32+o)<<5);
  const float* w1 = gw + (((1*4+hh)*32+o)<<5);
  const float* w2 = gw + (((2*4+hh)*32+o)<<5);
  const float* w3 = gw + (((3*4+hh)*32+o)<<5);
  const float* xch = &xcl[hh*32]; const float* xnh = &xnl[hh*32];
  for (int d=0; d<32; d+=4){
    float4 xc4 = *(const float4*)&xch[d];
    float4 xn4 = *(const float4*)&xnh[d];
    a0 += dot4(*(const float4*)&w0[d], xc4);
    a1 += dot4(*(const float4*)&w1[d], xc4);
    a2 += dot4(*(const float4*)&w2[d], xn4);
    a3 += dot4(*(const float4*)&w3[d], xn4);
  }
  size_t oidx = ((size_t)s*B_ + b)*E_ + t;
  gi[oidx]=(_Float16)a0; gf[oidx]=(_Float16)a1; gz[oidx]=(_Float16)a2; go[oidx]=(_Float16)a3;
}

// ---------------- K8: sLSTM recurrent scan (final y only) ----------------
__global__ __launch_bounds__(128) void k_scan(const _Float16* __restrict__ gi, const _Float16* __restrict__ gf,
    const _Float16* __restrict__ gz, const _Float16* __restrict__ go,
    const float* __restrict__ sr, const float* __restrict__ sb, float* __restrict__ yl){
  __shared__ _Float16 srt[16384];   // [h][d][k][g] fp16, 32KB
  int b = blockIdx.x; int t = threadIdx.x;
  for (int i=t;i<16384;i+=128){
    int g = i>>12; int rem = i&4095; int hh = rem>>10; int d = (rem>>5)&31; int kk = i&31;
    srt[(((hh*32+d)*32 + kk)<<2) + g] = (_Float16)sr[i];
  }
  __syncthreads();
  int hh = t>>5; int lane = t&63; int kk = t&31;
  float sb0 = sb[t], sb1 = sb[128+t], sb2 = sb[256+t], sb3 = sb[384+t];
  float y=0.f,cst=0.f,nst=0.f,mst=-1e30f;
  size_t base0 = (size_t)b*E_ + t;
  float gc0 = (float)gi[base0], gc1 = (float)gf[base0], gc2 = (float)gz[base0], gc3 = (float)go[base0];
  const _Float16* srh = srt + hh*4096;
  for (int s=0;s<S_;s++){
    int sn = (s+1 < S_)? s+1 : s;
    size_t nidx = ((size_t)sn*B_ + b)*E_ + t;
    float n0 = (float)gi[nidx], n1 = (float)gf[nidx], n2 = (float)gz[nidx], n3 = (float)go[nidx];
    float ry0=0.f,ry1=0.f,ry2=0.f,ry3=0.f;
#pragma unroll 8
    for (int d=0; d<32; d++){
      float yv = __shfl(y, (lane & 32) + d, 64);
      float4 w = h4f(*(const h4_t*)&srh[(d*32 + kk)<<2]);
      ry0 += yv*w.x; ry1 += yv*w.y; ry2 += yv*w.z; ry3 += yv*w.w;
    }
    float ir = gc0 + ry0 + sb0;
    float fr = gc1 + ry1 + sb1;
    float zr = gc2 + ry2 + sb2;
    float orr= gc3 + ry3 + sb3;
    float lfm = mst + logsigf_(fr);
    float mn = fmaxf(ir, lfm);
    float igt = expf(ir - mn);
    float fgt = expf(lfm - mn);
    cst = fgt*cst + igt*tanhf(zr);
    nst = fgt*nst + igt;
    mst = mn;
    y = sigmoidf_(orr)*cst/nst;
    gc0=n0; gc1=n1; gc2=n2; gc3=n3;
  }
  yl[(size_t)b*E_ + t] = y;
}

// ---------------- K9: last-position head (mhln + FFN + post-LN + fc) ----------------
__global__ __launch_bounds__(128) void k_head(const float* __restrict__ h, const float* __restrict__ yl,
   const float* __restrict__ snw, const float* __restrict__ lnffw,
   const float* __restrict__ upw, const float* __restrict__ upb,
   const float* __restrict__ dww, const float* __restrict__ dwb,
   const float* __restrict__ postw, const float* __restrict__ fcw, const float* __restrict__ fcb,
   float* __restrict__ out){
  __shared__ float ylsh[E_], xnf[E_], up[2*FF_], gg[FF_], red2[2];
  int b = blockIdx.x; int t = threadIdx.x;
  float yv = yl[(size_t)b*E_+t];
  ylsh[t] = yv;
  __syncthreads();
  int base = (t>>5)<<5;
  float mu=0.f;
  for (int d=0;d<32;d++) mu += ylsh[base+d];
  mu *= (1.f/32.f);
  float var=0.f;
  for (int d=0;d<32;d++){ float dd = ylsh[base+d]-mu; var += dd*dd; }
  var *= (1.f/32.f);
  float hn = (yv-mu)*rsqrtf(var+1e-5f)*snw[t];
  float h1 = h[((size_t)b*S_ + (S_-1))*E_ + t] + hn;
  float mu1 = bsum128(h1, red2)*(1.f/E_);
  float d1 = h1-mu1;
  float var1 = bsum128(d1*d1, red2)*(1.f/E_);
  xnf[t] = d1*rsqrtf(var1+1e-5f)*lnffw[t];
  __syncthreads();
  float u0=upb[t], u1=upb[t+128], u2=upb[t+256];
  for (int i=0;i<E_;i++){
    float x = xnf[i];
    u0 += x*upw[i*384+t];
    u1 += x*upw[i*384+t+128];
    u2 += x*upw[i*384+t+256];
  }
  up[t]=u0; up[t+128]=u1; up[t+256]=u2;
  __syncthreads();
  for (int j=t;j<FF_;j+=128){
    float gp = up[j];
    gg[j] = 0.5f*gp*(1.f+erff(gp*0.70710678118f))*up[FF_+j];
  }
  __syncthreads();
  float acc = dwb[t];
  for (int j=0;j<FF_;j++) acc += gg[j]*dww[j*E_+t];
  float h2 = h1 + acc;
  float mu2 = bsum128(h2, red2)*(1.f/E_);
  float d2 = h2-mu2;
  float var2 = bsum128(d2*d2, red2)*(1.f/E_);
  float hp = d2*rsqrtf(var2+1e-5f)*postw[t];
  float pr = bsum128(hp*fcw[t], red2);
  if (t==0) out[b] = pr + fcb[0];
}

extern "C" void kernel_launch(void* const* d_in, const int* in_sizes, int n_in,
                              void* d_out, int out_size, void* d_ws, size_t ws_size,
                              hipStream_t stream){
  const float* x        = (const float*)d_in[0];
  const float* w_in     = (const float*)d_in[1];
  const float* b_in     = (const float*)d_in[2];
  const float* ln0_w    = (const float*)d_in[3];
  const float* m_up_w   = (const float*)d_in[4];
  const float* m_up_b   = (const float*)d_in[5];
  const float* m_conv_w = (const float*)d_in[6];
  const float* m_conv_b = (const float*)d_in[7];
  const float* m_q_w    = (const float*)d_in[8];
  const float* m_q_b    = (const float*)d_in[9];
  const float* m_k_w    = (const float*)d_in[10];
  const float* m_k_b    = (const float*)d_in[11];
  const float* m_v_w    = (const float*)d_in[12];
  const float* m_v_b    = (const float*)d_in[13];
  const float* m_ig_w   = (const float*)d_in[14];
  const float* m_ig_b   = (const float*)d_in[15];
  const float* m_fg_w   = (const float*)d_in[16];
  const float* m_fg_b   = (const float*)d_in[17];
  const float* m_norm_w = (const float*)d_in[18];
  const float* m_skip   = (const float*)d_in[19];
  const float* m_down_w = (const float*)d_in[20];
  const float* m_down_b = (const float*)d_in[21];
  const float* ln1_w    = (const float*)d_in[22];
  const float* s_conv_w = (const float*)d_in[23];
  const float* s_conv_b = (const float*)d_in[24];
  const float* s_gate_w = (const float*)d_in[25];
  const float* s_r      = (const float*)d_in[26];
  const float* s_b      = (const float*)d_in[27];
  const float* s_norm_w = (const float*)d_in[28];
  const float* ln_ff_w  = (const float*)d_in[29];
  const float* ff_up_w  = (const float*)d_in[30];
  const float* ff_up_b  = (const float*)d_in[31];
  const float* ff_down_w= (const float*)d_in[32];
  const float* ff_down_b= (const float*)d_in[33];
  const float* post_w   = (const float*)d_in[34];
  const float* fc_w     = (const float*)d_in[35];
  const float* fc_b     = (const float*)d_in[36];
  float* out = (float*)d_out;
  float* wsf = (float*)d_ws;

  // workspace layout (units = f32 slots): total 40,001,536 f32 = 152.6 MiB
  float*     h  = wsf;                              // (B,S,E) f32
  _Float16*  A  = (_Float16*)(wsf + 9830400);       // x_m -> xcs | gz
  _Float16*  Bz = (_Float16*)(wsf + 19660800);      // z   -> gi | gf
  _Float16*  C  = (_Float16*)(wsf + 29491200);      // xc/hs -> go
  float*     ig = wsf + 39321600;
  float*     fg = wsf + 39628800;
  float*     yl = wsf + 39936000;

  k_inproj<<<ROWS_/16, 256, 0, stream>>>(x, w_in, b_in, h);
  k_ln_up<<<ROWS_/8, 256, 0, stream>>>(h, ln0_w, m_up_w, m_up_b, A, Bz);
  k_conv_qkv<<<ROWS_, 256, 0, stream>>>(A, m_conv_w, m_conv_b, m_q_w, m_q_b, m_k_w, m_k_b,
       m_v_w, m_v_b, m_ig_w, m_ig_b, m_fg_w, m_fg_b, C, ig, fg);
  k_mlstm<<<B_*4, 256, 0, stream>>>(C, A, Bz, m_q_w, m_q_b, m_k_w, m_k_b, m_v_w, m_v_b,
       ig, fg, m_norm_w, m_skip);
  k_down<<<ROWS_/8, 256, 0, stream>>>(C, m_down_w, m_down_b, h);
  _Float16* xcs = A;
  _Float16* gz  = A + 9830400;
  _Float16* gi  = Bz;
  _Float16* gf  = Bz + 9830400;
  _Float16* go  = C;
  k_lnconv<<<B_*10, 256, 0, stream>>>(h, ln1_w, s_conv_w, s_conv_b, xcs);
  k_gates<<<ROWS_, 128, 0, stream>>>(xcs, h, ln1_w, s_gate_w, gi, gf, gz, go);
  k_scan<<<B_, 128, 0, stream>>>(gi, gf, gz, go, s_r, s_b, yl);
  k_head<<<B_, 128, 0, stream>>>(h, yl, s_norm_w, ln_ff_w, ff_up_w, ff_up_b,
       ff_down_w, ff_down_b, post_w, fc_w, fc_b, out);
}

// Round 3
// 1724.342 us; speedup vs baseline: 1.6233x; 1.6233x over previous
//
#include <hip/hip_runtime.h>
#include <math.h>

#define B_ 512
#define S_ 150
#define FIN_ 75
#define E_ 128
#define D_ 256
#define FF_ 192
#define ROWS_ (B_*S_)

typedef _Float16 h4_t __attribute__((ext_vector_type(4)));
typedef _Float16 h8_t __attribute__((ext_vector_type(8)));
typedef float f4_t __attribute__((ext_vector_type(4)));

__device__ __forceinline__ float wsum(float v){
#pragma unroll
  for (int o=32;o;o>>=1) v += __shfl_xor(v,o,64);
  return v;
}
__device__ __forceinline__ float sigmoidf_(float x){ return 1.f/(1.f+expf(-x)); }
__device__ __forceinline__ float siluf_(float x){ return x/(1.f+expf(-x)); }
__device__ __forceinline__ float logsigf_(float x){ return fminf(x,0.f)-log1pf(expf(-fabsf(x))); }
__device__ __forceinline__ float dot4(float4 a, float4 b){ return a.x*b.x+a.y*b.y+a.z*b.z+a.w*b.w; }
__device__ __forceinline__ float hdot(float4 w, h4_t x){
  return w.x*(float)x[0] + w.y*(float)x[1] + w.z*(float)x[2] + w.w*(float)x[3];
}
__device__ __forceinline__ float4 h4f(h4_t v){
  return make_float4((float)v[0],(float)v[1],(float)v[2],(float)v[3]);
}
__device__ __forceinline__ float bsum128(float v, float* red2){
  v = wsum(v);
  __syncthreads();
  if ((threadIdx.x&63)==0) red2[threadIdx.x>>6]=v;
  __syncthreads();
  return red2[0]+red2[1];
}

// ---------------- K1: h = x @ w_in + b_in (f32 -> f32) ----------------
__global__ __launch_bounds__(256) void k_inproj(const float* __restrict__ x, const float* __restrict__ w,
    const float* __restrict__ b, float* __restrict__ h){
  __shared__ float xl[16*FIN_];
  int row0 = blockIdx.x*16;
  int tid = threadIdx.x;
  for (int i=tid;i<16*FIN_;i+=256) xl[i] = x[(size_t)row0*FIN_ + i];
  __syncthreads();
  int o = tid & 127, rh = tid >> 7;
  float acc[8];
#pragma unroll
  for (int r=0;r<8;r++) acc[r]=0.f;
  for (int i=0;i<FIN_;i++){
    float wv = w[i*E_ + o];
#pragma unroll
    for (int r=0;r<8;r++) acc[r] += xl[(rh + 2*r)*FIN_ + i]*wv;
  }
  float bv = b[o];
#pragma unroll
  for (int r=0;r<8;r++) h[(size_t)(row0 + rh + 2*r)*E_ + o] = acc[r] + bv;
}

// ---------------- K2: xn=LN(h); [x_m|z] = xn @ m_up_w + b (out fp16) ----------------
__global__ __launch_bounds__(256) void k_ln_up(const float* __restrict__ h, const float* __restrict__ lnw,
     const float* __restrict__ w, const float* __restrict__ bb,
     _Float16* __restrict__ xm, _Float16* __restrict__ z){
  __shared__ float xl[8*E_];
  int row0 = blockIdx.x*8; int tid = threadIdx.x;
  for (int i=tid;i<8*E_;i+=256) xl[i] = h[(size_t)row0*E_ + i];
  __syncthreads();
  int wave = tid>>6, lane = tid&63;
  for (int rr = wave; rr < 8; rr += 4){
    float x0 = xl[rr*E_+lane], x1 = xl[rr*E_+lane+64];
    float mu = wsum(x0+x1) * (1.f/E_);
    float d0=x0-mu, d1=x1-mu;
    float var = wsum(d0*d0+d1*d1)*(1.f/E_);
    float rs = rsqrtf(var+1e-5f);
    xl[rr*E_+lane] = d0*rs*lnw[lane];
    xl[rr*E_+lane+64] = d1*rs*lnw[lane+64];
  }
  __syncthreads();
  float a0[8], a1[8];
#pragma unroll
  for (int r=0;r<8;r++){a0[r]=0.f;a1[r]=0.f;}
  int o = tid;
  for (int i=0;i<E_;i+=4){
    float w0v[4], w1v[4];
#pragma unroll
    for (int ii=0;ii<4;ii++){ w0v[ii] = w[(i+ii)*512+o]; w1v[ii]=w[(i+ii)*512+o+256]; }
#pragma unroll
    for (int r=0;r<8;r++){
      float4 xr = *(const float4*)&xl[r*E_+i];
      a0[r] += xr.x*w0v[0] + xr.y*w0v[1] + xr.z*w0v[2] + xr.w*w0v[3];
      a1[r] += xr.x*w1v[0] + xr.y*w1v[1] + xr.z*w1v[2] + xr.w*w1v[3];
    }
  }
  float b0 = bb[o], b1 = bb[o+256];
#pragma unroll
  for (int r=0;r<8;r++){
    xm[(size_t)(row0+r)*D_ + o] = (_Float16)(a0[r]+b0);
    z [(size_t)(row0+r)*D_ + o] = (_Float16)(a1[r]+b1);
  }
}

// ---------------- K3: conv+silu -> xc (fp16); ig/fg (f32) ----------------
__global__ __launch_bounds__(256) void k_conv_qkv(const _Float16* __restrict__ xm,
    const float* __restrict__ cw, const float* __restrict__ cb,
    const float* __restrict__ qw, const float* __restrict__ qb2,
    const float* __restrict__ kw, const float* __restrict__ kb2,
    const float* __restrict__ vw, const float* __restrict__ vb2,
    const float* __restrict__ igw, const float* __restrict__ igb,
    const float* __restrict__ fgw, const float* __restrict__ fgb,
    _Float16* __restrict__ xc, float* __restrict__ ig, float* __restrict__ fg){
  __shared__ float xml[4][D_];
  __shared__ float xcl[D_];
  __shared__ float part[4][8];
  int row = blockIdx.x; int b = row/S_; int s = row - b*S_;
  int c = threadIdx.x;
#pragma unroll
  for (int j=0;j<4;j++){
    int sj = s-3+j;
    xml[j][c] = (sj>=0)? (float)xm[(size_t)(row-3+j)*D_ + c] : 0.f;
  }
  __syncthreads();
  float4 wc = *(const float4*)&cw[c*4];
  float cv = cb[c] + wc.x*xml[0][c] + wc.y*xml[1][c] + wc.z*xml[2][c] + wc.w*xml[3][c];
  cv = siluf_(cv);
  xcl[c] = cv;
  xc[(size_t)row*D_ + c] = (_Float16)cv;
  int nb = c>>2, rr = c&3;
  float4 vw4 = *(const float4*)&vw[nb*16 + rr*4];
  float4 xv4 = *(const float4*)&xml[3][nb*4];
  float vv = vb2[c] + dot4(vw4, xv4);
  __syncthreads();
  float4 qw4 = *(const float4*)&qw[nb*16 + rr*4];
  float4 kw4 = *(const float4*)&kw[nb*16 + rr*4];
  float4 xc4 = *(const float4*)&xcl[nb*4];
  float qv = qb2[c] + dot4(qw4, xc4);
  float kv = kb2[c] + dot4(kw4, xc4);
  float4 wiq = *(const float4*)&igw[c*4];
  float4 wik = *(const float4*)&igw[(256+c)*4];
  float4 wiv = *(const float4*)&igw[(512+c)*4];
  float4 wfq = *(const float4*)&fgw[c*4];
  float4 wfk = *(const float4*)&fgw[(256+c)*4];
  float4 wfv = *(const float4*)&fgw[(512+c)*4];
  float p[8];
  p[0] = qv*wiq.x + kv*wik.x + vv*wiv.x;
  p[1] = qv*wiq.y + kv*wik.y + vv*wiv.y;
  p[2] = qv*wiq.z + kv*wik.z + vv*wiv.z;
  p[3] = qv*wiq.w + kv*wik.w + vv*wiv.w;
  p[4] = qv*wfq.x + kv*wfk.x + vv*wfv.x;
  p[5] = qv*wfq.y + kv*wfk.y + vv*wfv.y;
  p[6] = qv*wfq.z + kv*wfk.z + vv*wfv.z;
  p[7] = qv*wfq.w + kv*wfk.w + vv*wfv.w;
#pragma unroll
  for (int j=0;j<8;j++) p[j] = wsum(p[j]);
  int wave = c>>6, lane = c&63;
  if (lane==0){
#pragma unroll
    for (int j=0;j<8;j++) part[wave][j]=p[j];
  }
  __syncthreads();
  if (c < 8){
    float t4 = part[0][c]+part[1][c]+part[2][c]+part[3][c];
    int g = c&3;
    if (c<4) ig[(size_t)(b*4+g)*S_ + s] = t4 + igb[g];
    else     fg[(size_t)(b*4+g)*S_ + s] = t4 + fgb[g];
  }
}

// ---------------- K4: mLSTM via MFMA (flash-style) + fused LN/skip/gate epilogue ----------------
// one block per (b,head); 4 waves; wave w handles query tiles {w, w+4, w+8} of 16 rows
__global__ __launch_bounds__(256) void k_mlstm(_Float16* xcio,
    const _Float16* __restrict__ xm, const _Float16* __restrict__ z,
    const float* __restrict__ qw, const float* __restrict__ qb2,
    const float* __restrict__ kw, const float* __restrict__ kb2,
    const float* __restrict__ vw, const float* __restrict__ vb2,
    const float* __restrict__ ig, const float* __restrict__ fg,
    const float* __restrict__ nw, const float* __restrict__ skip){
  __shared__ __align__(16) _Float16 kt[160*72];    // k[t][d], row stride 72 halves (144B, 16B-aligned)
  __shared__ __align__(16) _Float16 vT[64*184];    // v[d][t], row stride 184 halves (368B, 16B-aligned)
  __shared__ __align__(16) _Float16 ct[4][16*40];  // per-wave coef tile 16 x 32 (stride 40)
  __shared__ float lfc[S_+1];
  __shared__ float igl[S_];
  __shared__ float mxl[S_];
  int bh = blockIdx.x; int b = bh>>2; int hh = bh&3;
  int tid = threadIdx.x; int wave = tid>>6, lane = tid&63;
  int quad = lane>>4, lm = lane&15;
  _Float16* xcg = xcio + (size_t)b*S_*D_ + hh*64;
  const _Float16* xmg = xm + (size_t)b*S_*D_ + hh*64;
  const _Float16* zg  = z  + (size_t)b*S_*D_ + hh*64;
  // stage k (from xc) and v (from x_m) via block-diagonal 4x4 transforms; zero pad t>=S
  for (int i=tid;i<160*64;i+=256){
    int t=i>>6, d=i&63;
    float kvv=0.f, vvv=0.f;
    if (t<S_){
      int nb=d>>2, dd=d&3;
      h4_t xk = *(const h4_t*)&xcg[(size_t)t*D_+(nb<<2)];
      h4_t xv = *(const h4_t*)&xmg[(size_t)t*D_+(nb<<2)];
      float4 wk = *(const float4*)&kw[((hh*16+nb)<<4)+(dd<<2)];
      float4 wv = *(const float4*)&vw[((hh*16+nb)<<4)+(dd<<2)];
      kvv = kb2[hh*64+d]+hdot(wk,xk);
      vvv = vb2[hh*64+d]+hdot(wv,xv);
    }
    kt[t*72+d]=(_Float16)kvv;
    vT[d*184+t]=(_Float16)vvv;
  }
  // mxl temporarily holds logsig(fg) (parallel), then the serial scan overwrites with row-max
  if (tid<S_){ igl[tid]=ig[(size_t)bh*S_+tid]; mxl[tid]=logsigf_(fg[(size_t)bh*S_+tid]); }
  __syncthreads();
  if (tid==0){
    float run=0.f, rm=-3.0e38f;
    lfc[0]=0.f;
    for (int t=0;t<S_;t++){
      run += mxl[t];           // lfc[t+1]
      lfc[t+1]=run;
      float gv = igl[t]-run;   // ig[t]-lfc[t+1]
      rm = fmaxf(rm,gv);
      mxl[t] = run + rm;       // analytic row max of logD for row s=t
    }
  }
  __syncthreads();
  float nwv[4], skv[4];
#pragma unroll
  for (int dt=0;dt<4;dt++){ nwv[dt]=nw[hh*64+dt*16+lm]; skv[dt]=skip[hh*64+dt*16+lm]; }
  _Float16* ctw = ct[wave];
  for (int qi=wave; qi<10; qi+=4){
    int s0=qi*16;
    int srow=s0+quad*4;
    // build A-fragments of q for rows s0..s0+15 (lane's row = s0+lm), d in [0,32) and [32,64)
    int sq = s0+lm; if (sq>S_-1) sq=S_-1;
    const _Float16* xrow = &xcg[(size_t)sq*D_];
    h8_t qf0, qf1;
#pragma unroll
    for (int f=0; f<2; f++){
      int d0 = f*32 + quad*8;
      h4_t xa = *(const h4_t*)&xrow[d0];
      h4_t xb = *(const h4_t*)&xrow[d0+4];
      float4 xaf=h4f(xa), xbf=h4f(xb);
      int nb0 = (hh*16 + (d0>>2))<<4;
#pragma unroll
      for (int j=0;j<4;j++){
        float4 wr = *(const float4*)&qw[nb0 + j*4];
        float qv = qb2[hh*64+d0+j] + dot4(wr, xaf);
        if (f==0) qf0[j]=(_Float16)qv; else qf1[j]=(_Float16)qv;
      }
#pragma unroll
      for (int j=0;j<4;j++){
        float4 wr = *(const float4*)&qw[nb0 + 16 + j*4];
        float qv = qb2[hh*64+d0+4+j] + dot4(wr, xbf);
        if (f==0) qf0[4+j]=(_Float16)qv; else qf1[4+j]=(_Float16)qv;
      }
    }
    f4_t acc0={0,0,0,0},acc1={0,0,0,0},acc2={0,0,0,0},acc3={0,0,0,0};
    float rsum[4]={0.f,0.f,0.f,0.f};
    float lfs[4], mxs[4]; bool sv[4];
#pragma unroll
    for (int r=0;r<4;r++){
      int s=srow+r; sv[r]=(s<S_);
      int sc = sv[r]? s : S_-1;
      lfs[r]=lfc[sc+1]; mxs[r]=mxl[sc];
    }
    int npair=(qi+2)>>1;
    for (int tp=0; tp<npair; tp++){
#pragma unroll
      for (int half=0; half<2; half++){
        int ti=2*tp+half;
        f4_t aq={0,0,0,0};
        if (ti<=qi){
          int t0=ti*16;
          h8_t kb0=*(const h8_t*)&kt[(t0+lm)*72+quad*8];
          h8_t kb1=*(const h8_t*)&kt[(t0+lm)*72+32+quad*8];
          aq=__builtin_amdgcn_mfma_f32_16x16x32_f16(qf0,kb0,aq,0,0,0);
          aq=__builtin_amdgcn_mfma_f32_16x16x32_f16(qf1,kb1,aq,0,0,0);
        }
        int t=ti*16+lm;
        bool tv = (t<S_);
        float lfT = tv? lfc[t+1]:0.f;
        float igT = tv? igl[t]:0.f;
#pragma unroll
        for (int r=0;r<4;r++){
          float coef=0.f;
          if (tv && sv[r] && t<=srow+r){
            coef = aq[r]*0.125f*__expf(lfs[r]-lfT+igT-mxs[r]);
          }
          rsum[r]+=coef;
          ctw[(quad*4+r)*40 + half*16 + lm] = (_Float16)coef;
        }
      }
      asm volatile("s_waitcnt lgkmcnt(0)" ::: "memory");  // intra-wave LDS write->read ordering
      h8_t af=*(const h8_t*)&ctw[lm*40+quad*8];
      int tb=tp*32+quad*8;
      h8_t bv0=*(const h8_t*)&vT[(0*16+lm)*184+tb];
      h8_t bv1=*(const h8_t*)&vT[(1*16+lm)*184+tb];
      h8_t bv2=*(const h8_t*)&vT[(2*16+lm)*184+tb];
      h8_t bv3=*(const h8_t*)&vT[(3*16+lm)*184+tb];
      acc0=__builtin_amdgcn_mfma_f32_16x16x32_f16(af,bv0,acc0,0,0,0);
      acc1=__builtin_amdgcn_mfma_f32_16x16x32_f16(af,bv1,acc1,0,0,0);
      acc2=__builtin_amdgcn_mfma_f32_16x16x32_f16(af,bv2,acc2,0,0,0);
      acc3=__builtin_amdgcn_mfma_f32_16x16x32_f16(af,bv3,acc3,0,0,0);
    }
    // row-sum reduce over the 16 lanes holding each row (bits 0..3 of lane)
#pragma unroll
    for (int r=0;r<4;r++){
      float v_=rsum[r];
      v_+=__shfl_xor(v_,1,64); v_+=__shfl_xor(v_,2,64);
      v_+=__shfl_xor(v_,4,64); v_+=__shfl_xor(v_,8,64);
      rsum[r]=v_;
    }
    float nrm[4];
#pragma unroll
    for (int r=0;r<4;r++) nrm[r]=fmaxf(fabsf(rsum[r]), __expf(-mxs[r]))+1e-6f;
    // epilogue: per-head LN over 64 d + learnable skip + silu(z) gate; write hs in-place
#pragma unroll
    for (int r=0;r<4;r++){
      if (!sv[r]) continue;
      int s=srow+r;
      float o0=acc0[r]/nrm[r], o1=acc1[r]/nrm[r], o2=acc2[r]/nrm[r], o3=acc3[r]/nrm[r];
      float ss=o0+o1+o2+o3;
      ss+=__shfl_xor(ss,1,64); ss+=__shfl_xor(ss,2,64); ss+=__shfl_xor(ss,4,64); ss+=__shfl_xor(ss,8,64);
      float mu=ss*(1.f/64.f);
      float d0=o0-mu,d1=o1-mu,d2=o2-mu,d3=o3-mu;
      float vv=d0*d0+d1*d1+d2*d2+d3*d3;
      vv+=__shfl_xor(vv,1,64); vv+=__shfl_xor(vv,2,64); vv+=__shfl_xor(vv,4,64); vv+=__shfl_xor(vv,8,64);
      float rs=rsqrtf(vv*(1.f/64.f)+1e-5f);
      size_t rowoff=(size_t)s*D_;
      float dd4[4]={d0,d1,d2,d3};
#pragma unroll
      for (int dt=0;dt<4;dt++){
        float hn = dd4[dt]*rs*nwv[dt];
        float xcv=(float)xcg[rowoff+dt*16+lm];
        float zv =(float)zg [rowoff+dt*16+lm];
        xcg[rowoff+dt*16+lm]=(_Float16)((hn+skv[dt]*xcv)*siluf_(zv));
      }
    }
  }
}

// ---------------- K5: h += hs @ m_down_w + b ----------------
__global__ __launch_bounds__(256) void k_down(const _Float16* __restrict__ hs, const float* __restrict__ w,
    const float* __restrict__ bb, float* __restrict__ h){
  __shared__ float hl[8*D_];
  int row0 = blockIdx.x*8; int tid = threadIdx.x;
  for (int i=tid;i<8*D_;i+=256) hl[i] = (float)hs[(size_t)row0*D_ + i];
  __syncthreads();
  int o = tid&127, rh = tid>>7;
  float acc[4]={0.f,0.f,0.f,0.f};
  for (int i=0;i<D_;i+=4){
    float wv[4];
#pragma unroll
    for (int ii=0;ii<4;ii++) wv[ii] = w[(i+ii)*E_ + o];
#pragma unroll
    for (int r=0;r<4;r++){
      float4 xv = *(const float4*)&hl[(rh+2*r)*D_ + i];
      acc[r] += xv.x*wv[0]+xv.y*wv[1]+xv.z*wv[2]+xv.w*wv[3];
    }
  }
  float bv = bb[o];
#pragma unroll
  for (int r=0;r<4;r++){
    size_t idx = (size_t)(row0+rh+2*r)*E_ + o;
    h[idx] += acc[r] + bv;
  }
}

// ---------------- K6: fused LN(h) + causal conv + silu -> xcs (fp16) ----------------
__global__ __launch_bounds__(256) void k_lnconv(const float* __restrict__ h, const float* __restrict__ lnw,
    const float* __restrict__ cw, const float* __restrict__ cb, _Float16* __restrict__ xcs){
  __shared__ float xn[19][E_];
  int b = blockIdx.x/10, chunk = blockIdx.x - b*10;
  int s0 = chunk*16;
  int tid=threadIdx.x, wave=tid>>6, lane=tid&63;
  for (int ii=wave; ii<19; ii+=4){
    int sg = s0-3+ii;
    if (sg>=0 && sg<S_){
      size_t off = (size_t)(b*S_+sg)*E_;
      float x0=h[off+lane], x1=h[off+lane+64];
      float mu=wsum(x0+x1)*(1.f/E_);
      float d0=x0-mu,d1=x1-mu;
      float var=wsum(d0*d0+d1*d1)*(1.f/E_);
      float rs=rsqrtf(var+1e-5f);
      xn[ii][lane]=d0*rs*lnw[lane];
      xn[ii][lane+64]=d1*rs*lnw[lane+64];
    } else { xn[ii][lane]=0.f; xn[ii][lane+64]=0.f; }
  }
  __syncthreads();
  int ch=tid&127, rh=tid>>7;
  float4 w4 = *(const float4*)&cw[ch*4];
  float bv = cb[ch];
  for (int r=rh; r<16; r+=2){
    int s=s0+r;
    if (s<S_){
      float acc = bv + w4.x*xn[r][ch] + w4.y*xn[r+1][ch] + w4.z*xn[r+2][ch] + w4.w*xn[r+3][ch];
      xcs[(size_t)(b*S_+s)*E_+ch] = (_Float16)siluf_(acc);
    }
  }
}

// ---------------- K7: sLSTM gates (fused LN(h) for gz/go), fp16 out ----------------
__global__ __launch_bounds__(128) void k_gates(const _Float16* __restrict__ xcs, const float* __restrict__ h,
    const float* __restrict__ lnw, const float* __restrict__ gw,
    _Float16* __restrict__ gi, _Float16* __restrict__ gf,
    _Float16* __restrict__ gz, _Float16* __restrict__ go){
  __shared__ float xcl[E_], xnl[E_], red2[2];
  int row = blockIdx.x; int b = row/S_; int s = row - b*S_;
  int t = threadIdx.x;
  float hv = h[(size_t)row*E_+t];
  float mu = bsum128(hv, red2)*(1.f/E_);
  float dd = hv-mu;
  float var = bsum128(dd*dd, red2)*(1.f/E_);
  xnl[t] = dd*rsqrtf(var+1e-5f)*lnw[t];
  xcl[t] = (float)xcs[(size_t)row*E_+t];
  __syncthreads();
  int hh = t>>5, o = t&31;
  float a0=0.f,a1=0.f,a2=0.f,a3=0.f;
  const float* w0 = gw + (((0*4+hh)*32+o)<<5);
  const float* w1 = gw + (((1*4+hh)*32+o)<<5);
  const float* w2 = gw + (((2*4+hh)*32+o)<<5);
  const float* w3 = gw + (((3*4+hh)*32+o)<<5);
  const float* xch = &xcl[hh*32]; const float* xnh = &xnl[hh*32];
  for (int d=0; d<32; d+=4){
    float4 xc4 = *(const float4*)&xch[d];
    float4 xn4 = *(const float4*)&xnh[d];
    a0 += dot4(*(const float4*)&w0[d], xc4);
    a1 += dot4(*(const float4*)&w1[d], xc4);
    a2 += dot4(*(const float4*)&w2[d], xn4);
    a3 += dot4(*(const float4*)&w3[d], xn4);
  }
  size_t oidx = ((size_t)s*B_ + b)*E_ + t;
  gi[oidx]=(_Float16)a0; gf[oidx]=(_Float16)a1; gz[oidx]=(_Float16)a2; go[oidx]=(_Float16)a3;
}

// ---------------- K8: sLSTM recurrent scan (final y only) ----------------
__global__ __launch_bounds__(128) void k_scan(const _Float16* __restrict__ gi, const _Float16* __restrict__ gf,
    const _Float16* __restrict__ gz, const _Float16* __restrict__ go,
    const float* __restrict__ sr, const float* __restrict__ sb, float* __restrict__ yl){
  __shared__ _Float16 srt[16384];   // [h][d][k][g] fp16, 32KB
  int b = blockIdx.x; int t = threadIdx.x;
  for (int i=t;i<16384;i+=128){
    int g = i>>12; int rem = i&4095; int hh = rem>>10; int d = (rem>>5)&31; int kk = i&31;
    srt[(((hh*32+d)*32 + kk)<<2) + g] = (_Float16)sr[i];
  }
  __syncthreads();
  int hh = t>>5; int lane = t&63; int kk = t&31;
  float sb0 = sb[t], sb1 = sb[128+t], sb2 = sb[256+t], sb3 = sb[384+t];
  float y=0.f,cst=0.f,nst=0.f,mst=-1e30f;
  size_t base0 = (size_t)b*E_ + t;
  float gc0 = (float)gi[base0], gc1 = (float)gf[base0], gc2 = (float)gz[base0], gc3 = (float)go[base0];
  const _Float16* srh = srt + hh*4096;
  for (int s=0;s<S_;s++){
    int sn = (s+1 < S_)? s+1 : s;
    size_t nidx = ((size_t)sn*B_ + b)*E_ + t;
    float n0 = (float)gi[nidx], n1 = (float)gf[nidx], n2 = (float)gz[nidx], n3 = (float)go[nidx];
    float ry0=0.f,ry1=0.f,ry2=0.f,ry3=0.f;
#pragma unroll 8
    for (int d=0; d<32; d++){
      float yv = __shfl(y, (lane & 32) + d, 64);
      float4 w = h4f(*(const h4_t*)&srh[(d*32 + kk)<<2]);
      ry0 += yv*w.x; ry1 += yv*w.y; ry2 += yv*w.z; ry3 += yv*w.w;
    }
    float ir = gc0 + ry0 + sb0;
    float fr = gc1 + ry1 + sb1;
    float zr = gc2 + ry2 + sb2;
    float orr= gc3 + ry3 + sb3;
    float lfm = mst + logsigf_(fr);
    float mn = fmaxf(ir, lfm);
    float igt = expf(ir - mn);
    float fgt = expf(lfm - mn);
    cst = fgt*cst + igt*tanhf(zr);
    nst = fgt*nst + igt;
    mst = mn;
    y = sigmoidf_(orr)*cst/nst;
    gc0=n0; gc1=n1; gc2=n2; gc3=n3;
  }
  yl[(size_t)b*E_ + t] = y;
}

// ---------------- K9: last-position head (mhln + FFN + post-LN + fc) ----------------
__global__ __launch_bounds__(128) void k_head(const float* __restrict__ h, const float* __restrict__ yl,
   const float* __restrict__ snw, const float* __restrict__ lnffw,
   const float* __restrict__ upw, const float* __restrict__ upb,
   const float* __restrict__ dww, const float* __restrict__ dwb,
   const float* __restrict__ postw, const float* __restrict__ fcw, const float* __restrict__ fcb,
   float* __restrict__ out){
  __shared__ float ylsh[E_], xnf[E_], up[2*FF_], gg[FF_], red2[2];
  int b = blockIdx.x; int t = threadIdx.x;
  float yv = yl[(size_t)b*E_+t];
  ylsh[t] = yv;
  __syncthreads();
  int base = (t>>5)<<5;
  float mu=0.f;
  for (int d=0;d<32;d++) mu += ylsh[base+d];
  mu *= (1.f/32.f);
  float var=0.f;
  for (int d=0;d<32;d++){ float dd = ylsh[base+d]-mu; var += dd*dd; }
  var *= (1.f/32.f);
  float hn = (yv-mu)*rsqrtf(var+1e-5f)*snw[t];
  float h1 = h[((size_t)b*S_ + (S_-1))*E_ + t] + hn;
  float mu1 = bsum128(h1, red2)*(1.f/E_);
  float d1 = h1-mu1;
  float var1 = bsum128(d1*d1, red2)*(1.f/E_);
  xnf[t] = d1*rsqrtf(var1+1e-5f)*lnffw[t];
  __syncthreads();
  float u0=upb[t], u1=upb[t+128], u2=upb[t+256];
  for (int i=0;i<E_;i++){
    float x = xnf[i];
    u0 += x*upw[i*384+t];
    u1 += x*upw[i*384+t+128];
    u2 += x*upw[i*384+t+256];
  }
  up[t]=u0; up[t+128]=u1; up[t+256]=u2;
  __syncthreads();
  for (int j=t;j<FF_;j+=128){
    float gp = up[j];
    gg[j] = 0.5f*gp*(1.f+erff(gp*0.70710678118f))*up[FF_+j];
  }
  __syncthreads();
  float acc = dwb[t];
  for (int j=0;j<FF_;j++) acc += gg[j]*dww[j*E_+t];
  float h2 = h1 + acc;
  float mu2 = bsum128(h2, red2)*(1.f/E_);
  float d2 = h2-mu2;
  float var2 = bsum128(d2*d2, red2)*(1.f/E_);
  float hp = d2*rsqrtf(var2+1e-5f)*postw[t];
  float pr = bsum128(hp*fcw[t], red2);
  if (t==0) out[b] = pr + fcb[0];
}

extern "C" void kernel_launch(void* const* d_in, const int* in_sizes, int n_in,
                              void* d_out, int out_size, void* d_ws, size_t ws_size,
                              hipStream_t stream){
  const float* x        = (const float*)d_in[0];
  const float* w_in     = (const float*)d_in[1];
  const float* b_in     = (const float*)d_in[2];
  const float* ln0_w    = (const float*)d_in[3];
  const float* m_up_w   = (const float*)d_in[4];
  const float* m_up_b   = (const float*)d_in[5];
  const float* m_conv_w = (const float*)d_in[6];
  const float* m_conv_b = (const float*)d_in[7];
  const float* m_q_w    = (const float*)d_in[8];
  const float* m_q_b    = (const float*)d_in[9];
  const float* m_k_w    = (const float*)d_in[10];
  const float* m_k_b    = (const float*)d_in[11];
  const float* m_v_w    = (const float*)d_in[12];
  const float* m_v_b    = (const float*)d_in[13];
  const float* m_ig_w   = (const float*)d_in[14];
  const float* m_ig_b   = (const float*)d_in[15];
  const float* m_fg_w   = (const float*)d_in[16];
  const float* m_fg_b   = (const float*)d_in[17];
  const float* m_norm_w = (const float*)d_in[18];
  const float* m_skip   = (const float*)d_in[19];
  const float* m_down_w = (const float*)d_in[20];
  const float* m_down_b = (const float*)d_in[21];
  const float* ln1_w    = (const float*)d_in[22];
  const float* s_conv_w = (const float*)d_in[23];
  const float* s_conv_b = (const float*)d_in[24];
  const float* s_gate_w = (const float*)d_in[25];
  const float* s_r      = (const float*)d_in[26];
  const float* s_b      = (const float*)d_in[27];
  const float* s_norm_w = (const float*)d_in[28];
  const float* ln_ff_w  = (const float*)d_in[29];
  const float* ff_up_w  = (const float*)d_in[30];
  const float* ff_up_b  = (const float*)d_in[31];
  const float* ff_down_w= (const float*)d_in[32];
  const float* ff_down_b= (const float*)d_in[33];
  const float* post_w   = (const float*)d_in[34];
  const float* fc_w     = (const float*)d_in[35];
  const float* fc_b     = (const float*)d_in[36];
  float* out = (float*)d_out;
  float* wsf = (float*)d_ws;

  // workspace layout (units = f32 slots): total 40,001,536 f32 = 152.6 MiB
  float*     h  = wsf;                              // (B,S,E) f32
  _Float16*  A  = (_Float16*)(wsf + 9830400);       // x_m -> xcs | gz
  _Float16*  Bz = (_Float16*)(wsf + 19660800);      // z   -> gi | gf
  _Float16*  C  = (_Float16*)(wsf + 29491200);      // xc/hs -> go
  float*     ig = wsf + 39321600;
  float*     fg = wsf + 39628800;
  float*     yl = wsf + 39936000;

  k_inproj<<<ROWS_/16, 256, 0, stream>>>(x, w_in, b_in, h);
  k_ln_up<<<ROWS_/8, 256, 0, stream>>>(h, ln0_w, m_up_w, m_up_b, A, Bz);
  k_conv_qkv<<<ROWS_, 256, 0, stream>>>(A, m_conv_w, m_conv_b, m_q_w, m_q_b, m_k_w, m_k_b,
       m_v_w, m_v_b, m_ig_w, m_ig_b, m_fg_w, m_fg_b, C, ig, fg);
  k_mlstm<<<B_*4, 256, 0, stream>>>(C, A, Bz, m_q_w, m_q_b, m_k_w, m_k_b, m_v_w, m_v_b,
       ig, fg, m_norm_w, m_skip);
  k_down<<<ROWS_/8, 256, 0, stream>>>(C, m_down_w, m_down_b, h);
  _Float16* xcs = A;
  _Float16* gz  = A + 9830400;
  _Float16* gi  = Bz;
  _Float16* gf  = Bz + 9830400;
  _Float16* go  = C;
  k_lnconv<<<B_*10, 256, 0, stream>>>(h, ln1_w, s_conv_w, s_conv_b, xcs);
  k_gates<<<ROWS_, 128, 0, stream>>>(xcs, h, ln1_w, s_gate_w, gi, gf, gz, go);
  k_scan<<<B_, 128, 0, stream>>>(gi, gf, gz, go, s_r, s_b, yl);
  k_head<<<B_, 128, 0, stream>>>(h, yl, s_norm_w, ln_ff_w, ff_up_w, ff_up_b,
       ff_down_w, ff_down_b, post_w, fc_w, fc_b, out);
}

// Round 6
// 1370.860 us; speedup vs baseline: 2.0419x; 1.2579x over previous
//
#include <hip/hip_runtime.h>
#include <math.h>

#define B_ 512
#define S_ 150
#define FIN_ 75
#define E_ 128
#define D_ 256
#define FF_ 192
#define ROWS_ (B_*S_)

typedef _Float16 h4_t __attribute__((ext_vector_type(4)));
typedef _Float16 h8_t __attribute__((ext_vector_type(8)));
typedef float f4_t __attribute__((ext_vector_type(4)));

__device__ __forceinline__ float wsum(float v){
#pragma unroll
  for (int o=32;o;o>>=1) v += __shfl_xor(v,o,64);
  return v;
}
__device__ __forceinline__ float sigmoidf_(float x){ return 1.f/(1.f+expf(-x)); }
__device__ __forceinline__ float siluf_(float x){ return x/(1.f+expf(-x)); }
__device__ __forceinline__ float logsigf_(float x){ return fminf(x,0.f)-log1pf(expf(-fabsf(x))); }
__device__ __forceinline__ float dot4(float4 a, float4 b){ return a.x*b.x+a.y*b.y+a.z*b.z+a.w*b.w; }
__device__ __forceinline__ float hdot(float4 w, h4_t x){
  return w.x*(float)x[0] + w.y*(float)x[1] + w.z*(float)x[2] + w.w*(float)x[3];
}
__device__ __forceinline__ float4 h4f(h4_t v){
  return make_float4((float)v[0],(float)v[1],(float)v[2],(float)v[3]);
}
__device__ __forceinline__ float bsum128(float v, float* red2){
  v = wsum(v);
  __syncthreads();
  if ((threadIdx.x&63)==0) red2[threadIdx.x>>6]=v;
  __syncthreads();
  return red2[0]+red2[1];
}

// ---------------- K1: h = x @ w_in + b_in (f32 -> f32) ----------------
__global__ __launch_bounds__(256) void k_inproj(const float* __restrict__ x, const float* __restrict__ w,
    const float* __restrict__ b, float* __restrict__ h){
  __shared__ float xl[16*FIN_];
  int row0 = blockIdx.x*16;
  int tid = threadIdx.x;
  for (int i=tid;i<16*FIN_;i+=256) xl[i] = x[(size_t)row0*FIN_ + i];
  __syncthreads();
  int o = tid & 127, rh = tid >> 7;
  float acc[8];
#pragma unroll
  for (int r=0;r<8;r++) acc[r]=0.f;
  for (int i=0;i<FIN_;i++){
    float wv = w[i*E_ + o];
#pragma unroll
    for (int r=0;r<8;r++) acc[r] += xl[(rh + 2*r)*FIN_ + i]*wv;
  }
  float bv = b[o];
#pragma unroll
  for (int r=0;r<8;r++) h[(size_t)(row0 + rh + 2*r)*E_ + o] = acc[r] + bv;
}

// ---------------- K2: xn=LN(h); [x_m|z] = xn @ m_up_w + b (out fp16) ----------------
__global__ __launch_bounds__(256) void k_ln_up(const float* __restrict__ h, const float* __restrict__ lnw,
     const float* __restrict__ w, const float* __restrict__ bb,
     _Float16* __restrict__ xm, _Float16* __restrict__ z){
  __shared__ float xl[8*E_];
  int row0 = blockIdx.x*8; int tid = threadIdx.x;
  for (int i=tid;i<8*E_;i+=256) xl[i] = h[(size_t)row0*E_ + i];
  __syncthreads();
  int wave = tid>>6, lane = tid&63;
  for (int rr = wave; rr < 8; rr += 4){
    float x0 = xl[rr*E_+lane], x1 = xl[rr*E_+lane+64];
    float mu = wsum(x0+x1) * (1.f/E_);
    float d0=x0-mu, d1=x1-mu;
    float var = wsum(d0*d0+d1*d1)*(1.f/E_);
    float rs = rsqrtf(var+1e-5f);
    xl[rr*E_+lane] = d0*rs*lnw[lane];
    xl[rr*E_+lane+64] = d1*rs*lnw[lane+64];
  }
  __syncthreads();
  float a0[8], a1[8];
#pragma unroll
  for (int r=0;r<8;r++){a0[r]=0.f;a1[r]=0.f;}
  int o = tid;
  for (int i=0;i<E_;i+=4){
    float w0v[4], w1v[4];
#pragma unroll
    for (int ii=0;ii<4;ii++){ w0v[ii] = w[(i+ii)*512+o]; w1v[ii]=w[(i+ii)*512+o+256]; }
#pragma unroll
    for (int r=0;r<8;r++){
      float4 xr = *(const float4*)&xl[r*E_+i];
      a0[r] += xr.x*w0v[0] + xr.y*w0v[1] + xr.z*w0v[2] + xr.w*w0v[3];
      a1[r] += xr.x*w1v[0] + xr.y*w1v[1] + xr.z*w1v[2] + xr.w*w1v[3];
    }
  }
  float b0 = bb[o], b1 = bb[o+256];
#pragma unroll
  for (int r=0;r<8;r++){
    xm[(size_t)(row0+r)*D_ + o] = (_Float16)(a0[r]+b0);
    z [(size_t)(row0+r)*D_ + o] = (_Float16)(a1[r]+b1);
  }
}

// ---------------- K3: conv+silu -> xc (fp16); ig/fg (f32) ----------------
__global__ __launch_bounds__(256) void k_conv_qkv(const _Float16* __restrict__ xm,
    const float* __restrict__ cw, const float* __restrict__ cb,
    const float* __restrict__ qw, const float* __restrict__ qb2,
    const float* __restrict__ kw, const float* __restrict__ kb2,
    const float* __restrict__ vw, const float* __restrict__ vb2,
    const float* __restrict__ igw, const float* __restrict__ igb,
    const float* __restrict__ fgw, const float* __restrict__ fgb,
    _Float16* __restrict__ xc, float* __restrict__ ig, float* __restrict__ fg){
  __shared__ float xml[4][D_];
  __shared__ float xcl[D_];
  __shared__ float part[4][8];
  int row = blockIdx.x; int b = row/S_; int s = row - b*S_;
  int c = threadIdx.x;
#pragma unroll
  for (int j=0;j<4;j++){
    int sj = s-3+j;
    xml[j][c] = (sj>=0)? (float)xm[(size_t)(row-3+j)*D_ + c] : 0.f;
  }
  __syncthreads();
  float4 wc = *(const float4*)&cw[c*4];
  float cv = cb[c] + wc.x*xml[0][c] + wc.y*xml[1][c] + wc.z*xml[2][c] + wc.w*xml[3][c];
  cv = siluf_(cv);
  xcl[c] = cv;
  xc[(size_t)row*D_ + c] = (_Float16)cv;
  int nb = c>>2, rr = c&3;
  float4 vw4 = *(const float4*)&vw[nb*16 + rr*4];
  float4 xv4 = *(const float4*)&xml[3][nb*4];
  float vv = vb2[c] + dot4(vw4, xv4);
  __syncthreads();
  float4 qw4 = *(const float4*)&qw[nb*16 + rr*4];
  float4 kw4 = *(const float4*)&kw[nb*16 + rr*4];
  float4 xc4 = *(const float4*)&xcl[nb*4];
  float qv = qb2[c] + dot4(qw4, xc4);
  float kv = kb2[c] + dot4(kw4, xc4);
  float4 wiq = *(const float4*)&igw[c*4];
  float4 wik = *(const float4*)&igw[(256+c)*4];
  float4 wiv = *(const float4*)&igw[(512+c)*4];
  float4 wfq = *(const float4*)&fgw[c*4];
  float4 wfk = *(const float4*)&fgw[(256+c)*4];
  float4 wfv = *(const float4*)&fgw[(512+c)*4];
  float p[8];
  p[0] = qv*wiq.x + kv*wik.x + vv*wiv.x;
  p[1] = qv*wiq.y + kv*wik.y + vv*wiv.y;
  p[2] = qv*wiq.z + kv*wik.z + vv*wiv.z;
  p[3] = qv*wiq.w + kv*wik.w + vv*wiv.w;
  p[4] = qv*wfq.x + kv*wfk.x + vv*wfv.x;
  p[5] = qv*wfq.y + kv*wfk.y + vv*wfv.y;
  p[6] = qv*wfq.z + kv*wfk.z + vv*wfv.z;
  p[7] = qv*wfq.w + kv*wfk.w + vv*wfv.w;
#pragma unroll
  for (int j=0;j<8;j++) p[j] = wsum(p[j]);
  int wave = c>>6, lane = c&63;
  if (lane==0){
#pragma unroll
    for (int j=0;j<8;j++) part[wave][j]=p[j];
  }
  __syncthreads();
  if (c < 8){
    float t4 = part[0][c]+part[1][c]+part[2][c]+part[3][c];
    int g = c&3;
    if (c<4) ig[(size_t)(b*4+g)*S_ + s] = t4 + igb[g];
    else     fg[(size_t)(b*4+g)*S_ + s] = t4 + fgb[g];
  }
}

// ---------------- K4: mLSTM via MFMA (flash-style) + fused LN/skip/gate epilogue ----------------
__global__ __launch_bounds__(256) void k_mlstm(_Float16* xcio,
    const _Float16* __restrict__ xm, const _Float16* __restrict__ z,
    const float* __restrict__ qw, const float* __restrict__ qb2,
    const float* __restrict__ kw, const float* __restrict__ kb2,
    const float* __restrict__ vw, const float* __restrict__ vb2,
    const float* __restrict__ ig, const float* __restrict__ fg,
    const float* __restrict__ nw, const float* __restrict__ skip){
  __shared__ __align__(16) _Float16 kt[160*72];    // k[t][d], row stride 72 halves
  __shared__ __align__(16) _Float16 vT[64*184];    // v[d][t], row stride 184 halves
  __shared__ __align__(16) _Float16 ct[4][16*40];  // per-wave coef tile 16 x 32 (stride 40)
  __shared__ float lfc[S_+1];
  __shared__ float igl[S_];
  __shared__ float mxl[S_];
  int bh = blockIdx.x; int b = bh>>2; int hh = bh&3;
  int tid = threadIdx.x; int wave = tid>>6, lane = tid&63;
  int quad = lane>>4, lm = lane&15;
  _Float16* xcg = xcio + (size_t)b*S_*D_ + hh*64;
  const _Float16* xmg = xm + (size_t)b*S_*D_ + hh*64;
  const _Float16* zg  = z  + (size_t)b*S_*D_ + hh*64;
  for (int i=tid;i<160*64;i+=256){
    int t=i>>6, d=i&63;
    float kvv=0.f, vvv=0.f;
    if (t<S_){
      int nb=d>>2, dd=d&3;
      h4_t xk = *(const h4_t*)&xcg[(size_t)t*D_+(nb<<2)];
      h4_t xv = *(const h4_t*)&xmg[(size_t)t*D_+(nb<<2)];
      float4 wk = *(const float4*)&kw[((hh*16+nb)<<4)+(dd<<2)];
      float4 wv = *(const float4*)&vw[((hh*16+nb)<<4)+(dd<<2)];
      kvv = kb2[hh*64+d]+hdot(wk,xk);
      vvv = vb2[hh*64+d]+hdot(wv,xv);
    }
    kt[t*72+d]=(_Float16)kvv;
    vT[d*184+t]=(_Float16)vvv;
  }
  if (tid<S_){ igl[tid]=ig[(size_t)bh*S_+tid]; mxl[tid]=logsigf_(fg[(size_t)bh*S_+tid]); }
  __syncthreads();
  if (tid==0){
    float run=0.f, rm=-3.0e38f;
    lfc[0]=0.f;
    for (int t=0;t<S_;t++){
      run += mxl[t];
      lfc[t+1]=run;
      float gv = igl[t]-run;
      rm = fmaxf(rm,gv);
      mxl[t] = run + rm;
    }
  }
  __syncthreads();
  float nwv[4], skv[4];
#pragma unroll
  for (int dt=0;dt<4;dt++){ nwv[dt]=nw[hh*64+dt*16+lm]; skv[dt]=skip[hh*64+dt*16+lm]; }
  _Float16* ctw = ct[wave];
  for (int qi=wave; qi<10; qi+=4){
    int s0=qi*16;
    int srow=s0+quad*4;
    int sq = s0+lm; if (sq>S_-1) sq=S_-1;
    const _Float16* xrow = &xcg[(size_t)sq*D_];
    h8_t qf0, qf1;
#pragma unroll
    for (int f=0; f<2; f++){
      int d0 = f*32 + quad*8;
      h4_t xa = *(const h4_t*)&xrow[d0];
      h4_t xb = *(const h4_t*)&xrow[d0+4];
      float4 xaf=h4f(xa), xbf=h4f(xb);
      int nb0 = (hh*16 + (d0>>2))<<4;
#pragma unroll
      for (int j=0;j<4;j++){
        float4 wr = *(const float4*)&qw[nb0 + j*4];
        float qv = qb2[hh*64+d0+j] + dot4(wr, xaf);
        if (f==0) qf0[j]=(_Float16)qv; else qf1[j]=(_Float16)qv;
      }
#pragma unroll
      for (int j=0;j<4;j++){
        float4 wr = *(const float4*)&qw[nb0 + 16 + j*4];
        float qv = qb2[hh*64+d0+4+j] + dot4(wr, xbf);
        if (f==0) qf0[4+j]=(_Float16)qv; else qf1[4+j]=(_Float16)qv;
      }
    }
    f4_t acc0={0,0,0,0},acc1={0,0,0,0},acc2={0,0,0,0},acc3={0,0,0,0};
    float rsum[4]={0.f,0.f,0.f,0.f};
    float lfs[4], mxs[4]; bool sv[4];
#pragma unroll
    for (int r=0;r<4;r++){
      int s=srow+r; sv[r]=(s<S_);
      int sc = sv[r]? s : S_-1;
      lfs[r]=lfc[sc+1]; mxs[r]=mxl[sc];
    }
    int npair=(qi+2)>>1;
    for (int tp=0; tp<npair; tp++){
#pragma unroll
      for (int half=0; half<2; half++){
        int ti=2*tp+half;
        f4_t aq={0,0,0,0};
        if (ti<=qi){
          int t0=ti*16;
          h8_t kb0=*(const h8_t*)&kt[(t0+lm)*72+quad*8];
          h8_t kb1=*(const h8_t*)&kt[(t0+lm)*72+32+quad*8];
          aq=__builtin_amdgcn_mfma_f32_16x16x32_f16(qf0,kb0,aq,0,0,0);
          aq=__builtin_amdgcn_mfma_f32_16x16x32_f16(qf1,kb1,aq,0,0,0);
        }
        int t=ti*16+lm;
        bool tv = (t<S_);
        float lfT = tv? lfc[t+1]:0.f;
        float igT = tv? igl[t]:0.f;
#pragma unroll
        for (int r=0;r<4;r++){
          float coef=0.f;
          if (tv && sv[r] && t<=srow+r){
            coef = aq[r]*0.125f*__expf(lfs[r]-lfT+igT-mxs[r]);
          }
          rsum[r]+=coef;
          ctw[(quad*4+r)*40 + half*16 + lm] = (_Float16)coef;
        }
      }
      asm volatile("s_waitcnt lgkmcnt(0)" ::: "memory");
      h8_t af=*(const h8_t*)&ctw[lm*40+quad*8];
      int tb=tp*32+quad*8;
      h8_t bv0=*(const h8_t*)&vT[(0*16+lm)*184+tb];
      h8_t bv1=*(const h8_t*)&vT[(1*16+lm)*184+tb];
      h8_t bv2=*(const h8_t*)&vT[(2*16+lm)*184+tb];
      h8_t bv3=*(const h8_t*)&vT[(3*16+lm)*184+tb];
      acc0=__builtin_amdgcn_mfma_f32_16x16x32_f16(af,bv0,acc0,0,0,0);
      acc1=__builtin_amdgcn_mfma_f32_16x16x32_f16(af,bv1,acc1,0,0,0);
      acc2=__builtin_amdgcn_mfma_f32_16x16x32_f16(af,bv2,acc2,0,0,0);
      acc3=__builtin_amdgcn_mfma_f32_16x16x32_f16(af,bv3,acc3,0,0,0);
    }
#pragma unroll
    for (int r=0;r<4;r++){
      float v_=rsum[r];
      v_+=__shfl_xor(v_,1,64); v_+=__shfl_xor(v_,2,64);
      v_+=__shfl_xor(v_,4,64); v_+=__shfl_xor(v_,8,64);
      rsum[r]=v_;
    }
    float nrm[4];
#pragma unroll
    for (int r=0;r<4;r++) nrm[r]=fmaxf(fabsf(rsum[r]), __expf(-mxs[r]))+1e-6f;
#pragma unroll
    for (int r=0;r<4;r++){
      if (!sv[r]) continue;
      int s=srow+r;
      float o0=acc0[r]/nrm[r], o1=acc1[r]/nrm[r], o2=acc2[r]/nrm[r], o3=acc3[r]/nrm[r];
      float ss=o0+o1+o2+o3;
      ss+=__shfl_xor(ss,1,64); ss+=__shfl_xor(ss,2,64); ss+=__shfl_xor(ss,4,64); ss+=__shfl_xor(ss,8,64);
      float mu=ss*(1.f/64.f);
      float d0=o0-mu,d1=o1-mu,d2=o2-mu,d3=o3-mu;
      float vv=d0*d0+d1*d1+d2*d2+d3*d3;
      vv+=__shfl_xor(vv,1,64); vv+=__shfl_xor(vv,2,64); vv+=__shfl_xor(vv,4,64); vv+=__shfl_xor(vv,8,64);
      float rs=rsqrtf(vv*(1.f/64.f)+1e-5f);
      size_t rowoff=(size_t)s*D_;
      float dd4[4]={d0,d1,d2,d3};
#pragma unroll
      for (int dt=0;dt<4;dt++){
        float hn = dd4[dt]*rs*nwv[dt];
        float xcv=(float)xcg[rowoff+dt*16+lm];
        float zv =(float)zg [rowoff+dt*16+lm];
        xcg[rowoff+dt*16+lm]=(_Float16)((hn+skv[dt]*xcv)*siluf_(zv));
      }
    }
  }
}

// ---------------- K5: h += hs @ m_down_w + b ----------------
__global__ __launch_bounds__(256) void k_down(const _Float16* __restrict__ hs, const float* __restrict__ w,
    const float* __restrict__ bb, float* __restrict__ h){
  __shared__ float hl[8*D_];
  int row0 = blockIdx.x*8; int tid = threadIdx.x;
  for (int i=tid;i<8*D_;i+=256) hl[i] = (float)hs[(size_t)row0*D_ + i];
  __syncthreads();
  int o = tid&127, rh = tid>>7;
  float acc[4]={0.f,0.f,0.f,0.f};
  for (int i=0;i<D_;i+=4){
    float wv[4];
#pragma unroll
    for (int ii=0;ii<4;ii++) wv[ii] = w[(i+ii)*E_ + o];
#pragma unroll
    for (int r=0;r<4;r++){
      float4 xv = *(const float4*)&hl[(rh+2*r)*D_ + i];
      acc[r] += xv.x*wv[0]+xv.y*wv[1]+xv.z*wv[2]+xv.w*wv[3];
    }
  }
  float bv = bb[o];
#pragma unroll
  for (int r=0;r<4;r++){
    size_t idx = (size_t)(row0+rh+2*r)*E_ + o;
    h[idx] += acc[r] + bv;
  }
}

// ---------------- K6: fused LN(h) + causal conv + silu -> xcs (fp16) ----------------
__global__ __launch_bounds__(256) void k_lnconv(const float* __restrict__ h, const float* __restrict__ lnw,
    const float* __restrict__ cw, const float* __restrict__ cb, _Float16* __restrict__ xcs){
  __shared__ float xn[19][E_];
  int b = blockIdx.x/10, chunk = blockIdx.x - b*10;
  int s0 = chunk*16;
  int tid=threadIdx.x, wave=tid>>6, lane=tid&63;
  for (int ii=wave; ii<19; ii+=4){
    int sg = s0-3+ii;
    if (sg>=0 && sg<S_){
      size_t off = (size_t)(b*S_+sg)*E_;
      float x0=h[off+lane], x1=h[off+lane+64];
      float mu=wsum(x0+x1)*(1.f/E_);
      float d0=x0-mu,d1=x1-mu;
      float var=wsum(d0*d0+d1*d1)*(1.f/E_);
      float rs=rsqrtf(var+1e-5f);
      xn[ii][lane]=d0*rs*lnw[lane];
      xn[ii][lane+64]=d1*rs*lnw[lane+64];
    } else { xn[ii][lane]=0.f; xn[ii][lane+64]=0.f; }
  }
  __syncthreads();
  int ch=tid&127, rh=tid>>7;
  float4 w4 = *(const float4*)&cw[ch*4];
  float bv = cb[ch];
  for (int r=rh; r<16; r+=2){
    int s=s0+r;
    if (s<S_){
      float acc = bv + w4.x*xn[r][ch] + w4.y*xn[r+1][ch] + w4.z*xn[r+2][ch] + w4.w*xn[r+3][ch];
      xcs[(size_t)(b*S_+s)*E_+ch] = (_Float16)siluf_(acc);
    }
  }
}

// ---------------- K7: sLSTM gates, 8 rows/block (bit-identical per-row math to r3 k_gates) ----------------
__global__ __launch_bounds__(128) void k_gates8(const _Float16* __restrict__ xcs, const float* __restrict__ h,
    const float* __restrict__ lnw, const float* __restrict__ gw,
    _Float16* __restrict__ gi, _Float16* __restrict__ gf,
    _Float16* __restrict__ gz, _Float16* __restrict__ go){
  __shared__ float xcl[E_], xnl[E_], red2[2];
  int row0 = blockIdx.x*8;
  int t = threadIdx.x;
  int hh = t>>5, o = t&31;
  const float* w0 = gw + (((0*4+hh)*32+o)<<5);
  const float* w1 = gw + (((1*4+hh)*32+o)<<5);
  const float* w2 = gw + (((2*4+hh)*32+o)<<5);
  const float* w3 = gw + (((3*4+hh)*32+o)<<5);
  float4 w0v[8], w1v[8], w2v[8], w3v[8];
#pragma unroll
  for (int d=0;d<8;d++){
    w0v[d]=*(const float4*)&w0[d*4]; w1v[d]=*(const float4*)&w1[d*4];
    w2v[d]=*(const float4*)&w2[d*4]; w3v[d]=*(const float4*)&w3[d*4];
  }
  float lnwv = lnw[t];
  for (int rr=0; rr<8; rr++){
    int row = row0+rr; int b = row/S_; int s = row - b*S_;
    float hv = h[(size_t)row*E_+t];
    float mu = bsum128(hv, red2)*(1.f/E_);
    float dd = hv-mu;
    float var = bsum128(dd*dd, red2)*(1.f/E_);
    xnl[t] = dd*rsqrtf(var+1e-5f)*lnwv;
    xcl[t] = (float)xcs[(size_t)row*E_+t];
    __syncthreads();
    float a0=0.f,a1=0.f,a2=0.f,a3=0.f;
    const float* xch = &xcl[hh*32]; const float* xnh = &xnl[hh*32];
#pragma unroll
    for (int d=0; d<8; d++){
      float4 xc4 = *(const float4*)&xch[d*4];
      float4 xn4 = *(const float4*)&xnh[d*4];
      a0 += dot4(w0v[d], xc4);
      a1 += dot4(w1v[d], xc4);
      a2 += dot4(w2v[d], xn4);
      a3 += dot4(w3v[d], xn4);
    }
    size_t oidx = ((size_t)s*B_ + b)*E_ + t;
    gi[oidx]=(_Float16)a0; gf[oidx]=(_Float16)a1; gz[oidx]=(_Float16)a2; go[oidx]=(_Float16)a3;
    __syncthreads();   // protect xnl/xcl before next row overwrites
  }
}

// ---------------- K8: sLSTM recurrent scan (final y only) ----------------
__global__ __launch_bounds__(128) void k_scan(const _Float16* __restrict__ gi, const _Float16* __restrict__ gf,
    const _Float16* __restrict__ gz, const _Float16* __restrict__ go,
    const float* __restrict__ sr, const float* __restrict__ sb, float* __restrict__ yl){
  __shared__ _Float16 srt[16384];   // [h][d][k][g] fp16, 32KB
  int b = blockIdx.x; int t = threadIdx.x;
  for (int i=t;i<16384;i+=128){
    int g = i>>12; int rem = i&4095; int hh = rem>>10; int d = (rem>>5)&31; int kk = i&31;
    srt[(((hh*32+d)*32 + kk)<<2) + g] = (_Float16)sr[i];
  }
  __syncthreads();
  int hh = t>>5; int lane = t&63; int kk = t&31;
  float sb0 = sb[t], sb1 = sb[128+t], sb2 = sb[256+t], sb3 = sb[384+t];
  float y=0.f,cst=0.f,nst=0.f,mst=-1e30f;
  size_t base0 = (size_t)b*E_ + t;
  float gc0 = (float)gi[base0], gc1 = (float)gf[base0], gc2 = (float)gz[base0], gc3 = (float)go[base0];
  const _Float16* srh = srt + hh*4096;
  for (int s=0;s<S_;s++){
    int sn = (s+1 < S_)? s+1 : s;
    size_t nidx = ((size_t)sn*B_ + b)*E_ + t;
    float n0 = (float)gi[nidx], n1 = (float)gf[nidx], n2 = (float)gz[nidx], n3 = (float)go[nidx];
    float ry0=0.f,ry1=0.f,ry2=0.f,ry3=0.f;
#pragma unroll 8
    for (int d=0; d<32; d++){
      float yv = __shfl(y, (lane & 32) + d, 64);
      float4 w = h4f(*(const h4_t*)&srh[(d*32 + kk)<<2]);
      ry0 += yv*w.x; ry1 += yv*w.y; ry2 += yv*w.z; ry3 += yv*w.w;
    }
    float ir = gc0 + ry0 + sb0;
    float fr = gc1 + ry1 + sb1;
    float zr = gc2 + ry2 + sb2;
    float orr= gc3 + ry3 + sb3;
    float lfm = mst + logsigf_(fr);
    float mn = fmaxf(ir, lfm);
    float igt = expf(ir - mn);
    float fgt = expf(lfm - mn);
    cst = fgt*cst + igt*tanhf(zr);
    nst = fgt*nst + igt;
    mst = mn;
    y = sigmoidf_(orr)*cst/nst;
    gc0=n0; gc1=n1; gc2=n2; gc3=n3;
  }
  yl[(size_t)b*E_ + t] = y;
}

// ---------------- K9: last-position head (mhln + FFN + post-LN + fc) ----------------
__global__ __launch_bounds__(128) void k_head(const float* __restrict__ h, const float* __restrict__ yl,
   const float* __restrict__ snw, const float* __restrict__ lnffw,
   const float* __restrict__ upw, const float* __restrict__ upb,
   const float* __restrict__ dww, const float* __restrict__ dwb,
   const float* __restrict__ postw, const float* __restrict__ fcw, const float* __restrict__ fcb,
   float* __restrict__ out){
  __shared__ float ylsh[E_], xnf[E_], up[2*FF_], gg[FF_], red2[2];
  int b = blockIdx.x; int t = threadIdx.x;
  float yv = yl[(size_t)b*E_+t];
  ylsh[t] = yv;
  __syncthreads();
  int base = (t>>5)<<5;
  float mu=0.f;
  for (int d=0;d<32;d++) mu += ylsh[base+d];
  mu *= (1.f/32.f);
  float var=0.f;
  for (int d=0;d<32;d++){ float dd = ylsh[base+d]-mu; var += dd*dd; }
  var *= (1.f/32.f);
  float hn = (yv-mu)*rsqrtf(var+1e-5f)*snw[t];
  float h1 = h[((size_t)b*S_ + (S_-1))*E_ + t] + hn;
  float mu1 = bsum128(h1, red2)*(1.f/E_);
  float d1 = h1-mu1;
  float var1 = bsum128(d1*d1, red2)*(1.f/E_);
  xnf[t] = d1*rsqrtf(var1+1e-5f)*lnffw[t];
  __syncthreads();
  float u0=upb[t], u1=upb[t+128], u2=upb[t+256];
  for (int i=0;i<E_;i++){
    float x = xnf[i];
    u0 += x*upw[i*384+t];
    u1 += x*upw[i*384+t+128];
    u2 += x*upw[i*384+t+256];
  }
  up[t]=u0; up[t+128]=u1; up[t+256]=u2;
  __syncthreads();
  for (int j=t;j<FF_;j+=128){
    float gp = up[j];
    gg[j] = 0.5f*gp*(1.f+erff(gp*0.70710678118f))*up[FF_+j];
  }
  __syncthreads();
  float acc = dwb[t];
  for (int j=0;j<FF_;j++) acc += gg[j]*dww[j*E_+t];
  float h2 = h1 + acc;
  float mu2 = bsum128(h2, red2)*(1.f/E_);
  float d2 = h2-mu2;
  float var2 = bsum128(d2*d2, red2)*(1.f/E_);
  float hp = d2*rsqrtf(var2+1e-5f)*postw[t];
  float pr = bsum128(hp*fcw[t], red2);
  if (t==0) out[b] = pr + fcb[0];
}

extern "C" void kernel_launch(void* const* d_in, const int* in_sizes, int n_in,
                              void* d_out, int out_size, void* d_ws, size_t ws_size,
                              hipStream_t stream){
  const float* x        = (const float*)d_in[0];
  const float* w_in     = (const float*)d_in[1];
  const float* b_in     = (const float*)d_in[2];
  const float* ln0_w    = (const float*)d_in[3];
  const float* m_up_w   = (const float*)d_in[4];
  const float* m_up_b   = (const float*)d_in[5];
  const float* m_conv_w = (const float*)d_in[6];
  const float* m_conv_b = (const float*)d_in[7];
  const float* m_q_w    = (const float*)d_in[8];
  const float* m_q_b    = (const float*)d_in[9];
  const float* m_k_w    = (const float*)d_in[10];
  const float* m_k_b    = (const float*)d_in[11];
  const float* m_v_w    = (const float*)d_in[12];
  const float* m_v_b    = (const float*)d_in[13];
  const float* m_ig_w   = (const float*)d_in[14];
  const float* m_ig_b   = (const float*)d_in[15];
  const float* m_fg_w   = (const float*)d_in[16];
  const float* m_fg_b   = (const float*)d_in[17];
  const float* m_norm_w = (const float*)d_in[18];
  const float* m_skip   = (const float*)d_in[19];
  const float* m_down_w = (const float*)d_in[20];
  const float* m_down_b = (const float*)d_in[21];
  const float* ln1_w    = (const float*)d_in[22];
  const float* s_conv_w = (const float*)d_in[23];
  const float* s_conv_b = (const float*)d_in[24];
  const float* s_gate_w = (const float*)d_in[25];
  const float* s_r      = (const float*)d_in[26];
  const float* s_b      = (const float*)d_in[27];
  const float* s_norm_w = (const float*)d_in[28];
  const float* ln_ff_w  = (const float*)d_in[29];
  const float* ff_up_w  = (const float*)d_in[30];
  const float* ff_up_b  = (const float*)d_in[31];
  const float* ff_down_w= (const float*)d_in[32];
  const float* ff_down_b= (const float*)d_in[33];
  const float* post_w   = (const float*)d_in[34];
  const float* fc_w     = (const float*)d_in[35];
  const float* fc_b     = (const float*)d_in[36];
  float* out = (float*)d_out;
  float* wsf = (float*)d_ws;

  // workspace layout (units = f32 slots): total 40,001,536 f32 = 152.6 MiB (r3-identical)
  float*     h  = wsf;                              // (B,S,E) f32
  _Float16*  A  = (_Float16*)(wsf + 9830400);       // x_m -> xcs | gz
  _Float16*  Bz = (_Float16*)(wsf + 19660800);      // z   -> gi | gf
  _Float16*  C  = (_Float16*)(wsf + 29491200);      // xc/hs -> go
  float*     ig = wsf + 39321600;
  float*     fg = wsf + 39628800;
  float*     yl = wsf + 39936000;

  k_inproj<<<ROWS_/16, 256, 0, stream>>>(x, w_in, b_in, h);
  k_ln_up<<<ROWS_/8, 256, 0, stream>>>(h, ln0_w, m_up_w, m_up_b, A, Bz);
  k_conv_qkv<<<ROWS_, 256, 0, stream>>>(A, m_conv_w, m_conv_b, m_q_w, m_q_b, m_k_w, m_k_b,
       m_v_w, m_v_b, m_ig_w, m_ig_b, m_fg_w, m_fg_b, C, ig, fg);
  k_mlstm<<<B_*4, 256, 0, stream>>>(C, A, Bz, m_q_w, m_q_b, m_k_w, m_k_b, m_v_w, m_v_b,
       ig, fg, m_norm_w, m_skip);
  k_down<<<ROWS_/8, 256, 0, stream>>>(C, m_down_w, m_down_b, h);
  _Float16* xcs = A;
  _Float16* gz  = A + 9830400;
  _Float16* gi  = Bz;
  _Float16* gf  = Bz + 9830400;
  _Float16* go  = C;
  k_lnconv<<<B_*10, 256, 0, stream>>>(h, ln1_w, s_conv_w, s_conv_b, xcs);
  k_gates8<<<ROWS_/8, 128, 0, stream>>>(xcs, h, ln1_w, s_gate_w, gi, gf, gz, go);
  k_scan<<<B_, 128, 0, stream>>>(gi, gf, gz, go, s_r, s_b, yl);
  k_head<<<B_, 128, 0, stream>>>(h, yl, s_norm_w, ln_ff_w, ff_up_w, ff_up_b,
       ff_down_w, ff_down_b, post_w, fc_w, fc_b, out);
}

// Round 7
// 1332.206 us; speedup vs baseline: 2.1011x; 1.0290x over previous
//
#include <hip/hip_runtime.h>
#include <math.h>

#define B_ 512
#define S_ 150
#define FIN_ 75
#define E_ 128
#define D_ 256
#define FF_ 192
#define ROWS_ (B_*S_)

typedef _Float16 h4_t __attribute__((ext_vector_type(4)));
typedef _Float16 h8_t __attribute__((ext_vector_type(8)));
typedef float f4_t __attribute__((ext_vector_type(4)));

__device__ __forceinline__ float wsum(float v){
#pragma unroll
  for (int o=32;o;o>>=1) v += __shfl_xor(v,o,64);
  return v;
}
__device__ __forceinline__ float sigmoidf_(float x){ return 1.f/(1.f+expf(-x)); }
__device__ __forceinline__ float siluf_(float x){ return x/(1.f+expf(-x)); }
__device__ __forceinline__ float logsigf_(float x){ return fminf(x,0.f)-log1pf(expf(-fabsf(x))); }
__device__ __forceinline__ float dot4(float4 a, float4 b){ return a.x*b.x+a.y*b.y+a.z*b.z+a.w*b.w; }
__device__ __forceinline__ float hdot(float4 w, h4_t x){
  return w.x*(float)x[0] + w.y*(float)x[1] + w.z*(float)x[2] + w.w*(float)x[3];
}
__device__ __forceinline__ float4 h4f(h4_t v){
  return make_float4((float)v[0],(float)v[1],(float)v[2],(float)v[3]);
}
__device__ __forceinline__ float bsum128(float v, float* red2){
  v = wsum(v);
  __syncthreads();
  if ((threadIdx.x&63)==0) red2[threadIdx.x>>6]=v;
  __syncthreads();
  return red2[0]+red2[1];
}

// ---------------- K1: h = x @ w_in + b_in (f32 -> f32) ----------------
__global__ __launch_bounds__(256) void k_inproj(const float* __restrict__ x, const float* __restrict__ w,
    const float* __restrict__ b, float* __restrict__ h){
  __shared__ float xl[16*FIN_];
  int row0 = blockIdx.x*16;
  int tid = threadIdx.x;
  for (int i=tid;i<16*FIN_;i+=256) xl[i] = x[(size_t)row0*FIN_ + i];
  __syncthreads();
  int o = tid & 127, rh = tid >> 7;
  float acc[8];
#pragma unroll
  for (int r=0;r<8;r++) acc[r]=0.f;
  for (int i=0;i<FIN_;i++){
    float wv = w[i*E_ + o];
#pragma unroll
    for (int r=0;r<8;r++) acc[r] += xl[(rh + 2*r)*FIN_ + i]*wv;
  }
  float bv = b[o];
#pragma unroll
  for (int r=0;r<8;r++) h[(size_t)(row0 + rh + 2*r)*E_ + o] = acc[r] + bv;
}

// ---------------- K2: xn=LN(h); [x_m|z] = xn @ m_up_w + b (out fp16) ----------------
__global__ __launch_bounds__(256) void k_ln_up(const float* __restrict__ h, const float* __restrict__ lnw,
     const float* __restrict__ w, const float* __restrict__ bb,
     _Float16* __restrict__ xm, _Float16* __restrict__ z){
  __shared__ float xl[8*E_];
  int row0 = blockIdx.x*8; int tid = threadIdx.x;
  for (int i=tid;i<8*E_;i+=256) xl[i] = h[(size_t)row0*E_ + i];
  __syncthreads();
  int wave = tid>>6, lane = tid&63;
  for (int rr = wave; rr < 8; rr += 4){
    float x0 = xl[rr*E_+lane], x1 = xl[rr*E_+lane+64];
    float mu = wsum(x0+x1) * (1.f/E_);
    float d0=x0-mu, d1=x1-mu;
    float var = wsum(d0*d0+d1*d1)*(1.f/E_);
    float rs = rsqrtf(var+1e-5f);
    xl[rr*E_+lane] = d0*rs*lnw[lane];
    xl[rr*E_+lane+64] = d1*rs*lnw[lane+64];
  }
  __syncthreads();
  float a0[8], a1[8];
#pragma unroll
  for (int r=0;r<8;r++){a0[r]=0.f;a1[r]=0.f;}
  int o = tid;
  for (int i=0;i<E_;i+=4){
    float w0v[4], w1v[4];
#pragma unroll
    for (int ii=0;ii<4;ii++){ w0v[ii] = w[(i+ii)*512+o]; w1v[ii]=w[(i+ii)*512+o+256]; }
#pragma unroll
    for (int r=0;r<8;r++){
      float4 xr = *(const float4*)&xl[r*E_+i];
      a0[r] += xr.x*w0v[0] + xr.y*w0v[1] + xr.z*w0v[2] + xr.w*w0v[3];
      a1[r] += xr.x*w1v[0] + xr.y*w1v[1] + xr.z*w1v[2] + xr.w*w1v[3];
    }
  }
  float b0 = bb[o], b1 = bb[o+256];
#pragma unroll
  for (int r=0;r<8;r++){
    xm[(size_t)(row0+r)*D_ + o] = (_Float16)(a0[r]+b0);
    z [(size_t)(row0+r)*D_ + o] = (_Float16)(a1[r]+b1);
  }
}

// ---------------- K3: conv+silu -> xc (fp16); ig/fg (f32) ----------------
__global__ __launch_bounds__(256) void k_conv_qkv(const _Float16* __restrict__ xm,
    const float* __restrict__ cw, const float* __restrict__ cb,
    const float* __restrict__ qw, const float* __restrict__ qb2,
    const float* __restrict__ kw, const float* __restrict__ kb2,
    const float* __restrict__ vw, const float* __restrict__ vb2,
    const float* __restrict__ igw, const float* __restrict__ igb,
    const float* __restrict__ fgw, const float* __restrict__ fgb,
    _Float16* __restrict__ xc, float* __restrict__ ig, float* __restrict__ fg){
  __shared__ float xml[4][D_];
  __shared__ float xcl[D_];
  __shared__ float part[4][8];
  int row = blockIdx.x; int b = row/S_; int s = row - b*S_;
  int c = threadIdx.x;
#pragma unroll
  for (int j=0;j<4;j++){
    int sj = s-3+j;
    xml[j][c] = (sj>=0)? (float)xm[(size_t)(row-3+j)*D_ + c] : 0.f;
  }
  __syncthreads();
  float4 wc = *(const float4*)&cw[c*4];
  float cv = cb[c] + wc.x*xml[0][c] + wc.y*xml[1][c] + wc.z*xml[2][c] + wc.w*xml[3][c];
  cv = siluf_(cv);
  xcl[c] = cv;
  xc[(size_t)row*D_ + c] = (_Float16)cv;
  int nb = c>>2, rr = c&3;
  float4 vw4 = *(const float4*)&vw[nb*16 + rr*4];
  float4 xv4 = *(const float4*)&xml[3][nb*4];
  float vv = vb2[c] + dot4(vw4, xv4);
  __syncthreads();
  float4 qw4 = *(const float4*)&qw[nb*16 + rr*4];
  float4 kw4 = *(const float4*)&kw[nb*16 + rr*4];
  float4 xc4 = *(const float4*)&xcl[nb*4];
  float qv = qb2[c] + dot4(qw4, xc4);
  float kv = kb2[c] + dot4(kw4, xc4);
  float4 wiq = *(const float4*)&igw[c*4];
  float4 wik = *(const float4*)&igw[(256+c)*4];
  float4 wiv = *(const float4*)&igw[(512+c)*4];
  float4 wfq = *(const float4*)&fgw[c*4];
  float4 wfk = *(const float4*)&fgw[(256+c)*4];
  float4 wfv = *(const float4*)&fgw[(512+c)*4];
  float p[8];
  p[0] = qv*wiq.x + kv*wik.x + vv*wiv.x;
  p[1] = qv*wiq.y + kv*wik.y + vv*wiv.y;
  p[2] = qv*wiq.z + kv*wik.z + vv*wiv.z;
  p[3] = qv*wiq.w + kv*wik.w + vv*wiv.w;
  p[4] = qv*wfq.x + kv*wfk.x + vv*wfv.x;
  p[5] = qv*wfq.y + kv*wfk.y + vv*wfv.y;
  p[6] = qv*wfq.z + kv*wfk.z + vv*wfv.z;
  p[7] = qv*wfq.w + kv*wfk.w + vv*wfv.w;
#pragma unroll
  for (int j=0;j<8;j++) p[j] = wsum(p[j]);
  int wave = c>>6, lane = c&63;
  if (lane==0){
#pragma unroll
    for (int j=0;j<8;j++) part[wave][j]=p[j];
  }
  __syncthreads();
  if (c < 8){
    float t4 = part[0][c]+part[1][c]+part[2][c]+part[3][c];
    int g = c&3;
    if (c<4) ig[(size_t)(b*4+g)*S_ + s] = t4 + igb[g];
    else     fg[(size_t)(b*4+g)*S_ + s] = t4 + fgb[g];
  }
}

// ---------------- K4: mLSTM via MFMA (flash-style) + fused LN/skip/gate epilogue ----------------
__global__ __launch_bounds__(256) void k_mlstm(_Float16* xcio,
    const _Float16* __restrict__ xm, const _Float16* __restrict__ z,
    const float* __restrict__ qw, const float* __restrict__ qb2,
    const float* __restrict__ kw, const float* __restrict__ kb2,
    const float* __restrict__ vw, const float* __restrict__ vb2,
    const float* __restrict__ ig, const float* __restrict__ fg,
    const float* __restrict__ nw, const float* __restrict__ skip){
  __shared__ __align__(16) _Float16 kt[160*72];    // k[t][d], row stride 72 halves
  __shared__ __align__(16) _Float16 vT[64*184];    // v[d][t], row stride 184 halves
  __shared__ __align__(16) _Float16 ct[4][16*40];  // per-wave coef tile 16 x 32 (stride 40)
  __shared__ float lfc[S_+1];
  __shared__ float igl[S_];
  __shared__ float mxl[S_];
  int bh = blockIdx.x; int b = bh>>2; int hh = bh&3;
  int tid = threadIdx.x; int wave = tid>>6, lane = tid&63;
  int quad = lane>>4, lm = lane&15;
  _Float16* xcg = xcio + (size_t)b*S_*D_ + hh*64;
  const _Float16* xmg = xm + (size_t)b*S_*D_ + hh*64;
  const _Float16* zg  = z  + (size_t)b*S_*D_ + hh*64;
  for (int i=tid;i<160*64;i+=256){
    int t=i>>6, d=i&63;
    float kvv=0.f, vvv=0.f;
    if (t<S_){
      int nb=d>>2, dd=d&3;
      h4_t xk = *(const h4_t*)&xcg[(size_t)t*D_+(nb<<2)];
      h4_t xv = *(const h4_t*)&xmg[(size_t)t*D_+(nb<<2)];
      float4 wk = *(const float4*)&kw[((hh*16+nb)<<4)+(dd<<2)];
      float4 wv = *(const float4*)&vw[((hh*16+nb)<<4)+(dd<<2)];
      kvv = kb2[hh*64+d]+hdot(wk,xk);
      vvv = vb2[hh*64+d]+hdot(wv,xv);
    }
    kt[t*72+d]=(_Float16)kvv;
    vT[d*184+t]=(_Float16)vvv;
  }
  if (tid<S_){ igl[tid]=ig[(size_t)bh*S_+tid]; mxl[tid]=logsigf_(fg[(size_t)bh*S_+tid]); }
  __syncthreads();
  if (tid==0){
    float run=0.f, rm=-3.0e38f;
    lfc[0]=0.f;
    for (int t=0;t<S_;t++){
      run += mxl[t];
      lfc[t+1]=run;
      float gv = igl[t]-run;
      rm = fmaxf(rm,gv);
      mxl[t] = run + rm;
    }
  }
  __syncthreads();
  float nwv[4], skv[4];
#pragma unroll
  for (int dt=0;dt<4;dt++){ nwv[dt]=nw[hh*64+dt*16+lm]; skv[dt]=skip[hh*64+dt*16+lm]; }
  _Float16* ctw = ct[wave];
  for (int qi=wave; qi<10; qi+=4){
    int s0=qi*16;
    int srow=s0+quad*4;
    int sq = s0+lm; if (sq>S_-1) sq=S_-1;
    const _Float16* xrow = &xcg[(size_t)sq*D_];
    h8_t qf0, qf1;
#pragma unroll
    for (int f=0; f<2; f++){
      int d0 = f*32 + quad*8;
      h4_t xa = *(const h4_t*)&xrow[d0];
      h4_t xb = *(const h4_t*)&xrow[d0+4];
      float4 xaf=h4f(xa), xbf=h4f(xb);
      int nb0 = (hh*16 + (d0>>2))<<4;
#pragma unroll
      for (int j=0;j<4;j++){
        float4 wr = *(const float4*)&qw[nb0 + j*4];
        float qv = qb2[hh*64+d0+j] + dot4(wr, xaf);
        if (f==0) qf0[j]=(_Float16)qv; else qf1[j]=(_Float16)qv;
      }
#pragma unroll
      for (int j=0;j<4;j++){
        float4 wr = *(const float4*)&qw[nb0 + 16 + j*4];
        float qv = qb2[hh*64+d0+4+j] + dot4(wr, xbf);
        if (f==0) qf0[4+j]=(_Float16)qv; else qf1[4+j]=(_Float16)qv;
      }
    }
    f4_t acc0={0,0,0,0},acc1={0,0,0,0},acc2={0,0,0,0},acc3={0,0,0,0};
    float rsum[4]={0.f,0.f,0.f,0.f};
    float lfs[4], mxs[4]; bool sv[4];
#pragma unroll
    for (int r=0;r<4;r++){
      int s=srow+r; sv[r]=(s<S_);
      int sc = sv[r]? s : S_-1;
      lfs[r]=lfc[sc+1]; mxs[r]=mxl[sc];
    }
    int npair=(qi+2)>>1;
    for (int tp=0; tp<npair; tp++){
#pragma unroll
      for (int half=0; half<2; half++){
        int ti=2*tp+half;
        f4_t aq={0,0,0,0};
        if (ti<=qi){
          int t0=ti*16;
          h8_t kb0=*(const h8_t*)&kt[(t0+lm)*72+quad*8];
          h8_t kb1=*(const h8_t*)&kt[(t0+lm)*72+32+quad*8];
          aq=__builtin_amdgcn_mfma_f32_16x16x32_f16(qf0,kb0,aq,0,0,0);
          aq=__builtin_amdgcn_mfma_f32_16x16x32_f16(qf1,kb1,aq,0,0,0);
        }
        int t=ti*16+lm;
        bool tv = (t<S_);
        float lfT = tv? lfc[t+1]:0.f;
        float igT = tv? igl[t]:0.f;
#pragma unroll
        for (int r=0;r<4;r++){
          float coef=0.f;
          if (tv && sv[r] && t<=srow+r){
            coef = aq[r]*0.125f*__expf(lfs[r]-lfT+igT-mxs[r]);
          }
          rsum[r]+=coef;
          ctw[(quad*4+r)*40 + half*16 + lm] = (_Float16)coef;
        }
      }
      asm volatile("s_waitcnt lgkmcnt(0)" ::: "memory");
      h8_t af=*(const h8_t*)&ctw[lm*40+quad*8];
      int tb=tp*32+quad*8;
      h8_t bv0=*(const h8_t*)&vT[(0*16+lm)*184+tb];
      h8_t bv1=*(const h8_t*)&vT[(1*16+lm)*184+tb];
      h8_t bv2=*(const h8_t*)&vT[(2*16+lm)*184+tb];
      h8_t bv3=*(const h8_t*)&vT[(3*16+lm)*184+tb];
      acc0=__builtin_amdgcn_mfma_f32_16x16x32_f16(af,bv0,acc0,0,0,0);
      acc1=__builtin_amdgcn_mfma_f32_16x16x32_f16(af,bv1,acc1,0,0,0);
      acc2=__builtin_amdgcn_mfma_f32_16x16x32_f16(af,bv2,acc2,0,0,0);
      acc3=__builtin_amdgcn_mfma_f32_16x16x32_f16(af,bv3,acc3,0,0,0);
    }
#pragma unroll
    for (int r=0;r<4;r++){
      float v_=rsum[r];
      v_+=__shfl_xor(v_,1,64); v_+=__shfl_xor(v_,2,64);
      v_+=__shfl_xor(v_,4,64); v_+=__shfl_xor(v_,8,64);
      rsum[r]=v_;
    }
    float nrm[4];
#pragma unroll
    for (int r=0;r<4;r++) nrm[r]=fmaxf(fabsf(rsum[r]), __expf(-mxs[r]))+1e-6f;
#pragma unroll
    for (int r=0;r<4;r++){
      if (!sv[r]) continue;
      int s=srow+r;
      float o0=acc0[r]/nrm[r], o1=acc1[r]/nrm[r], o2=acc2[r]/nrm[r], o3=acc3[r]/nrm[r];
      float ss=o0+o1+o2+o3;
      ss+=__shfl_xor(ss,1,64); ss+=__shfl_xor(ss,2,64); ss+=__shfl_xor(ss,4,64); ss+=__shfl_xor(ss,8,64);
      float mu=ss*(1.f/64.f);
      float d0=o0-mu,d1=o1-mu,d2=o2-mu,d3=o3-mu;
      float vv=d0*d0+d1*d1+d2*d2+d3*d3;
      vv+=__shfl_xor(vv,1,64); vv+=__shfl_xor(vv,2,64); vv+=__shfl_xor(vv,4,64); vv+=__shfl_xor(vv,8,64);
      float rs=rsqrtf(vv*(1.f/64.f)+1e-5f);
      size_t rowoff=(size_t)s*D_;
      float dd4[4]={d0,d1,d2,d3};
#pragma unroll
      for (int dt=0;dt<4;dt++){
        float hn = dd4[dt]*rs*nwv[dt];
        float xcv=(float)xcg[rowoff+dt*16+lm];
        float zv =(float)zg [rowoff+dt*16+lm];
        xcg[rowoff+dt*16+lm]=(_Float16)((hn+skv[dt]*xcv)*siluf_(zv));
      }
    }
  }
}

// ---------------- K5: h += hs @ m_down_w + b ----------------
__global__ __launch_bounds__(256) void k_down(const _Float16* __restrict__ hs, const float* __restrict__ w,
    const float* __restrict__ bb, float* __restrict__ h){
  __shared__ float hl[8*D_];
  int row0 = blockIdx.x*8; int tid = threadIdx.x;
  for (int i=tid;i<8*D_;i+=256) hl[i] = (float)hs[(size_t)row0*D_ + i];
  __syncthreads();
  int o = tid&127, rh = tid>>7;
  float acc[4]={0.f,0.f,0.f,0.f};
  for (int i=0;i<D_;i+=4){
    float wv[4];
#pragma unroll
    for (int ii=0;ii<4;ii++) wv[ii] = w[(i+ii)*E_ + o];
#pragma unroll
    for (int r=0;r<4;r++){
      float4 xv = *(const float4*)&hl[(rh+2*r)*D_ + i];
      acc[r] += xv.x*wv[0]+xv.y*wv[1]+xv.z*wv[2]+xv.w*wv[3];
    }
  }
  float bv = bb[o];
#pragma unroll
  for (int r=0;r<4;r++){
    size_t idx = (size_t)(row0+rh+2*r)*E_ + o;
    h[idx] += acc[r] + bv;
  }
}

// ---------------- K6: fused LN(h) + causal conv + silu -> xcs (fp16) ----------------
__global__ __launch_bounds__(256) void k_lnconv(const float* __restrict__ h, const float* __restrict__ lnw,
    const float* __restrict__ cw, const float* __restrict__ cb, _Float16* __restrict__ xcs){
  __shared__ float xn[19][E_];
  int b = blockIdx.x/10, chunk = blockIdx.x - b*10;
  int s0 = chunk*16;
  int tid=threadIdx.x, wave=tid>>6, lane=tid&63;
  for (int ii=wave; ii<19; ii+=4){
    int sg = s0-3+ii;
    if (sg>=0 && sg<S_){
      size_t off = (size_t)(b*S_+sg)*E_;
      float x0=h[off+lane], x1=h[off+lane+64];
      float mu=wsum(x0+x1)*(1.f/E_);
      float d0=x0-mu,d1=x1-mu;
      float var=wsum(d0*d0+d1*d1)*(1.f/E_);
      float rs=rsqrtf(var+1e-5f);
      xn[ii][lane]=d0*rs*lnw[lane];
      xn[ii][lane+64]=d1*rs*lnw[lane+64];
    } else { xn[ii][lane]=0.f; xn[ii][lane+64]=0.f; }
  }
  __syncthreads();
  int ch=tid&127, rh=tid>>7;
  float4 w4 = *(const float4*)&cw[ch*4];
  float bv = cb[ch];
  for (int r=rh; r<16; r+=2){
    int s=s0+r;
    if (s<S_){
      float acc = bv + w4.x*xn[r][ch] + w4.y*xn[r+1][ch] + w4.z*xn[r+2][ch] + w4.w*xn[r+3][ch];
      xcs[(size_t)(b*S_+s)*E_+ch] = (_Float16)siluf_(acc);
    }
  }
}

// ---------------- K7: sLSTM gates, 8 rows/block (bit-identical per-row math to r3 k_gates) ----------------
__global__ __launch_bounds__(128) void k_gates8(const _Float16* __restrict__ xcs, const float* __restrict__ h,
    const float* __restrict__ lnw, const float* __restrict__ gw,
    _Float16* __restrict__ gi, _Float16* __restrict__ gf,
    _Float16* __restrict__ gz, _Float16* __restrict__ go){
  __shared__ float xcl[E_], xnl[E_], red2[2];
  int row0 = blockIdx.x*8;
  int t = threadIdx.x;
  int hh = t>>5, o = t&31;
  const float* w0 = gw + (((0*4+hh)*32+o)<<5);
  const float* w1 = gw + (((1*4+hh)*32+o)<<5);
  const float* w2 = gw + (((2*4+hh)*32+o)<<5);
  const float* w3 = gw + (((3*4+hh)*32+o)<<5);
  float4 w0v[8], w1v[8], w2v[8], w3v[8];
#pragma unroll
  for (int d=0;d<8;d++){
    w0v[d]=*(const float4*)&w0[d*4]; w1v[d]=*(const float4*)&w1[d*4];
    w2v[d]=*(const float4*)&w2[d*4]; w3v[d]=*(const float4*)&w3[d*4];
  }
  float lnwv = lnw[t];
  for (int rr=0; rr<8; rr++){
    int row = row0+rr; int b = row/S_; int s = row - b*S_;
    float hv = h[(size_t)row*E_+t];
    float mu = bsum128(hv, red2)*(1.f/E_);
    float dd = hv-mu;
    float var = bsum128(dd*dd, red2)*(1.f/E_);
    xnl[t] = dd*rsqrtf(var+1e-5f)*lnwv;
    xcl[t] = (float)xcs[(size_t)row*E_+t];
    __syncthreads();
    float a0=0.f,a1=0.f,a2=0.f,a3=0.f;
    const float* xch = &xcl[hh*32]; const float* xnh = &xnl[hh*32];
#pragma unroll
    for (int d=0; d<8; d++){
      float4 xc4 = *(const float4*)&xch[d*4];
      float4 xn4 = *(const float4*)&xnh[d*4];
      a0 += dot4(w0v[d], xc4);
      a1 += dot4(w1v[d], xc4);
      a2 += dot4(w2v[d], xn4);
      a3 += dot4(w3v[d], xn4);
    }
    size_t oidx = ((size_t)s*B_ + b)*E_ + t;
    gi[oidx]=(_Float16)a0; gf[oidx]=(_Float16)a1; gz[oidx]=(_Float16)a2; go[oidx]=(_Float16)a3;
    __syncthreads();   // protect xnl/xcl before next row overwrites
  }
}

// ---------------- K8: sLSTM recurrent scan — one wave per (b,head), weights in registers ----------------
// bit-identical per-step math to r6: same fp16-rounded s_r, same sequential d=0..31 accumulation
__global__ __launch_bounds__(64) void k_scan(const _Float16* __restrict__ gi, const _Float16* __restrict__ gf,
    const _Float16* __restrict__ gz, const _Float16* __restrict__ go,
    const float* __restrict__ sr, const float* __restrict__ sb, float* __restrict__ yl){
  int bh = blockIdx.x; int b = bh>>2; int hh = bh&3;
  int lane = threadIdx.x; int kk = lane&31; int half = lane>>5;
  // lanes 0-31: gates (i,f); lanes 32-63: gates (z,o). 32 weights each, in VGPRs.
  int gA = half*2, gB = half*2+1;
  const float* srA = sr + (size_t)((gA*4+hh)*32)*32 + kk;
  const float* srB = sr + (size_t)((gB*4+hh)*32)*32 + kk;
  float wA[32], wB[32];
#pragma unroll
  for (int d=0; d<32; d++){
    wA[d] = (float)(_Float16)srA[d*32];   // fp16-round to match r6 LDS staging numerics
    wB[d] = (float)(_Float16)srB[d*32];
  }
  int c = hh*32 + kk;
  float sb0 = sb[c], sb1 = sb[128+c], sb2 = sb[256+c], sb3 = sb[384+c];
  float y=0.f,cst=0.f,nst=0.f,mst=-1e30f;
  size_t base0 = (size_t)b*E_ + c;
  float gc0 = (float)gi[base0], gc1 = (float)gf[base0], gc2 = (float)gz[base0], gc3 = (float)go[base0];
  for (int s=0;s<S_;s++){
    int sn = (s+1 < S_)? s+1 : s;
    size_t nidx = ((size_t)sn*B_ + b)*E_ + c;
    float n0 = (float)gi[nidx], n1 = (float)gf[nidx], n2 = (float)gz[nidx], n3 = (float)go[nidx];
    float ryA=0.f, ryB=0.f;
#pragma unroll
    for (int d=0; d<32; d++){
      float yv = __shfl(y, d, 64);    // y lives on lanes 0-31 (dup on 32-63)
      ryA += yv*wA[d];
      ryB += yv*wB[d];
    }
    // exchange: pair (lane, lane^32) swaps so every lane has all 4 gate recurrents
    float oA = __shfl_xor(ryA, 32, 64);
    float oB = __shfl_xor(ryB, 32, 64);
    float ry0 = half? oA  : ryA;
    float ry1 = half? oB  : ryB;
    float ry2 = half? ryA : oA;
    float ry3 = half? ryB : oB;
    float ir = gc0 + ry0 + sb0;
    float fr = gc1 + ry1 + sb1;
    float zr = gc2 + ry2 + sb2;
    float orr= gc3 + ry3 + sb3;
    float lfm = mst + logsigf_(fr);
    float mn = fmaxf(ir, lfm);
    float igt = expf(ir - mn);
    float fgt = expf(lfm - mn);
    cst = fgt*cst + igt*tanhf(zr);
    nst = fgt*nst + igt;
    mst = mn;
    y = sigmoidf_(orr)*cst/nst;
    gc0=n0; gc1=n1; gc2=n2; gc3=n3;
  }
  if (half==0) yl[(size_t)b*E_ + c] = y;
}

// ---------------- K9: last-position head (mhln + FFN + post-LN + fc) ----------------
__global__ __launch_bounds__(128) void k_head(const float* __restrict__ h, const float* __restrict__ yl,
   const float* __restrict__ snw, const float* __restrict__ lnffw,
   const float* __restrict__ upw, const float* __restrict__ upb,
   const float* __restrict__ dww, const float* __restrict__ dwb,
   const float* __restrict__ postw, const float* __restrict__ fcw, const float* __restrict__ fcb,
   float* __restrict__ out){
  __shared__ float ylsh[E_], xnf[E_], up[2*FF_], gg[FF_], red2[2];
  int b = blockIdx.x; int t = threadIdx.x;
  float yv = yl[(size_t)b*E_+t];
  ylsh[t] = yv;
  __syncthreads();
  int base = (t>>5)<<5;
  float mu=0.f;
  for (int d=0;d<32;d++) mu += ylsh[base+d];
  mu *= (1.f/32.f);
  float var=0.f;
  for (int d=0;d<32;d++){ float dd = ylsh[base+d]-mu; var += dd*dd; }
  var *= (1.f/32.f);
  float hn = (yv-mu)*rsqrtf(var+1e-5f)*snw[t];
  float h1 = h[((size_t)b*S_ + (S_-1))*E_ + t] + hn;
  float mu1 = bsum128(h1, red2)*(1.f/E_);
  float d1 = h1-mu1;
  float var1 = bsum128(d1*d1, red2)*(1.f/E_);
  xnf[t] = d1*rsqrtf(var1+1e-5f)*lnffw[t];
  __syncthreads();
  float u0=upb[t], u1=upb[t+128], u2=upb[t+256];
  for (int i=0;i<E_;i++){
    float x = xnf[i];
    u0 += x*upw[i*384+t];
    u1 += x*upw[i*384+t+128];
    u2 += x*upw[i*384+t+256];
  }
  up[t]=u0; up[t+128]=u1; up[t+256]=u2;
  __syncthreads();
  for (int j=t;j<FF_;j+=128){
    float gp = up[j];
    gg[j] = 0.5f*gp*(1.f+erff(gp*0.70710678118f))*up[FF_+j];
  }
  __syncthreads();
  float acc = dwb[t];
  for (int j=0;j<FF_;j++) acc += gg[j]*dww[j*E_+t];
  float h2 = h1 + acc;
  float mu2 = bsum128(h2, red2)*(1.f/E_);
  float d2 = h2-mu2;
  float var2 = bsum128(d2*d2, red2)*(1.f/E_);
  float hp = d2*rsqrtf(var2+1e-5f)*postw[t];
  float pr = bsum128(hp*fcw[t], red2);
  if (t==0) out[b] = pr + fcb[0];
}

extern "C" void kernel_launch(void* const* d_in, const int* in_sizes, int n_in,
                              void* d_out, int out_size, void* d_ws, size_t ws_size,
                              hipStream_t stream){
  const float* x        = (const float*)d_in[0];
  const float* w_in     = (const float*)d_in[1];
  const float* b_in     = (const float*)d_in[2];
  const float* ln0_w    = (const float*)d_in[3];
  const float* m_up_w   = (const float*)d_in[4];
  const float* m_up_b   = (const float*)d_in[5];
  const float* m_conv_w = (const float*)d_in[6];
  const float* m_conv_b = (const float*)d_in[7];
  const float* m_q_w    = (const float*)d_in[8];
  const float* m_q_b    = (const float*)d_in[9];
  const float* m_k_w    = (const float*)d_in[10];
  const float* m_k_b    = (const float*)d_in[11];
  const float* m_v_w    = (const float*)d_in[12];
  const float* m_v_b    = (const float*)d_in[13];
  const float* m_ig_w   = (const float*)d_in[14];
  const float* m_ig_b   = (const float*)d_in[15];
  const float* m_fg_w   = (const float*)d_in[16];
  const float* m_fg_b   = (const float*)d_in[17];
  const float* m_norm_w = (const float*)d_in[18];
  const float* m_skip   = (const float*)d_in[19];
  const float* m_down_w = (const float*)d_in[20];
  const float* m_down_b = (const float*)d_in[21];
  const float* ln1_w    = (const float*)d_in[22];
  const float* s_conv_w = (const float*)d_in[23];
  const float* s_conv_b = (const float*)d_in[24];
  const float* s_gate_w = (const float*)d_in[25];
  const float* s_r      = (const float*)d_in[26];
  const float* s_b      = (const float*)d_in[27];
  const float* s_norm_w = (const float*)d_in[28];
  const float* ln_ff_w  = (const float*)d_in[29];
  const float* ff_up_w  = (const float*)d_in[30];
  const float* ff_up_b  = (const float*)d_in[31];
  const float* ff_down_w= (const float*)d_in[32];
  const float* ff_down_b= (const float*)d_in[33];
  const float* post_w   = (const float*)d_in[34];
  const float* fc_w     = (const float*)d_in[35];
  const float* fc_b     = (const float*)d_in[36];
  float* out = (float*)d_out;
  float* wsf = (float*)d_ws;

  // workspace layout (units = f32 slots): total 40,001,536 f32 = 152.6 MiB (r3-identical)
  float*     h  = wsf;                              // (B,S,E) f32
  _Float16*  A  = (_Float16*)(wsf + 9830400);       // x_m -> xcs | gz
  _Float16*  Bz = (_Float16*)(wsf + 19660800);      // z   -> gi | gf
  _Float16*  C  = (_Float16*)(wsf + 29491200);      // xc/hs -> go
  float*     ig = wsf + 39321600;
  float*     fg = wsf + 39628800;
  float*     yl = wsf + 39936000;

  k_inproj<<<ROWS_/16, 256, 0, stream>>>(x, w_in, b_in, h);
  k_ln_up<<<ROWS_/8, 256, 0, stream>>>(h, ln0_w, m_up_w, m_up_b, A, Bz);
  k_conv_qkv<<<ROWS_, 256, 0, stream>>>(A, m_conv_w, m_conv_b, m_q_w, m_q_b, m_k_w, m_k_b,
       m_v_w, m_v_b, m_ig_w, m_ig_b, m_fg_w, m_fg_b, C, ig, fg);
  k_mlstm<<<B_*4, 256, 0, stream>>>(C, A, Bz, m_q_w, m_q_b, m_k_w, m_k_b, m_v_w, m_v_b,
       ig, fg, m_norm_w, m_skip);
  k_down<<<ROWS_/8, 256, 0, stream>>>(C, m_down_w, m_down_b, h);
  _Float16* xcs = A;
  _Float16* gz  = A + 9830400;
  _Float16* gi  = Bz;
  _Float16* gf  = Bz + 9830400;
  _Float16* go  = C;
  k_lnconv<<<B_*10, 256, 0, stream>>>(h, ln1_w, s_conv_w, s_conv_b, xcs);
  k_gates8<<<ROWS_/8, 128, 0, stream>>>(xcs, h, ln1_w, s_gate_w, gi, gf, gz, go);
  k_scan<<<B_*4, 64, 0, stream>>>(gi, gf, gz, go, s_r, s_b, yl);
  k_head<<<B_, 128, 0, stream>>>(h, yl, s_norm_w, ln_ff_w, ff_up_w, ff_up_b,
       ff_down_w, ff_down_b, post_w, fc_w, fc_b, out);
}

// Round 10
// 1316.720 us; speedup vs baseline: 2.1258x; 1.0118x over previous
//
#include <hip/hip_runtime.h>
#include <math.h>

#define B_ 512
#define S_ 150
#define FIN_ 75
#define E_ 128
#define D_ 256
#define FF_ 192
#define ROWS_ (B_*S_)

typedef _Float16 h4_t __attribute__((ext_vector_type(4)));
typedef _Float16 h8_t __attribute__((ext_vector_type(8)));
typedef float f4_t __attribute__((ext_vector_type(4)));

__device__ __forceinline__ float wsum(float v){
#pragma unroll
  for (int o=32;o;o>>=1) v += __shfl_xor(v,o,64);
  return v;
}
__device__ __forceinline__ float sigmoidf_(float x){ return 1.f/(1.f+expf(-x)); }
__device__ __forceinline__ float siluf_(float x){ return x/(1.f+expf(-x)); }
__device__ __forceinline__ float logsigf_(float x){ return fminf(x,0.f)-log1pf(expf(-fabsf(x))); }
__device__ __forceinline__ float dot4(float4 a, float4 b){ return a.x*b.x+a.y*b.y+a.z*b.z+a.w*b.w; }
__device__ __forceinline__ float hdot(float4 w, h4_t x){
  return w.x*(float)x[0] + w.y*(float)x[1] + w.z*(float)x[2] + w.w*(float)x[3];
}
__device__ __forceinline__ float4 h4f(h4_t v){
  return make_float4((float)v[0],(float)v[1],(float)v[2],(float)v[3]);
}
__device__ __forceinline__ float bsum128(float v, float* red2){
  v = wsum(v);
  __syncthreads();
  if ((threadIdx.x&63)==0) red2[threadIdx.x>>6]=v;
  __syncthreads();
  return red2[0]+red2[1];
}

// ---------------- K1: h = x @ w_in + b_in (f32 -> f32) ----------------
__global__ __launch_bounds__(256) void k_inproj(const float* __restrict__ x, const float* __restrict__ w,
    const float* __restrict__ b, float* __restrict__ h){
  __shared__ float xl[16*FIN_];
  int row0 = blockIdx.x*16;
  int tid = threadIdx.x;
  for (int i=tid;i<16*FIN_;i+=256) xl[i] = x[(size_t)row0*FIN_ + i];
  __syncthreads();
  int o = tid & 127, rh = tid >> 7;
  float acc[8];
#pragma unroll
  for (int r=0;r<8;r++) acc[r]=0.f;
  for (int i=0;i<FIN_;i++){
    float wv = w[i*E_ + o];
#pragma unroll
    for (int r=0;r<8;r++) acc[r] += xl[(rh + 2*r)*FIN_ + i]*wv;
  }
  float bv = b[o];
#pragma unroll
  for (int r=0;r<8;r++) h[(size_t)(row0 + rh + 2*r)*E_ + o] = acc[r] + bv;
}

// ---------------- K2: xn=LN(h); [x_m|z] = xn @ m_up_w + b (out fp16) ----------------
__global__ __launch_bounds__(256) void k_ln_up(const float* __restrict__ h, const float* __restrict__ lnw,
     const float* __restrict__ w, const float* __restrict__ bb,
     _Float16* __restrict__ xm, _Float16* __restrict__ z){
  __shared__ float xl[8*E_];
  int row0 = blockIdx.x*8; int tid = threadIdx.x;
  for (int i=tid;i<8*E_;i+=256) xl[i] = h[(size_t)row0*E_ + i];
  __syncthreads();
  int wave = tid>>6, lane = tid&63;
  for (int rr = wave; rr < 8; rr += 4){
    float x0 = xl[rr*E_+lane], x1 = xl[rr*E_+lane+64];
    float mu = wsum(x0+x1) * (1.f/E_);
    float d0=x0-mu, d1=x1-mu;
    float var = wsum(d0*d0+d1*d1)*(1.f/E_);
    float rs = rsqrtf(var+1e-5f);
    xl[rr*E_+lane] = d0*rs*lnw[lane];
    xl[rr*E_+lane+64] = d1*rs*lnw[lane+64];
  }
  __syncthreads();
  float a0[8], a1[8];
#pragma unroll
  for (int r=0;r<8;r++){a0[r]=0.f;a1[r]=0.f;}
  int o = tid;
  for (int i=0;i<E_;i+=4){
    float w0v[4], w1v[4];
#pragma unroll
    for (int ii=0;ii<4;ii++){ w0v[ii] = w[(i+ii)*512+o]; w1v[ii]=w[(i+ii)*512+o+256]; }
#pragma unroll
    for (int r=0;r<8;r++){
      float4 xr = *(const float4*)&xl[r*E_+i];
      a0[r] += xr.x*w0v[0] + xr.y*w0v[1] + xr.z*w0v[2] + xr.w*w0v[3];
      a1[r] += xr.x*w1v[0] + xr.y*w1v[1] + xr.z*w1v[2] + xr.w*w1v[3];
    }
  }
  float b0 = bb[o], b1 = bb[o+256];
#pragma unroll
  for (int r=0;r<8;r++){
    xm[(size_t)(row0+r)*D_ + o] = (_Float16)(a0[r]+b0);
    z [(size_t)(row0+r)*D_ + o] = (_Float16)(a1[r]+b1);
  }
}

// ---------------- K3: conv+silu -> xc (fp16); ig/fg (f32); 8 rows/block ----------------
// per-row math identical to the r3/r6/r7-passing k_conv_qkv; only blocking/staging changed
__global__ __launch_bounds__(256) void k_conv_qkv8(const _Float16* __restrict__ xm,
    const float* __restrict__ cw, const float* __restrict__ cb,
    const float* __restrict__ qw, const float* __restrict__ qb2,
    const float* __restrict__ kw, const float* __restrict__ kb2,
    const float* __restrict__ vw, const float* __restrict__ vb2,
    const float* __restrict__ igw, const float* __restrict__ igb,
    const float* __restrict__ fgw, const float* __restrict__ fgb,
    _Float16* __restrict__ xc, float* __restrict__ ig, float* __restrict__ fg){
  __shared__ float xr[12][D_];   // rows s0-3 .. s0+8 staged as f32 (same conversion point as r3)
  __shared__ float xcl[D_];
  __shared__ float part[4][8];
  int b = blockIdx.x/19, chunk = blockIdx.x - b*19;
  int s0 = chunk*8;
  int tid = threadIdx.x;
  for (int i=tid; i<12*D_; i+=256){
    int j = i>>8, c2 = i&255;
    int sg = s0-3+j;
    xr[j][c2] = (sg>=0 && sg<S_)? (float)xm[(size_t)(b*S_+sg)*D_ + c2] : 0.f;
  }
  __syncthreads();
  int c = tid;
  // loop-invariant weights, hoisted (values identical to r3's per-row loads)
  float4 wc  = *(const float4*)&cw[c*4];
  float cbv  = cb[c];
  int nb = c>>2, rr2 = c&3;
  float4 vw4 = *(const float4*)&vw[nb*16 + rr2*4];
  float4 qw4 = *(const float4*)&qw[nb*16 + rr2*4];
  float4 kw4 = *(const float4*)&kw[nb*16 + rr2*4];
  float vbv = vb2[c], qbv = qb2[c], kbv = kb2[c];
  float4 wiq = *(const float4*)&igw[c*4];
  float4 wik = *(const float4*)&igw[(256+c)*4];
  float4 wiv = *(const float4*)&igw[(512+c)*4];
  float4 wfq = *(const float4*)&fgw[c*4];
  float4 wfk = *(const float4*)&fgw[(256+c)*4];
  float4 wfv = *(const float4*)&fgw[(512+c)*4];
  int wave = c>>6, lane = c&63;
  for (int r=0; r<8; r++){
    int s = s0+r;
    if (s >= S_) break;                      // uniform across block
    size_t row = (size_t)b*S_ + s;
    float cv = cbv + wc.x*xr[r][c] + wc.y*xr[r+1][c] + wc.z*xr[r+2][c] + wc.w*xr[r+3][c];
    cv = siluf_(cv);
    xcl[c] = cv;
    xc[row*D_ + c] = (_Float16)cv;
    float4 xv4 = *(const float4*)&xr[r+3][nb*4];
    float vv = vbv + dot4(vw4, xv4);
    __syncthreads();
    float4 xc4 = *(const float4*)&xcl[nb*4];
    float qv = qbv + dot4(qw4, xc4);
    float kv = kbv + dot4(kw4, xc4);
    float p[8];
    p[0] = qv*wiq.x + kv*wik.x + vv*wiv.x;
    p[1] = qv*wiq.y + kv*wik.y + vv*wiv.y;
    p[2] = qv*wiq.z + kv*wik.z + vv*wiv.z;
    p[3] = qv*wiq.w + kv*wik.w + vv*wiv.w;
    p[4] = qv*wfq.x + kv*wfk.x + vv*wfv.x;
    p[5] = qv*wfq.y + kv*wfk.y + vv*wfv.y;
    p[6] = qv*wfq.z + kv*wfk.z + vv*wfv.z;
    p[7] = qv*wfq.w + kv*wfk.w + vv*wfv.w;
#pragma unroll
    for (int j=0;j<8;j++) p[j] = wsum(p[j]);
    if (lane==0){
#pragma unroll
      for (int j=0;j<8;j++) part[wave][j]=p[j];
    }
    __syncthreads();
    if (c < 8){
      float t4 = part[0][c]+part[1][c]+part[2][c]+part[3][c];
      int g = c&3;
      if (c<4) ig[(size_t)(b*4+g)*S_ + s] = t4 + igb[g];
      else     fg[(size_t)(b*4+g)*S_ + s] = t4 + fgb[g];
    }
    __syncthreads();   // protect xcl/part before next row
  }
}

// ---------------- K4: mLSTM via MFMA (flash-style) + fused LN/skip/gate epilogue ----------------
__global__ __launch_bounds__(256) void k_mlstm(_Float16* xcio,
    const _Float16* __restrict__ xm, const _Float16* __restrict__ z,
    const float* __restrict__ qw, const float* __restrict__ qb2,
    const float* __restrict__ kw, const float* __restrict__ kb2,
    const float* __restrict__ vw, const float* __restrict__ vb2,
    const float* __restrict__ ig, const float* __restrict__ fg,
    const float* __restrict__ nw, const float* __restrict__ skip){
  __shared__ __align__(16) _Float16 kt[160*72];    // k[t][d], row stride 72 halves
  __shared__ __align__(16) _Float16 vT[64*184];    // v[d][t], row stride 184 halves
  __shared__ __align__(16) _Float16 ct[4][16*40];  // per-wave coef tile 16 x 32 (stride 40)
  __shared__ float lfc[S_+1];
  __shared__ float igl[S_];
  __shared__ float mxl[S_];
  int bh = blockIdx.x; int b = bh>>2; int hh = bh&3;
  int tid = threadIdx.x; int wave = tid>>6, lane = tid&63;
  int quad = lane>>4, lm = lane&15;
  _Float16* xcg = xcio + (size_t)b*S_*D_ + hh*64;
  const _Float16* xmg = xm + (size_t)b*S_*D_ + hh*64;
  const _Float16* zg  = z  + (size_t)b*S_*D_ + hh*64;
  for (int i=tid;i<160*64;i+=256){
    int t=i>>6, d=i&63;
    float kvv=0.f, vvv=0.f;
    if (t<S_){
      int nb=d>>2, dd=d&3;
      h4_t xk = *(const h4_t*)&xcg[(size_t)t*D_+(nb<<2)];
      h4_t xv = *(const h4_t*)&xmg[(size_t)t*D_+(nb<<2)];
      float4 wk = *(const float4*)&kw[((hh*16+nb)<<4)+(dd<<2)];
      float4 wv = *(const float4*)&vw[((hh*16+nb)<<4)+(dd<<2)];
      kvv = kb2[hh*64+d]+hdot(wk,xk);
      vvv = vb2[hh*64+d]+hdot(wv,xv);
    }
    kt[t*72+d]=(_Float16)kvv;
    vT[d*184+t]=(_Float16)vvv;
  }
  if (tid<S_){ igl[tid]=ig[(size_t)bh*S_+tid]; mxl[tid]=logsigf_(fg[(size_t)bh*S_+tid]); }
  __syncthreads();
  if (tid==0){
    float run=0.f, rm=-3.0e38f;
    lfc[0]=0.f;
    for (int t=0;t<S_;t++){
      run += mxl[t];
      lfc[t+1]=run;
      float gv = igl[t]-run;
      rm = fmaxf(rm,gv);
      mxl[t] = run + rm;
    }
  }
  __syncthreads();
  float nwv[4], skv[4];
#pragma unroll
  for (int dt=0;dt<4;dt++){ nwv[dt]=nw[hh*64+dt*16+lm]; skv[dt]=skip[hh*64+dt*16+lm]; }
  _Float16* ctw = ct[wave];
  for (int qi=wave; qi<10; qi+=4){
    int s0=qi*16;
    int srow=s0+quad*4;
    int sq = s0+lm; if (sq>S_-1) sq=S_-1;
    const _Float16* xrow = &xcg[(size_t)sq*D_];
    h8_t qf0, qf1;
#pragma unroll
    for (int f=0; f<2; f++){
      int d0 = f*32 + quad*8;
      h4_t xa = *(const h4_t*)&xrow[d0];
      h4_t xb = *(const h4_t*)&xrow[d0+4];
      float4 xaf=h4f(xa), xbf=h4f(xb);
      int nb0 = (hh*16 + (d0>>2))<<4;
#pragma unroll
      for (int j=0;j<4;j++){
        float4 wr = *(const float4*)&qw[nb0 + j*4];
        float qv = qb2[hh*64+d0+j] + dot4(wr, xaf);
        if (f==0) qf0[j]=(_Float16)qv; else qf1[j]=(_Float16)qv;
      }
#pragma unroll
      for (int j=0;j<4;j++){
        float4 wr = *(const float4*)&qw[nb0 + 16 + j*4];
        float qv = qb2[hh*64+d0+4+j] + dot4(wr, xbf);
        if (f==0) qf0[4+j]=(_Float16)qv; else qf1[4+j]=(_Float16)qv;
      }
    }
    f4_t acc0={0,0,0,0},acc1={0,0,0,0},acc2={0,0,0,0},acc3={0,0,0,0};
    float rsum[4]={0.f,0.f,0.f,0.f};
    float lfs[4], mxs[4]; bool sv[4];
#pragma unroll
    for (int r=0;r<4;r++){
      int s=srow+r; sv[r]=(s<S_);
      int sc = sv[r]? s : S_-1;
      lfs[r]=lfc[sc+1]; mxs[r]=mxl[sc];
    }
    int npair=(qi+2)>>1;
    for (int tp=0; tp<npair; tp++){
#pragma unroll
      for (int half=0; half<2; half++){
        int ti=2*tp+half;
        f4_t aq={0,0,0,0};
        if (ti<=qi){
          int t0=ti*16;
          h8_t kb0=*(const h8_t*)&kt[(t0+lm)*72+quad*8];
          h8_t kb1=*(const h8_t*)&kt[(t0+lm)*72+32+quad*8];
          aq=__builtin_amdgcn_mfma_f32_16x16x32_f16(qf0,kb0,aq,0,0,0);
          aq=__builtin_amdgcn_mfma_f32_16x16x32_f16(qf1,kb1,aq,0,0,0);
        }
        int t=ti*16+lm;
        bool tv = (t<S_);
        float lfT = tv? lfc[t+1]:0.f;
        float igT = tv? igl[t]:0.f;
#pragma unroll
        for (int r=0;r<4;r++){
          float coef=0.f;
          if (tv && sv[r] && t<=srow+r){
            coef = aq[r]*0.125f*__expf(lfs[r]-lfT+igT-mxs[r]);
          }
          rsum[r]+=coef;
          ctw[(quad*4+r)*40 + half*16 + lm] = (_Float16)coef;
        }
      }
      asm volatile("s_waitcnt lgkmcnt(0)" ::: "memory");
      h8_t af=*(const h8_t*)&ctw[lm*40+quad*8];
      int tb=tp*32+quad*8;
      h8_t bv0=*(const h8_t*)&vT[(0*16+lm)*184+tb];
      h8_t bv1=*(const h8_t*)&vT[(1*16+lm)*184+tb];
      h8_t bv2=*(const h8_t*)&vT[(2*16+lm)*184+tb];
      h8_t bv3=*(const h8_t*)&vT[(3*16+lm)*184+tb];
      acc0=__builtin_amdgcn_mfma_f32_16x16x32_f16(af,bv0,acc0,0,0,0);
      acc1=__builtin_amdgcn_mfma_f32_16x16x32_f16(af,bv1,acc1,0,0,0);
      acc2=__builtin_amdgcn_mfma_f32_16x16x32_f16(af,bv2,acc2,0,0,0);
      acc3=__builtin_amdgcn_mfma_f32_16x16x32_f16(af,bv3,acc3,0,0,0);
    }
#pragma unroll
    for (int r=0;r<4;r++){
      float v_=rsum[r];
      v_+=__shfl_xor(v_,1,64); v_+=__shfl_xor(v_,2,64);
      v_+=__shfl_xor(v_,4,64); v_+=__shfl_xor(v_,8,64);
      rsum[r]=v_;
    }
    float nrm[4];
#pragma unroll
    for (int r=0;r<4;r++) nrm[r]=fmaxf(fabsf(rsum[r]), __expf(-mxs[r]))+1e-6f;
#pragma unroll
    for (int r=0;r<4;r++){
      if (!sv[r]) continue;
      int s=srow+r;
      float o0=acc0[r]/nrm[r], o1=acc1[r]/nrm[r], o2=acc2[r]/nrm[r], o3=acc3[r]/nrm[r];
      float ss=o0+o1+o2+o3;
      ss+=__shfl_xor(ss,1,64); ss+=__shfl_xor(ss,2,64); ss+=__shfl_xor(ss,4,64); ss+=__shfl_xor(ss,8,64);
      float mu=ss*(1.f/64.f);
      float d0=o0-mu,d1=o1-mu,d2=o2-mu,d3=o3-mu;
      float vv=d0*d0+d1*d1+d2*d2+d3*d3;
      vv+=__shfl_xor(vv,1,64); vv+=__shfl_xor(vv,2,64); vv+=__shfl_xor(vv,4,64); vv+=__shfl_xor(vv,8,64);
      float rs=rsqrtf(vv*(1.f/64.f)+1e-5f);
      size_t rowoff=(size_t)s*D_;
      float dd4[4]={d0,d1,d2,d3};
#pragma unroll
      for (int dt=0;dt<4;dt++){
        float hn = dd4[dt]*rs*nwv[dt];
        float xcv=(float)xcg[rowoff+dt*16+lm];
        float zv =(float)zg [rowoff+dt*16+lm];
        xcg[rowoff+dt*16+lm]=(_Float16)((hn+skv[dt]*xcv)*siluf_(zv));
      }
    }
  }
}

// ---------------- K5: h += hs @ m_down_w + b ----------------
__global__ __launch_bounds__(256) void k_down(const _Float16* __restrict__ hs, const float* __restrict__ w,
    const float* __restrict__ bb, float* __restrict__ h){
  __shared__ float hl[8*D_];
  int row0 = blockIdx.x*8; int tid = threadIdx.x;
  for (int i=tid;i<8*D_;i+=256) hl[i] = (float)hs[(size_t)row0*D_ + i];
  __syncthreads();
  int o = tid&127, rh = tid>>7;
  float acc[4]={0.f,0.f,0.f,0.f};
  for (int i=0;i<D_;i+=4){
    float wv[4];
#pragma unroll
    for (int ii=0;ii<4;ii++) wv[ii] = w[(i+ii)*E_ + o];
#pragma unroll
    for (int r=0;r<4;r++){
      float4 xv = *(const float4*)&hl[(rh+2*r)*D_ + i];
      acc[r] += xv.x*wv[0]+xv.y*wv[1]+xv.z*wv[2]+xv.w*wv[3];
    }
  }
  float bv = bb[o];
#pragma unroll
  for (int r=0;r<4;r++){
    size_t idx = (size_t)(row0+rh+2*r)*E_ + o;
    h[idx] += acc[r] + bv;
  }
}

// ---------------- K6: fused LN(h) + causal conv + silu -> xcs (fp16) ----------------
__global__ __launch_bounds__(256) void k_lnconv(const float* __restrict__ h, const float* __restrict__ lnw,
    const float* __restrict__ cw, const float* __restrict__ cb, _Float16* __restrict__ xcs){
  __shared__ float xn[19][E_];
  int b = blockIdx.x/10, chunk = blockIdx.x - b*10;
  int s0 = chunk*16;
  int tid=threadIdx.x, wave=tid>>6, lane=tid&63;
  for (int ii=wave; ii<19; ii+=4){
    int sg = s0-3+ii;
    if (sg>=0 && sg<S_){
      size_t off = (size_t)(b*S_+sg)*E_;
      float x0=h[off+lane], x1=h[off+lane+64];
      float mu=wsum(x0+x1)*(1.f/E_);
      float d0=x0-mu,d1=x1-mu;
      float var=wsum(d0*d0+d1*d1)*(1.f/E_);
      float rs=rsqrtf(var+1e-5f);
      xn[ii][lane]=d0*rs*lnw[lane];
      xn[ii][lane+64]=d1*rs*lnw[lane+64];
    } else { xn[ii][lane]=0.f; xn[ii][lane+64]=0.f; }
  }
  __syncthreads();
  int ch=tid&127, rh=tid>>7;
  float4 w4 = *(const float4*)&cw[ch*4];
  float bv = cb[ch];
  for (int r=rh; r<16; r+=2){
    int s=s0+r;
    if (s<S_){
      float acc = bv + w4.x*xn[r][ch] + w4.y*xn[r+1][ch] + w4.z*xn[r+2][ch] + w4.w*xn[r+3][ch];
      xcs[(size_t)(b*S_+s)*E_+ch] = (_Float16)siluf_(acc);
    }
  }
}

// ---------------- K7: sLSTM gates, 8 rows/block (bit-identical per-row math to r3 k_gates) ----------------
__global__ __launch_bounds__(128) void k_gates8(const _Float16* __restrict__ xcs, const float* __restrict__ h,
    const float* __restrict__ lnw, const float* __restrict__ gw,
    _Float16* __restrict__ gi, _Float16* __restrict__ gf,
    _Float16* __restrict__ gz, _Float16* __restrict__ go){
  __shared__ float xcl[E_], xnl[E_], red2[2];
  int row0 = blockIdx.x*8;
  int t = threadIdx.x;
  int hh = t>>5, o = t&31;
  const float* w0 = gw + (((0*4+hh)*32+o)<<5);
  const float* w1 = gw + (((1*4+hh)*32+o)<<5);
  const float* w2 = gw + (((2*4+hh)*32+o)<<5);
  const float* w3 = gw + (((3*4+hh)*32+o)<<5);
  float4 w0v[8], w1v[8], w2v[8], w3v[8];
#pragma unroll
  for (int d=0;d<8;d++){
    w0v[d]=*(const float4*)&w0[d*4]; w1v[d]=*(const float4*)&w1[d*4];
    w2v[d]=*(const float4*)&w2[d*4]; w3v[d]=*(const float4*)&w3[d*4];
  }
  float lnwv = lnw[t];
  for (int rr=0; rr<8; rr++){
    int row = row0+rr; int b = row/S_; int s = row - b*S_;
    float hv = h[(size_t)row*E_+t];
    float mu = bsum128(hv, red2)*(1.f/E_);
    float dd = hv-mu;
    float var = bsum128(dd*dd, red2)*(1.f/E_);
    xnl[t] = dd*rsqrtf(var+1e-5f)*lnwv;
    xcl[t] = (float)xcs[(size_t)row*E_+t];
    __syncthreads();
    float a0=0.f,a1=0.f,a2=0.f,a3=0.f;
    const float* xch = &xcl[hh*32]; const float* xnh = &xnl[hh*32];
#pragma unroll
    for (int d=0; d<8; d++){
      float4 xc4 = *(const float4*)&xch[d*4];
      float4 xn4 = *(const float4*)&xnh[d*4];
      a0 += dot4(w0v[d], xc4);
      a1 += dot4(w1v[d], xc4);
      a2 += dot4(w2v[d], xn4);
      a3 += dot4(w3v[d], xn4);
    }
    size_t oidx = ((size_t)s*B_ + b)*E_ + t;
    gi[oidx]=(_Float16)a0; gf[oidx]=(_Float16)a1; gz[oidx]=(_Float16)a2; go[oidx]=(_Float16)a3;
    __syncthreads();   // protect xnl/xcl before next row overwrites
  }
}

// ---------------- K8: sLSTM recurrent scan — r7-exact (passed all checks) ----------------
__global__ __launch_bounds__(64) void k_scan(const _Float16* __restrict__ gi, const _Float16* __restrict__ gf,
    const _Float16* __restrict__ gz, const _Float16* __restrict__ go,
    const float* __restrict__ sr, const float* __restrict__ sb, float* __restrict__ yl){
  int bh = blockIdx.x; int b = bh>>2; int hh = bh&3;
  int lane = threadIdx.x; int kk = lane&31; int half = lane>>5;
  // lanes 0-31: gates (i,f); lanes 32-63: gates (z,o). 32 weights each, in VGPRs.
  int gA = half*2, gB = half*2+1;
  const float* srA = sr + (size_t)((gA*4+hh)*32)*32 + kk;
  const float* srB = sr + (size_t)((gB*4+hh)*32)*32 + kk;
  float wA[32], wB[32];
#pragma unroll
  for (int d=0; d<32; d++){
    wA[d] = (float)(_Float16)srA[d*32];   // fp16-round to match r6 LDS staging numerics
    wB[d] = (float)(_Float16)srB[d*32];
  }
  int c = hh*32 + kk;
  float sb0 = sb[c], sb1 = sb[128+c], sb2 = sb[256+c], sb3 = sb[384+c];
  float y=0.f,cst=0.f,nst=0.f,mst=-1e30f;
  size_t base0 = (size_t)b*E_ + c;
  float gc0 = (float)gi[base0], gc1 = (float)gf[base0], gc2 = (float)gz[base0], gc3 = (float)go[base0];
  for (int s=0;s<S_;s++){
    int sn = (s+1 < S_)? s+1 : s;
    size_t nidx = ((size_t)sn*B_ + b)*E_ + c;
    float n0 = (float)gi[nidx], n1 = (float)gf[nidx], n2 = (float)gz[nidx], n3 = (float)go[nidx];
    float ryA=0.f, ryB=0.f;
#pragma unroll
    for (int d=0; d<32; d++){
      float yv = __shfl(y, d, 64);    // y lives on lanes 0-31 (dup on 32-63)
      ryA += yv*wA[d];
      ryB += yv*wB[d];
    }
    // exchange: pair (lane, lane^32) swaps so every lane has all 4 gate recurrents
    float oA = __shfl_xor(ryA, 32, 64);
    float oB = __shfl_xor(ryB, 32, 64);
    float ry0 = half? oA  : ryA;
    float ry1 = half? oB  : ryB;
    float ry2 = half? ryA : oA;
    float ry3 = half? ryB : oB;
    float ir = gc0 + ry0 + sb0;
    float fr = gc1 + ry1 + sb1;
    float zr = gc2 + ry2 + sb2;
    float orr= gc3 + ry3 + sb3;
    float lfm = mst + logsigf_(fr);
    float mn = fmaxf(ir, lfm);
    float igt = expf(ir - mn);
    float fgt = expf(lfm - mn);
    cst = fgt*cst + igt*tanhf(zr);
    nst = fgt*nst + igt;
    mst = mn;
    y = sigmoidf_(orr)*cst/nst;
    gc0=n0; gc1=n1; gc2=n2; gc3=n3;
  }
  if (half==0) yl[(size_t)b*E_ + c] = y;
}

// ---------------- K9: last-position head (mhln + FFN + post-LN + fc) ----------------
__global__ __launch_bounds__(128) void k_head(const float* __restrict__ h, const float* __restrict__ yl,
   const float* __restrict__ snw, const float* __restrict__ lnffw,
   const float* __restrict__ upw, const float* __restrict__ upb,
   const float* __restrict__ dww, const float* __restrict__ dwb,
   const float* __restrict__ postw, const float* __restrict__ fcw, const float* __restrict__ fcb,
   float* __restrict__ out){
  __shared__ float ylsh[E_], xnf[E_], up[2*FF_], gg[FF_], red2[2];
  int b = blockIdx.x; int t = threadIdx.x;
  float yv = yl[(size_t)b*E_+t];
  ylsh[t] = yv;
  __syncthreads();
  int base = (t>>5)<<5;
  float mu=0.f;
  for (int d=0;d<32;d++) mu += ylsh[base+d];
  mu *= (1.f/32.f);
  float var=0.f;
  for (int d=0;d<32;d++){ float dd = ylsh[base+d]-mu; var += dd*dd; }
  var *= (1.f/32.f);
  float hn = (yv-mu)*rsqrtf(var+1e-5f)*snw[t];
  float h1 = h[((size_t)b*S_ + (S_-1))*E_ + t] + hn;
  float mu1 = bsum128(h1, red2)*(1.f/E_);
  float d1 = h1-mu1;
  float var1 = bsum128(d1*d1, red2)*(1.f/E_);
  xnf[t] = d1*rsqrtf(var1+1e-5f)*lnffw[t];
  __syncthreads();
  float u0=upb[t], u1=upb[t+128], u2=upb[t+256];
  for (int i=0;i<E_;i++){
    float x = xnf[i];
    u0 += x*upw[i*384+t];
    u1 += x*upw[i*384+t+128];
    u2 += x*upw[i*384+t+256];
  }
  up[t]=u0; up[t+128]=u1; up[t+256]=u2;
  __syncthreads();
  for (int j=t;j<FF_;j+=128){
    float gp = up[j];
    gg[j] = 0.5f*gp*(1.f+erff(gp*0.70710678118f))*up[FF_+j];
  }
  __syncthreads();
  float acc = dwb[t];
  for (int j=0;j<FF_;j++) acc += gg[j]*dww[j*E_+t];
  float h2 = h1 + acc;
  float mu2 = bsum128(h2, red2)*(1.f/E_);
  float d2 = h2-mu2;
  float var2 = bsum128(d2*d2, red2)*(1.f/E_);
  float hp = d2*rsqrtf(var2+1e-5f)*postw[t];
  float pr = bsum128(hp*fcw[t], red2);
  if (t==0) out[b] = pr + fcb[0];
}

extern "C" void kernel_launch(void* const* d_in, const int* in_sizes, int n_in,
                              void* d_out, int out_size, void* d_ws, size_t ws_size,
                              hipStream_t stream){
  const float* x        = (const float*)d_in[0];
  const float* w_in     = (const float*)d_in[1];
  const float* b_in     = (const float*)d_in[2];
  const float* ln0_w    = (const float*)d_in[3];
  const float* m_up_w   = (const float*)d_in[4];
  const float* m_up_b   = (const float*)d_in[5];
  const float* m_conv_w = (const float*)d_in[6];
  const float* m_conv_b = (const float*)d_in[7];
  const float* m_q_w    = (const float*)d_in[8];
  const float* m_q_b    = (const float*)d_in[9];
  const float* m_k_w    = (const float*)d_in[10];
  const float* m_k_b    = (const float*)d_in[11];
  const float* m_v_w    = (const float*)d_in[12];
  const float* m_v_b    = (const float*)d_in[13];
  const float* m_ig_w   = (const float*)d_in[14];
  const float* m_ig_b   = (const float*)d_in[15];
  const float* m_fg_w   = (const float*)d_in[16];
  const float* m_fg_b   = (const float*)d_in[17];
  const float* m_norm_w = (const float*)d_in[18];
  const float* m_skip   = (const float*)d_in[19];
  const float* m_down_w = (const float*)d_in[20];
  const float* m_down_b = (const float*)d_in[21];
  const float* ln1_w    = (const float*)d_in[22];
  const float* s_conv_w = (const float*)d_in[23];
  const float* s_conv_b = (const float*)d_in[24];
  const float* s_gate_w = (const float*)d_in[25];
  const float* s_r      = (const float*)d_in[26];
  const float* s_b      = (const float*)d_in[27];
  const float* s_norm_w = (const float*)d_in[28];
  const float* ln_ff_w  = (const float*)d_in[29];
  const float* ff_up_w  = (const float*)d_in[30];
  const float* ff_up_b  = (const float*)d_in[31];
  const float* ff_down_w= (const float*)d_in[32];
  const float* ff_down_b= (const float*)d_in[33];
  const float* post_w   = (const float*)d_in[34];
  const float* fc_w     = (const float*)d_in[35];
  const float* fc_b     = (const float*)d_in[36];
  float* out = (float*)d_out;
  float* wsf = (float*)d_ws;

  // workspace layout (units = f32 slots): total 40,001,536 f32 = 152.6 MiB (r3-identical)
  float*     h  = wsf;                              // (B,S,E) f32
  _Float16*  A  = (_Float16*)(wsf + 9830400);       // x_m -> xcs | gz
  _Float16*  Bz = (_Float16*)(wsf + 19660800);      // z   -> gi | gf
  _Float16*  C  = (_Float16*)(wsf + 29491200);      // xc/hs -> go
  float*     ig = wsf + 39321600;
  float*     fg = wsf + 39628800;
  float*     yl = wsf + 39936000;

  k_inproj<<<ROWS_/16, 256, 0, stream>>>(x, w_in, b_in, h);
  k_ln_up<<<ROWS_/8, 256, 0, stream>>>(h, ln0_w, m_up_w, m_up_b, A, Bz);
  k_conv_qkv8<<<B_*19, 256, 0, stream>>>(A, m_conv_w, m_conv_b, m_q_w, m_q_b, m_k_w, m_k_b,
       m_v_w, m_v_b, m_ig_w, m_ig_b, m_fg_w, m_fg_b, C, ig, fg);
  k_mlstm<<<B_*4, 256, 0, stream>>>(C, A, Bz, m_q_w, m_q_b, m_k_w, m_k_b, m_v_w, m_v_b,
       ig, fg, m_norm_w, m_skip);
  k_down<<<ROWS_/8, 256, 0, stream>>>(C, m_down_w, m_down_b, h);
  _Float16* xcs = A;
  _Float16* gz  = A + 9830400;
  _Float16* gi  = Bz;
  _Float16* gf  = Bz + 9830400;
  _Float16* go  = C;
  k_lnconv<<<B_*10, 256, 0, stream>>>(h, ln1_w, s_conv_w, s_conv_b, xcs);
  k_gates8<<<ROWS_/8, 128, 0, stream>>>(xcs, h, ln1_w, s_gate_w, gi, gf, gz, go);
  k_scan<<<B_*4, 64, 0, stream>>>(gi, gf, gz, go, s_r, s_b, yl);
  k_head<<<B_, 128, 0, stream>>>(h, yl, s_norm_w, ln_ff_w, ff_up_w, ff_up_b,
       ff_down_w, ff_down_b, post_w, fc_w, fc_b, out);
}

// Round 11
// 1316.219 us; speedup vs baseline: 2.1267x; 1.0004x over previous
//
#include <hip/hip_runtime.h>
#include <math.h>

#define B_ 512
#define S_ 150
#define FIN_ 75
#define E_ 128
#define D_ 256
#define FF_ 192
#define ROWS_ (B_*S_)

typedef _Float16 h4_t __attribute__((ext_vector_type(4)));
typedef _Float16 h8_t __attribute__((ext_vector_type(8)));
typedef float f4_t __attribute__((ext_vector_type(4)));

__device__ __forceinline__ float wsum(float v){
#pragma unroll
  for (int o=32;o;o>>=1) v += __shfl_xor(v,o,64);
  return v;
}
__device__ __forceinline__ float sigmoidf_(float x){ return 1.f/(1.f+expf(-x)); }
__device__ __forceinline__ float siluf_(float x){ return x/(1.f+expf(-x)); }
__device__ __forceinline__ float logsigf_(float x){ return fminf(x,0.f)-log1pf(expf(-fabsf(x))); }
__device__ __forceinline__ float dot4(float4 a, float4 b){ return a.x*b.x+a.y*b.y+a.z*b.z+a.w*b.w; }
__device__ __forceinline__ float hdot(float4 w, h4_t x){
  return w.x*(float)x[0] + w.y*(float)x[1] + w.z*(float)x[2] + w.w*(float)x[3];
}
__device__ __forceinline__ float4 h4f(h4_t v){
  return make_float4((float)v[0],(float)v[1],(float)v[2],(float)v[3]);
}
__device__ __forceinline__ float bsum128(float v, float* red2){
  v = wsum(v);
  __syncthreads();
  if ((threadIdx.x&63)==0) red2[threadIdx.x>>6]=v;
  __syncthreads();
  return red2[0]+red2[1];
}

// ---------------- K1: h = x @ w_in + b_in (f32 -> f32) ----------------
__global__ __launch_bounds__(256) void k_inproj(const float* __restrict__ x, const float* __restrict__ w,
    const float* __restrict__ b, float* __restrict__ h){
  __shared__ float xl[16*FIN_];
  int row0 = blockIdx.x*16;
  int tid = threadIdx.x;
  for (int i=tid;i<16*FIN_;i+=256) xl[i] = x[(size_t)row0*FIN_ + i];
  __syncthreads();
  int o = tid & 127, rh = tid >> 7;
  float acc[8];
#pragma unroll
  for (int r=0;r<8;r++) acc[r]=0.f;
  for (int i=0;i<FIN_;i++){
    float wv = w[i*E_ + o];
#pragma unroll
    for (int r=0;r<8;r++) acc[r] += xl[(rh + 2*r)*FIN_ + i]*wv;
  }
  float bv = b[o];
#pragma unroll
  for (int r=0;r<8;r++) h[(size_t)(row0 + rh + 2*r)*E_ + o] = acc[r] + bv;
}

// ---------------- K2: xn=LN(h); [x_m|z] = xn @ m_up_w + b (out fp16) ----------------
__global__ __launch_bounds__(256) void k_ln_up(const float* __restrict__ h, const float* __restrict__ lnw,
     const float* __restrict__ w, const float* __restrict__ bb,
     _Float16* __restrict__ xm, _Float16* __restrict__ z){
  __shared__ float xl[8*E_];
  int row0 = blockIdx.x*8; int tid = threadIdx.x;
  for (int i=tid;i<8*E_;i+=256) xl[i] = h[(size_t)row0*E_ + i];
  __syncthreads();
  int wave = tid>>6, lane = tid&63;
  for (int rr = wave; rr < 8; rr += 4){
    float x0 = xl[rr*E_+lane], x1 = xl[rr*E_+lane+64];
    float mu = wsum(x0+x1) * (1.f/E_);
    float d0=x0-mu, d1=x1-mu;
    float var = wsum(d0*d0+d1*d1)*(1.f/E_);
    float rs = rsqrtf(var+1e-5f);
    xl[rr*E_+lane] = d0*rs*lnw[lane];
    xl[rr*E_+lane+64] = d1*rs*lnw[lane+64];
  }
  __syncthreads();
  float a0[8], a1[8];
#pragma unroll
  for (int r=0;r<8;r++){a0[r]=0.f;a1[r]=0.f;}
  int o = tid;
  for (int i=0;i<E_;i+=4){
    float w0v[4], w1v[4];
#pragma unroll
    for (int ii=0;ii<4;ii++){ w0v[ii] = w[(i+ii)*512+o]; w1v[ii]=w[(i+ii)*512+o+256]; }
#pragma unroll
    for (int r=0;r<8;r++){
      float4 xr = *(const float4*)&xl[r*E_+i];
      a0[r] += xr.x*w0v[0] + xr.y*w0v[1] + xr.z*w0v[2] + xr.w*w0v[3];
      a1[r] += xr.x*w1v[0] + xr.y*w1v[1] + xr.z*w1v[2] + xr.w*w1v[3];
    }
  }
  float b0 = bb[o], b1 = bb[o+256];
#pragma unroll
  for (int r=0;r<8;r++){
    xm[(size_t)(row0+r)*D_ + o] = (_Float16)(a0[r]+b0);
    z [(size_t)(row0+r)*D_ + o] = (_Float16)(a1[r]+b1);
  }
}

// ---------------- K3: conv+silu -> xc (fp16); ig/fg (f32); 8 rows/block ----------------
__global__ __launch_bounds__(256) void k_conv_qkv8(const _Float16* __restrict__ xm,
    const float* __restrict__ cw, const float* __restrict__ cb,
    const float* __restrict__ qw, const float* __restrict__ qb2,
    const float* __restrict__ kw, const float* __restrict__ kb2,
    const float* __restrict__ vw, const float* __restrict__ vb2,
    const float* __restrict__ igw, const float* __restrict__ igb,
    const float* __restrict__ fgw, const float* __restrict__ fgb,
    _Float16* __restrict__ xc, float* __restrict__ ig, float* __restrict__ fg){
  __shared__ float xr[12][D_];
  __shared__ float xcl[D_];
  __shared__ float part[4][8];
  int b = blockIdx.x/19, chunk = blockIdx.x - b*19;
  int s0 = chunk*8;
  int tid = threadIdx.x;
  for (int i=tid; i<12*D_; i+=256){
    int j = i>>8, c2 = i&255;
    int sg = s0-3+j;
    xr[j][c2] = (sg>=0 && sg<S_)? (float)xm[(size_t)(b*S_+sg)*D_ + c2] : 0.f;
  }
  __syncthreads();
  int c = tid;
  float4 wc  = *(const float4*)&cw[c*4];
  float cbv  = cb[c];
  int nb = c>>2, rr2 = c&3;
  float4 vw4 = *(const float4*)&vw[nb*16 + rr2*4];
  float4 qw4 = *(const float4*)&qw[nb*16 + rr2*4];
  float4 kw4 = *(const float4*)&kw[nb*16 + rr2*4];
  float vbv = vb2[c], qbv = qb2[c], kbv = kb2[c];
  float4 wiq = *(const float4*)&igw[c*4];
  float4 wik = *(const float4*)&igw[(256+c)*4];
  float4 wiv = *(const float4*)&igw[(512+c)*4];
  float4 wfq = *(const float4*)&fgw[c*4];
  float4 wfk = *(const float4*)&fgw[(256+c)*4];
  float4 wfv = *(const float4*)&fgw[(512+c)*4];
  int wave = c>>6, lane = c&63;
  for (int r=0; r<8; r++){
    int s = s0+r;
    if (s >= S_) break;
    size_t row = (size_t)b*S_ + s;
    float cv = cbv + wc.x*xr[r][c] + wc.y*xr[r+1][c] + wc.z*xr[r+2][c] + wc.w*xr[r+3][c];
    cv = siluf_(cv);
    xcl[c] = cv;
    xc[row*D_ + c] = (_Float16)cv;
    float4 xv4 = *(const float4*)&xr[r+3][nb*4];
    float vv = vbv + dot4(vw4, xv4);
    __syncthreads();
    float4 xc4 = *(const float4*)&xcl[nb*4];
    float qv = qbv + dot4(qw4, xc4);
    float kv = kbv + dot4(kw4, xc4);
    float p[8];
    p[0] = qv*wiq.x + kv*wik.x + vv*wiv.x;
    p[1] = qv*wiq.y + kv*wik.y + vv*wiv.y;
    p[2] = qv*wiq.z + kv*wik.z + vv*wiv.z;
    p[3] = qv*wiq.w + kv*wik.w + vv*wiv.w;
    p[4] = qv*wfq.x + kv*wfk.x + vv*wfv.x;
    p[5] = qv*wfq.y + kv*wfk.y + vv*wfv.y;
    p[6] = qv*wfq.z + kv*wfk.z + vv*wfv.z;
    p[7] = qv*wfq.w + kv*wfk.w + vv*wfv.w;
#pragma unroll
    for (int j=0;j<8;j++) p[j] = wsum(p[j]);
    if (lane==0){
#pragma unroll
      for (int j=0;j<8;j++) part[wave][j]=p[j];
    }
    __syncthreads();
    if (c < 8){
      float t4 = part[0][c]+part[1][c]+part[2][c]+part[3][c];
      int g = c&3;
      if (c<4) ig[(size_t)(b*4+g)*S_ + s] = t4 + igb[g];
      else     fg[(size_t)(b*4+g)*S_ + s] = t4 + fgb[g];
    }
    __syncthreads();
  }
}

// ---------------- K4: mLSTM via MFMA (flash-style) + fused LN/skip/gate epilogue ----------------
__global__ __launch_bounds__(256) void k_mlstm(_Float16* xcio,
    const _Float16* __restrict__ xm, const _Float16* __restrict__ z,
    const float* __restrict__ qw, const float* __restrict__ qb2,
    const float* __restrict__ kw, const float* __restrict__ kb2,
    const float* __restrict__ vw, const float* __restrict__ vb2,
    const float* __restrict__ ig, const float* __restrict__ fg,
    const float* __restrict__ nw, const float* __restrict__ skip){
  __shared__ __align__(16) _Float16 kt[160*72];    // k[t][d], row stride 72 halves
  __shared__ __align__(16) _Float16 vT[64*184];    // v[d][t], row stride 184 halves
  __shared__ __align__(16) _Float16 ct[4][16*40];  // per-wave coef tile 16 x 32 (stride 40)
  __shared__ float lfc[S_+1];
  __shared__ float igl[S_];
  __shared__ float mxl[S_];
  int bh = blockIdx.x; int b = bh>>2; int hh = bh&3;
  int tid = threadIdx.x; int wave = tid>>6, lane = tid&63;
  int quad = lane>>4, lm = lane&15;
  _Float16* xcg = xcio + (size_t)b*S_*D_ + hh*64;
  const _Float16* xmg = xm + (size_t)b*S_*D_ + hh*64;
  const _Float16* zg  = z  + (size_t)b*S_*D_ + hh*64;
  for (int i=tid;i<160*64;i+=256){
    int t=i>>6, d=i&63;
    float kvv=0.f, vvv=0.f;
    if (t<S_){
      int nb=d>>2, dd=d&3;
      h4_t xk = *(const h4_t*)&xcg[(size_t)t*D_+(nb<<2)];
      h4_t xv = *(const h4_t*)&xmg[(size_t)t*D_+(nb<<2)];
      float4 wk = *(const float4*)&kw[((hh*16+nb)<<4)+(dd<<2)];
      float4 wv = *(const float4*)&vw[((hh*16+nb)<<4)+(dd<<2)];
      kvv = kb2[hh*64+d]+hdot(wk,xk);
      vvv = vb2[hh*64+d]+hdot(wv,xv);
    }
    kt[t*72+d]=(_Float16)kvv;
    vT[d*184+t]=(_Float16)vvv;
  }
  if (tid<S_){ igl[tid]=ig[(size_t)bh*S_+tid]; mxl[tid]=logsigf_(fg[(size_t)bh*S_+tid]); }
  __syncthreads();
  if (tid==0){
    float run=0.f, rm=-3.0e38f;
    lfc[0]=0.f;
    for (int t=0;t<S_;t++){
      run += mxl[t];
      lfc[t+1]=run;
      float gv = igl[t]-run;
      rm = fmaxf(rm,gv);
      mxl[t] = run + rm;
    }
  }
  __syncthreads();
  float nwv[4], skv[4];
#pragma unroll
  for (int dt=0;dt<4;dt++){ nwv[dt]=nw[hh*64+dt*16+lm]; skv[dt]=skip[hh*64+dt*16+lm]; }
  _Float16* ctw = ct[wave];
  for (int qi=wave; qi<10; qi+=4){
    int s0=qi*16;
    int srow=s0+quad*4;
    int sq = s0+lm; if (sq>S_-1) sq=S_-1;
    const _Float16* xrow = &xcg[(size_t)sq*D_];
    h8_t qf0, qf1;
#pragma unroll
    for (int f=0; f<2; f++){
      int d0 = f*32 + quad*8;
      h4_t xa = *(const h4_t*)&xrow[d0];
      h4_t xb = *(const h4_t*)&xrow[d0+4];
      float4 xaf=h4f(xa), xbf=h4f(xb);
      int nb0 = (hh*16 + (d0>>2))<<4;
#pragma unroll
      for (int j=0;j<4;j++){
        float4 wr = *(const float4*)&qw[nb0 + j*4];
        float qv = qb2[hh*64+d0+j] + dot4(wr, xaf);
        if (f==0) qf0[j]=(_Float16)qv; else qf1[j]=(_Float16)qv;
      }
#pragma unroll
      for (int j=0;j<4;j++){
        float4 wr = *(const float4*)&qw[nb0 + 16 + j*4];
        float qv = qb2[hh*64+d0+4+j] + dot4(wr, xbf);
        if (f==0) qf0[4+j]=(_Float16)qv; else qf1[4+j]=(_Float16)qv;
      }
    }
    f4_t acc0={0,0,0,0},acc1={0,0,0,0},acc2={0,0,0,0},acc3={0,0,0,0};
    float rsum[4]={0.f,0.f,0.f,0.f};
    float lfs[4], mxs[4]; bool sv[4];
#pragma unroll
    for (int r=0;r<4;r++){
      int s=srow+r; sv[r]=(s<S_);
      int sc = sv[r]? s : S_-1;
      lfs[r]=lfc[sc+1]; mxs[r]=mxl[sc];
    }
    int npair=(qi+2)>>1;
    for (int tp=0; tp<npair; tp++){
#pragma unroll
      for (int half=0; half<2; half++){
        int ti=2*tp+half;
        f4_t aq={0,0,0,0};
        if (ti<=qi){
          int t0=ti*16;
          h8_t kb0=*(const h8_t*)&kt[(t0+lm)*72+quad*8];
          h8_t kb1=*(const h8_t*)&kt[(t0+lm)*72+32+quad*8];
          aq=__builtin_amdgcn_mfma_f32_16x16x32_f16(qf0,kb0,aq,0,0,0);
          aq=__builtin_amdgcn_mfma_f32_16x16x32_f16(qf1,kb1,aq,0,0,0);
        }
        int t=ti*16+lm;
        bool tv = (t<S_);
        float lfT = tv? lfc[t+1]:0.f;
        float igT = tv? igl[t]:0.f;
#pragma unroll
        for (int r=0;r<4;r++){
          float coef=0.f;
          if (tv && sv[r] && t<=srow+r){
            coef = aq[r]*0.125f*__expf(lfs[r]-lfT+igT-mxs[r]);
          }
          rsum[r]+=coef;
          ctw[(quad*4+r)*40 + half*16 + lm] = (_Float16)coef;
        }
      }
      asm volatile("s_waitcnt lgkmcnt(0)" ::: "memory");
      h8_t af=*(const h8_t*)&ctw[lm*40+quad*8];
      int tb=tp*32+quad*8;
      h8_t bv0=*(const h8_t*)&vT[(0*16+lm)*184+tb];
      h8_t bv1=*(const h8_t*)&vT[(1*16+lm)*184+tb];
      h8_t bv2=*(const h8_t*)&vT[(2*16+lm)*184+tb];
      h8_t bv3=*(const h8_t*)&vT[(3*16+lm)*184+tb];
      acc0=__builtin_amdgcn_mfma_f32_16x16x32_f16(af,bv0,acc0,0,0,0);
      acc1=__builtin_amdgcn_mfma_f32_16x16x32_f16(af,bv1,acc1,0,0,0);
      acc2=__builtin_amdgcn_mfma_f32_16x16x32_f16(af,bv2,acc2,0,0,0);
      acc3=__builtin_amdgcn_mfma_f32_16x16x32_f16(af,bv3,acc3,0,0,0);
    }
#pragma unroll
    for (int r=0;r<4;r++){
      float v_=rsum[r];
      v_+=__shfl_xor(v_,1,64); v_+=__shfl_xor(v_,2,64);
      v_+=__shfl_xor(v_,4,64); v_+=__shfl_xor(v_,8,64);
      rsum[r]=v_;
    }
    float nrm[4];
#pragma unroll
    for (int r=0;r<4;r++) nrm[r]=fmaxf(fabsf(rsum[r]), __expf(-mxs[r]))+1e-6f;
#pragma unroll
    for (int r=0;r<4;r++){
      if (!sv[r]) continue;
      int s=srow+r;
      float o0=acc0[r]/nrm[r], o1=acc1[r]/nrm[r], o2=acc2[r]/nrm[r], o3=acc3[r]/nrm[r];
      float ss=o0+o1+o2+o3;
      ss+=__shfl_xor(ss,1,64); ss+=__shfl_xor(ss,2,64); ss+=__shfl_xor(ss,4,64); ss+=__shfl_xor(ss,8,64);
      float mu=ss*(1.f/64.f);
      float d0=o0-mu,d1=o1-mu,d2=o2-mu,d3=o3-mu;
      float vv=d0*d0+d1*d1+d2*d2+d3*d3;
      vv+=__shfl_xor(vv,1,64); vv+=__shfl_xor(vv,2,64); vv+=__shfl_xor(vv,4,64); vv+=__shfl_xor(vv,8,64);
      float rs=rsqrtf(vv*(1.f/64.f)+1e-5f);
      size_t rowoff=(size_t)s*D_;
      float dd4[4]={d0,d1,d2,d3};
#pragma unroll
      for (int dt=0;dt<4;dt++){
        float hn = dd4[dt]*rs*nwv[dt];
        float xcv=(float)xcg[rowoff+dt*16+lm];
        float zv =(float)zg [rowoff+dt*16+lm];
        xcg[rowoff+dt*16+lm]=(_Float16)((hn+skv[dt]*xcv)*siluf_(zv));
      }
    }
  }
}

// ---------------- K5: h += hs @ m_down_w + b ----------------
__global__ __launch_bounds__(256) void k_down(const _Float16* __restrict__ hs, const float* __restrict__ w,
    const float* __restrict__ bb, float* __restrict__ h){
  __shared__ float hl[8*D_];
  int row0 = blockIdx.x*8; int tid = threadIdx.x;
  for (int i=tid;i<8*D_;i+=256) hl[i] = (float)hs[(size_t)row0*D_ + i];
  __syncthreads();
  int o = tid&127, rh = tid>>7;
  float acc[4]={0.f,0.f,0.f,0.f};
  for (int i=0;i<D_;i+=4){
    float wv[4];
#pragma unroll
    for (int ii=0;ii<4;ii++) wv[ii] = w[(i+ii)*E_ + o];
#pragma unroll
    for (int r=0;r<4;r++){
      float4 xv = *(const float4*)&hl[(rh+2*r)*D_ + i];
      acc[r] += xv.x*wv[0]+xv.y*wv[1]+xv.z*wv[2]+xv.w*wv[3];
    }
  }
  float bv = bb[o];
#pragma unroll
  for (int r=0;r<4;r++){
    size_t idx = (size_t)(row0+rh+2*r)*E_ + o;
    h[idx] += acc[r] + bv;
  }
}

// ---------------- K6: fused LN(h) + causal conv + silu -> xcs (fp16) ----------------
__global__ __launch_bounds__(256) void k_lnconv(const float* __restrict__ h, const float* __restrict__ lnw,
    const float* __restrict__ cw, const float* __restrict__ cb, _Float16* __restrict__ xcs){
  __shared__ float xn[19][E_];
  int b = blockIdx.x/10, chunk = blockIdx.x - b*10;
  int s0 = chunk*16;
  int tid=threadIdx.x, wave=tid>>6, lane=tid&63;
  for (int ii=wave; ii<19; ii+=4){
    int sg = s0-3+ii;
    if (sg>=0 && sg<S_){
      size_t off = (size_t)(b*S_+sg)*E_;
      float x0=h[off+lane], x1=h[off+lane+64];
      float mu=wsum(x0+x1)*(1.f/E_);
      float d0=x0-mu,d1=x1-mu;
      float var=wsum(d0*d0+d1*d1)*(1.f/E_);
      float rs=rsqrtf(var+1e-5f);
      xn[ii][lane]=d0*rs*lnw[lane];
      xn[ii][lane+64]=d1*rs*lnw[lane+64];
    } else { xn[ii][lane]=0.f; xn[ii][lane+64]=0.f; }
  }
  __syncthreads();
  int ch=tid&127, rh=tid>>7;
  float4 w4 = *(const float4*)&cw[ch*4];
  float bv = cb[ch];
  for (int r=rh; r<16; r+=2){
    int s=s0+r;
    if (s<S_){
      float acc = bv + w4.x*xn[r][ch] + w4.y*xn[r+1][ch] + w4.z*xn[r+2][ch] + w4.w*xn[r+3][ch];
      xcs[(size_t)(b*S_+s)*E_+ch] = (_Float16)siluf_(acc);
    }
  }
}

// ---------------- K7: sLSTM gates, 8 rows/block (bit-identical per-row math to r3 k_gates) ----------------
__global__ __launch_bounds__(128) void k_gates8(const _Float16* __restrict__ xcs, const float* __restrict__ h,
    const float* __restrict__ lnw, const float* __restrict__ gw,
    _Float16* __restrict__ gi, _Float16* __restrict__ gf,
    _Float16* __restrict__ gz, _Float16* __restrict__ go){
  __shared__ float xcl[E_], xnl[E_], red2[2];
  int row0 = blockIdx.x*8;
  int t = threadIdx.x;
  int hh = t>>5, o = t&31;
  const float* w0 = gw + (((0*4+hh)*32+o)<<5);
  const float* w1 = gw + (((1*4+hh)*32+o)<<5);
  const float* w2 = gw + (((2*4+hh)*32+o)<<5);
  const float* w3 = gw + (((3*4+hh)*32+o)<<5);
  float4 w0v[8], w1v[8], w2v[8], w3v[8];
#pragma unroll
  for (int d=0;d<8;d++){
    w0v[d]=*(const float4*)&w0[d*4]; w1v[d]=*(const float4*)&w1[d*4];
    w2v[d]=*(const float4*)&w2[d*4]; w3v[d]=*(const float4*)&w3[d*4];
  }
  float lnwv = lnw[t];
  for (int rr=0; rr<8; rr++){
    int row = row0+rr; int b = row/S_; int s = row - b*S_;
    float hv = h[(size_t)row*E_+t];
    float mu = bsum128(hv, red2)*(1.f/E_);
    float dd = hv-mu;
    float var = bsum128(dd*dd, red2)*(1.f/E_);
    xnl[t] = dd*rsqrtf(var+1e-5f)*lnwv;
    xcl[t] = (float)xcs[(size_t)row*E_+t];
    __syncthreads();
    float a0=0.f,a1=0.f,a2=0.f,a3=0.f;
    const float* xch = &xcl[hh*32]; const float* xnh = &xnl[hh*32];
#pragma unroll
    for (int d=0; d<8; d++){
      float4 xc4 = *(const float4*)&xch[d*4];
      float4 xn4 = *(const float4*)&xnh[d*4];
      a0 += dot4(w0v[d], xc4);
      a1 += dot4(w1v[d], xc4);
      a2 += dot4(w2v[d], xn4);
      a3 += dot4(w3v[d], xn4);
    }
    size_t oidx = ((size_t)s*B_ + b)*E_ + t;
    gi[oidx]=(_Float16)a0; gf[oidx]=(_Float16)a1; gz[oidx]=(_Float16)a2; go[oidx]=(_Float16)a3;
    __syncthreads();   // protect xnl/xcl before next row overwrites
  }
}

// ---------------- K8: sLSTM recurrent scan — r7 structure; weights packed fp16 in VGPRs ----------------
// value-identical to r7/r10: wA[d] was (float)(_Float16)sr[...]; here the fp16 is stored
// and widened at use — same float value, half the register footprint (32 vs 64 VGPRs)
__global__ __launch_bounds__(64) void k_scan(const _Float16* __restrict__ gi, const _Float16* __restrict__ gf,
    const _Float16* __restrict__ gz, const _Float16* __restrict__ go,
    const float* __restrict__ sr, const float* __restrict__ sb, float* __restrict__ yl){
  int bh = blockIdx.x; int b = bh>>2; int hh = bh&3;
  int lane = threadIdx.x; int kk = lane&31; int half = lane>>5;
  int gA = half*2, gB = half*2+1;
  const float* srA = sr + (size_t)((gA*4+hh)*32)*32 + kk;
  const float* srB = sr + (size_t)((gB*4+hh)*32)*32 + kk;
  h4_t wAh[8], wBh[8];
#pragma unroll
  for (int d8=0; d8<8; d8++){
    h4_t a, bb_;
#pragma unroll
    for (int j=0;j<4;j++){
      a[j]   = (_Float16)srA[(d8*4+j)*32];
      bb_[j] = (_Float16)srB[(d8*4+j)*32];
    }
    wAh[d8]=a; wBh[d8]=bb_;
  }
  int c = hh*32 + kk;
  float sb0 = sb[c], sb1 = sb[128+c], sb2 = sb[256+c], sb3 = sb[384+c];
  float y=0.f,cst=0.f,nst=0.f,mst=-1e30f;
  size_t base0 = (size_t)b*E_ + c;
  float gc0 = (float)gi[base0], gc1 = (float)gf[base0], gc2 = (float)gz[base0], gc3 = (float)go[base0];
  for (int s=0;s<S_;s++){
    int sn = (s+1 < S_)? s+1 : s;
    size_t nidx = ((size_t)sn*B_ + b)*E_ + c;
    float n0 = (float)gi[nidx], n1 = (float)gf[nidx], n2 = (float)gz[nidx], n3 = (float)go[nidx];
    float ryA=0.f, ryB=0.f;
#pragma unroll
    for (int d=0; d<32; d++){
      float yv = __shfl(y, d, 64);    // y lives on lanes 0-31 (dup on 32-63)
      ryA += yv*(float)wAh[d>>2][d&3];
      ryB += yv*(float)wBh[d>>2][d&3];
    }
    float oA = __shfl_xor(ryA, 32, 64);
    float oB = __shfl_xor(ryB, 32, 64);
    float ry0 = half? oA  : ryA;
    float ry1 = half? oB  : ryB;
    float ry2 = half? ryA : oA;
    float ry3 = half? ryB : oB;
    float ir = gc0 + ry0 + sb0;
    float fr = gc1 + ry1 + sb1;
    float zr = gc2 + ry2 + sb2;
    float orr= gc3 + ry3 + sb3;
    float lfm = mst + logsigf_(fr);
    float mn = fmaxf(ir, lfm);
    float igt = expf(ir - mn);
    float fgt = expf(lfm - mn);
    cst = fgt*cst + igt*tanhf(zr);
    nst = fgt*nst + igt;
    mst = mn;
    y = sigmoidf_(orr)*cst/nst;
    gc0=n0; gc1=n1; gc2=n2; gc3=n3;
  }
  if (half==0) yl[(size_t)b*E_ + c] = y;
}

// ---------------- K9: last-position head (mhln + FFN + post-LN + fc) ----------------
__global__ __launch_bounds__(128) void k_head(const float* __restrict__ h, const float* __restrict__ yl,
   const float* __restrict__ snw, const float* __restrict__ lnffw,
   const float* __restrict__ upw, const float* __restrict__ upb,
   const float* __restrict__ dww, const float* __restrict__ dwb,
   const float* __restrict__ postw, const float* __restrict__ fcw, const float* __restrict__ fcb,
   float* __restrict__ out){
  __shared__ float ylsh[E_], xnf[E_], up[2*FF_], gg[FF_], red2[2];
  int b = blockIdx.x; int t = threadIdx.x;
  float yv = yl[(size_t)b*E_+t];
  ylsh[t] = yv;
  __syncthreads();
  int base = (t>>5)<<5;
  float mu=0.f;
  for (int d=0;d<32;d++) mu += ylsh[base+d];
  mu *= (1.f/32.f);
  float var=0.f;
  for (int d=0;d<32;d++){ float dd = ylsh[base+d]-mu; var += dd*dd; }
  var *= (1.f/32.f);
  float hn = (yv-mu)*rsqrtf(var+1e-5f)*snw[t];
  float h1 = h[((size_t)b*S_ + (S_-1))*E_ + t] + hn;
  float mu1 = bsum128(h1, red2)*(1.f/E_);
  float d1 = h1-mu1;
  float var1 = bsum128(d1*d1, red2)*(1.f/E_);
  xnf[t] = d1*rsqrtf(var1+1e-5f)*lnffw[t];
  __syncthreads();
  float u0=upb[t], u1=upb[t+128], u2=upb[t+256];
  for (int i=0;i<E_;i++){
    float x = xnf[i];
    u0 += x*upw[i*384+t];
    u1 += x*upw[i*384+t+128];
    u2 += x*upw[i*384+t+256];
  }
  up[t]=u0; up[t+128]=u1; up[t+256]=u2;
  __syncthreads();
  for (int j=t;j<FF_;j+=128){
    float gp = up[j];
    gg[j] = 0.5f*gp*(1.f+erff(gp*0.70710678118f))*up[FF_+j];
  }
  __syncthreads();
  float acc = dwb[t];
  for (int j=0;j<FF_;j++) acc += gg[j]*dww[j*E_+t];
  float h2 = h1 + acc;
  float mu2 = bsum128(h2, red2)*(1.f/E_);
  float d2 = h2-mu2;
  float var2 = bsum128(d2*d2, red2)*(1.f/E_);
  float hp = d2*rsqrtf(var2+1e-5f)*postw[t];
  float pr = bsum128(hp*fcw[t], red2);
  if (t==0) out[b] = pr + fcb[0];
}

extern "C" void kernel_launch(void* const* d_in, const int* in_sizes, int n_in,
                              void* d_out, int out_size, void* d_ws, size_t ws_size,
                              hipStream_t stream){
  const float* x        = (const float*)d_in[0];
  const float* w_in     = (const float*)d_in[1];
  const float* b_in     = (const float*)d_in[2];
  const float* ln0_w    = (const float*)d_in[3];
  const float* m_up_w   = (const float*)d_in[4];
  const float* m_up_b   = (const float*)d_in[5];
  const float* m_conv_w = (const float*)d_in[6];
  const float* m_conv_b = (const float*)d_in[7];
  const float* m_q_w    = (const float*)d_in[8];
  const float* m_q_b    = (const float*)d_in[9];
  const float* m_k_w    = (const float*)d_in[10];
  const float* m_k_b    = (const float*)d_in[11];
  const float* m_v_w    = (const float*)d_in[12];
  const float* m_v_b    = (const float*)d_in[13];
  const float* m_ig_w   = (const float*)d_in[14];
  const float* m_ig_b   = (const float*)d_in[15];
  const float* m_fg_w   = (const float*)d_in[16];
  const float* m_fg_b   = (const float*)d_in[17];
  const float* m_norm_w = (const float*)d_in[18];
  const float* m_skip   = (const float*)d_in[19];
  const float* m_down_w = (const float*)d_in[20];
  const float* m_down_b = (const float*)d_in[21];
  const float* ln1_w    = (const float*)d_in[22];
  const float* s_conv_w = (const float*)d_in[23];
  const float* s_conv_b = (const float*)d_in[24];
  const float* s_gate_w = (const float*)d_in[25];
  const float* s_r      = (const float*)d_in[26];
  const float* s_b      = (const float*)d_in[27];
  const float* s_norm_w = (const float*)d_in[28];
  const float* ln_ff_w  = (const float*)d_in[29];
  const float* ff_up_w  = (const float*)d_in[30];
  const float* ff_up_b  = (const float*)d_in[31];
  const float* ff_down_w= (const float*)d_in[32];
  const float* ff_down_b= (const float*)d_in[33];
  const float* post_w   = (const float*)d_in[34];
  const float* fc_w     = (const float*)d_in[35];
  const float* fc_b     = (const float*)d_in[36];
  float* out = (float*)d_out;
  float* wsf = (float*)d_ws;

  // workspace layout (units = f32 slots): total 40,001,536 f32 = 152.6 MiB (r3-identical)
  float*     h  = wsf;                              // (B,S,E) f32
  _Float16*  A  = (_Float16*)(wsf + 9830400);       // x_m -> xcs | gz
  _Float16*  Bz = (_Float16*)(wsf + 19660800);      // z   -> gi | gf
  _Float16*  C  = (_Float16*)(wsf + 29491200);      // xc/hs -> go
  float*     ig = wsf + 39321600;
  float*     fg = wsf + 39628800;
  float*     yl = wsf + 39936000;

  k_inproj<<<ROWS_/16, 256, 0, stream>>>(x, w_in, b_in, h);
  k_ln_up<<<ROWS_/8, 256, 0, stream>>>(h, ln0_w, m_up_w, m_up_b, A, Bz);
  k_conv_qkv8<<<B_*19, 256, 0, stream>>>(A, m_conv_w, m_conv_b, m_q_w, m_q_b, m_k_w, m_k_b,
       m_v_w, m_v_b, m_ig_w, m_ig_b, m_fg_w, m_fg_b, C, ig, fg);
  k_mlstm<<<B_*4, 256, 0, stream>>>(C, A, Bz, m_q_w, m_q_b, m_k_w, m_k_b, m_v_w, m_v_b,
       ig, fg, m_norm_w, m_skip);
  k_down<<<ROWS_/8, 256, 0, stream>>>(C, m_down_w, m_down_b, h);
  _Float16* xcs = A;
  _Float16* gz  = A + 9830400;
  _Float16* gi  = Bz;
  _Float16* gf  = Bz + 9830400;
  _Float16* go  = C;
  k_lnconv<<<B_*10, 256, 0, stream>>>(h, ln1_w, s_conv_w, s_conv_b, xcs);
  k_gates8<<<ROWS_/8, 128, 0, stream>>>(xcs, h, ln1_w, s_gate_w, gi, gf, gz, go);
  k_scan<<<B_*4, 64, 0, stream>>>(gi, gf, gz, go, s_r, s_b, yl);
  k_head<<<B_, 128, 0, stream>>>(h, yl, s_norm_w, ln_ff_w, ff_up_w, ff_up_b,
       ff_down_w, ff_down_b, post_w, fc_w, fc_b, out);
}

// Round 12
// 1264.445 us; speedup vs baseline: 2.2137x; 1.0409x over previous
//
#include <hip/hip_runtime.h>
#include <math.h>

#define B_ 512
#define S_ 150
#define FIN_ 75
#define E_ 128
#define D_ 256
#define FF_ 192
#define ROWS_ (B_*S_)

typedef _Float16 h4_t __attribute__((ext_vector_type(4)));
typedef _Float16 h8_t __attribute__((ext_vector_type(8)));
typedef float f4_t __attribute__((ext_vector_type(4)));

__device__ __forceinline__ float wsum(float v){
#pragma unroll
  for (int o=32;o;o>>=1) v += __shfl_xor(v,o,64);
  return v;
}
__device__ __forceinline__ float sigmoidf_(float x){ return 1.f/(1.f+expf(-x)); }
__device__ __forceinline__ float siluf_(float x){ return x/(1.f+expf(-x)); }
__device__ __forceinline__ float logsigf_(float x){ return fminf(x,0.f)-log1pf(expf(-fabsf(x))); }
__device__ __forceinline__ float dot4(float4 a, float4 b){ return a.x*b.x+a.y*b.y+a.z*b.z+a.w*b.w; }
__device__ __forceinline__ float hdot(float4 w, h4_t x){
  return w.x*(float)x[0] + w.y*(float)x[1] + w.z*(float)x[2] + w.w*(float)x[3];
}
__device__ __forceinline__ float4 h4f(h4_t v){
  return make_float4((float)v[0],(float)v[1],(float)v[2],(float)v[3]);
}
__device__ __forceinline__ float bsum128(float v, float* red2){
  v = wsum(v);
  __syncthreads();
  if ((threadIdx.x&63)==0) red2[threadIdx.x>>6]=v;
  __syncthreads();
  return red2[0]+red2[1];
}

// ---------------- K1: h = x @ w_in + b_in (f32 -> f32) ----------------
__global__ __launch_bounds__(256) void k_inproj(const float* __restrict__ x, const float* __restrict__ w,
    const float* __restrict__ b, float* __restrict__ h){
  __shared__ float xl[16*FIN_];
  int row0 = blockIdx.x*16;
  int tid = threadIdx.x;
  for (int i=tid;i<16*FIN_;i+=256) xl[i] = x[(size_t)row0*FIN_ + i];
  __syncthreads();
  int o = tid & 127, rh = tid >> 7;
  float acc[8];
#pragma unroll
  for (int r=0;r<8;r++) acc[r]=0.f;
  for (int i=0;i<FIN_;i++){
    float wv = w[i*E_ + o];
#pragma unroll
    for (int r=0;r<8;r++) acc[r] += xl[(rh + 2*r)*FIN_ + i]*wv;
  }
  float bv = b[o];
#pragma unroll
  for (int r=0;r<8;r++) h[(size_t)(row0 + rh + 2*r)*E_ + o] = acc[r] + bv;
}

// ---------------- K2: xn=LN(h); [x_m|z] = xn @ m_up_w + b (out fp16); 16 rows/block ----------------
// per-row math bit-identical to the 8-row version (same wave-LN order, same i-loop)
__global__ __launch_bounds__(256) void k_ln_up(const float* __restrict__ h, const float* __restrict__ lnw,
     const float* __restrict__ w, const float* __restrict__ bb,
     _Float16* __restrict__ xm, _Float16* __restrict__ z){
  __shared__ float xl[16*E_];
  int row0 = blockIdx.x*16; int tid = threadIdx.x;
  for (int i=tid;i<16*E_;i+=256) xl[i] = h[(size_t)row0*E_ + i];
  __syncthreads();
  int wave = tid>>6, lane = tid&63;
  for (int rr = wave; rr < 16; rr += 4){
    float x0 = xl[rr*E_+lane], x1 = xl[rr*E_+lane+64];
    float mu = wsum(x0+x1) * (1.f/E_);
    float d0=x0-mu, d1=x1-mu;
    float var = wsum(d0*d0+d1*d1)*(1.f/E_);
    float rs = rsqrtf(var+1e-5f);
    xl[rr*E_+lane] = d0*rs*lnw[lane];
    xl[rr*E_+lane+64] = d1*rs*lnw[lane+64];
  }
  __syncthreads();
  float a0[16], a1[16];
#pragma unroll
  for (int r=0;r<16;r++){a0[r]=0.f;a1[r]=0.f;}
  int o = tid;
  for (int i=0;i<E_;i+=4){
    float w0v[4], w1v[4];
#pragma unroll
    for (int ii=0;ii<4;ii++){ w0v[ii] = w[(i+ii)*512+o]; w1v[ii]=w[(i+ii)*512+o+256]; }
#pragma unroll
    for (int r=0;r<16;r++){
      float4 xr = *(const float4*)&xl[r*E_+i];
      a0[r] += xr.x*w0v[0] + xr.y*w0v[1] + xr.z*w0v[2] + xr.w*w0v[3];
      a1[r] += xr.x*w1v[0] + xr.y*w1v[1] + xr.z*w1v[2] + xr.w*w1v[3];
    }
  }
  float b0 = bb[o], b1 = bb[o+256];
#pragma unroll
  for (int r=0;r<16;r++){
    xm[(size_t)(row0+r)*D_ + o] = (_Float16)(a0[r]+b0);
    z [(size_t)(row0+r)*D_ + o] = (_Float16)(a1[r]+b1);
  }
}

// ---------------- K3: conv+silu -> xc (fp16); ig/fg (f32); 8 rows/block ----------------
__global__ __launch_bounds__(256) void k_conv_qkv8(const _Float16* __restrict__ xm,
    const float* __restrict__ cw, const float* __restrict__ cb,
    const float* __restrict__ qw, const float* __restrict__ qb2,
    const float* __restrict__ kw, const float* __restrict__ kb2,
    const float* __restrict__ vw, const float* __restrict__ vb2,
    const float* __restrict__ igw, const float* __restrict__ igb,
    const float* __restrict__ fgw, const float* __restrict__ fgb,
    _Float16* __restrict__ xc, float* __restrict__ ig, float* __restrict__ fg){
  __shared__ float xr[12][D_];
  __shared__ float xcl[D_];
  __shared__ float part[4][8];
  int b = blockIdx.x/19, chunk = blockIdx.x - b*19;
  int s0 = chunk*8;
  int tid = threadIdx.x;
  for (int i=tid; i<12*D_; i+=256){
    int j = i>>8, c2 = i&255;
    int sg = s0-3+j;
    xr[j][c2] = (sg>=0 && sg<S_)? (float)xm[(size_t)(b*S_+sg)*D_ + c2] : 0.f;
  }
  __syncthreads();
  int c = tid;
  float4 wc  = *(const float4*)&cw[c*4];
  float cbv  = cb[c];
  int nb = c>>2, rr2 = c&3;
  float4 vw4 = *(const float4*)&vw[nb*16 + rr2*4];
  float4 qw4 = *(const float4*)&qw[nb*16 + rr2*4];
  float4 kw4 = *(const float4*)&kw[nb*16 + rr2*4];
  float vbv = vb2[c], qbv = qb2[c], kbv = kb2[c];
  float4 wiq = *(const float4*)&igw[c*4];
  float4 wik = *(const float4*)&igw[(256+c)*4];
  float4 wiv = *(const float4*)&igw[(512+c)*4];
  float4 wfq = *(const float4*)&fgw[c*4];
  float4 wfk = *(const float4*)&fgw[(256+c)*4];
  float4 wfv = *(const float4*)&fgw[(512+c)*4];
  int wave = c>>6, lane = c&63;
  for (int r=0; r<8; r++){
    int s = s0+r;
    if (s >= S_) break;
    size_t row = (size_t)b*S_ + s;
    float cv = cbv + wc.x*xr[r][c] + wc.y*xr[r+1][c] + wc.z*xr[r+2][c] + wc.w*xr[r+3][c];
    cv = siluf_(cv);
    xcl[c] = cv;
    xc[row*D_ + c] = (_Float16)cv;
    float4 xv4 = *(const float4*)&xr[r+3][nb*4];
    float vv = vbv + dot4(vw4, xv4);
    __syncthreads();
    float4 xc4 = *(const float4*)&xcl[nb*4];
    float qv = qbv + dot4(qw4, xc4);
    float kv = kbv + dot4(kw4, xc4);
    float p[8];
    p[0] = qv*wiq.x + kv*wik.x + vv*wiv.x;
    p[1] = qv*wiq.y + kv*wik.y + vv*wiv.y;
    p[2] = qv*wiq.z + kv*wik.z + vv*wiv.z;
    p[3] = qv*wiq.w + kv*wik.w + vv*wiv.w;
    p[4] = qv*wfq.x + kv*wfk.x + vv*wfv.x;
    p[5] = qv*wfq.y + kv*wfk.y + vv*wfv.y;
    p[6] = qv*wfq.z + kv*wfk.z + vv*wfv.z;
    p[7] = qv*wfq.w + kv*wfk.w + vv*wfv.w;
#pragma unroll
    for (int j=0;j<8;j++) p[j] = wsum(p[j]);
    if (lane==0){
#pragma unroll
      for (int j=0;j<8;j++) part[wave][j]=p[j];
    }
    __syncthreads();
    if (c < 8){
      float t4 = part[0][c]+part[1][c]+part[2][c]+part[3][c];
      int g = c&3;
      if (c<4) ig[(size_t)(b*4+g)*S_ + s] = t4 + igb[g];
      else     fg[(size_t)(b*4+g)*S_ + s] = t4 + fgb[g];
    }
    __syncthreads();
  }
}

// ---------------- K4: mLSTM via MFMA (flash-style) + fused LN/skip/gate epilogue ----------------
__global__ __launch_bounds__(256) void k_mlstm(_Float16* xcio,
    const _Float16* __restrict__ xm, const _Float16* __restrict__ z,
    const float* __restrict__ qw, const float* __restrict__ qb2,
    const float* __restrict__ kw, const float* __restrict__ kb2,
    const float* __restrict__ vw, const float* __restrict__ vb2,
    const float* __restrict__ ig, const float* __restrict__ fg,
    const float* __restrict__ nw, const float* __restrict__ skip){
  __shared__ __align__(16) _Float16 kt[160*72];    // k[t][d], row stride 72 halves
  __shared__ __align__(16) _Float16 vT[64*184];    // v[d][t], row stride 184 halves
  __shared__ __align__(16) _Float16 ct[4][16*40];  // per-wave coef tile 16 x 32 (stride 40)
  __shared__ float lfc[S_+1];
  __shared__ float igl[S_];
  __shared__ float mxl[S_];
  int bh = blockIdx.x; int b = bh>>2; int hh = bh&3;
  int tid = threadIdx.x; int wave = tid>>6, lane = tid&63;
  int quad = lane>>4, lm = lane&15;
  _Float16* xcg = xcio + (size_t)b*S_*D_ + hh*64;
  const _Float16* xmg = xm + (size_t)b*S_*D_ + hh*64;
  const _Float16* zg  = z  + (size_t)b*S_*D_ + hh*64;
  for (int i=tid;i<160*64;i+=256){
    int t=i>>6, d=i&63;
    float kvv=0.f, vvv=0.f;
    if (t<S_){
      int nb=d>>2, dd=d&3;
      h4_t xk = *(const h4_t*)&xcg[(size_t)t*D_+(nb<<2)];
      h4_t xv = *(const h4_t*)&xmg[(size_t)t*D_+(nb<<2)];
      float4 wk = *(const float4*)&kw[((hh*16+nb)<<4)+(dd<<2)];
      float4 wv = *(const float4*)&vw[((hh*16+nb)<<4)+(dd<<2)];
      kvv = kb2[hh*64+d]+hdot(wk,xk);
      vvv = vb2[hh*64+d]+hdot(wv,xv);
    }
    kt[t*72+d]=(_Float16)kvv;
    vT[d*184+t]=(_Float16)vvv;
  }
  if (tid<S_){ igl[tid]=ig[(size_t)bh*S_+tid]; mxl[tid]=logsigf_(fg[(size_t)bh*S_+tid]); }
  __syncthreads();
  if (tid==0){
    float run=0.f, rm=-3.0e38f;
    lfc[0]=0.f;
    for (int t=0;t<S_;t++){
      run += mxl[t];
      lfc[t+1]=run;
      float gv = igl[t]-run;
      rm = fmaxf(rm,gv);
      mxl[t] = run + rm;
    }
  }
  __syncthreads();
  float nwv[4], skv[4];
#pragma unroll
  for (int dt=0;dt<4;dt++){ nwv[dt]=nw[hh*64+dt*16+lm]; skv[dt]=skip[hh*64+dt*16+lm]; }
  _Float16* ctw = ct[wave];
  for (int qi=wave; qi<10; qi+=4){
    int s0=qi*16;
    int srow=s0+quad*4;
    int sq = s0+lm; if (sq>S_-1) sq=S_-1;
    const _Float16* xrow = &xcg[(size_t)sq*D_];
    h8_t qf0, qf1;
#pragma unroll
    for (int f=0; f<2; f++){
      int d0 = f*32 + quad*8;
      h4_t xa = *(const h4_t*)&xrow[d0];
      h4_t xb = *(const h4_t*)&xrow[d0+4];
      float4 xaf=h4f(xa), xbf=h4f(xb);
      int nb0 = (hh*16 + (d0>>2))<<4;
#pragma unroll
      for (int j=0;j<4;j++){
        float4 wr = *(const float4*)&qw[nb0 + j*4];
        float qv = qb2[hh*64+d0+j] + dot4(wr, xaf);
        if (f==0) qf0[j]=(_Float16)qv; else qf1[j]=(_Float16)qv;
      }
#pragma unroll
      for (int j=0;j<4;j++){
        float4 wr = *(const float4*)&qw[nb0 + 16 + j*4];
        float qv = qb2[hh*64+d0+4+j] + dot4(wr, xbf);
        if (f==0) qf0[4+j]=(_Float16)qv; else qf1[4+j]=(_Float16)qv;
      }
    }
    f4_t acc0={0,0,0,0},acc1={0,0,0,0},acc2={0,0,0,0},acc3={0,0,0,0};
    float rsum[4]={0.f,0.f,0.f,0.f};
    float lfs[4], mxs[4]; bool sv[4];
#pragma unroll
    for (int r=0;r<4;r++){
      int s=srow+r; sv[r]=(s<S_);
      int sc = sv[r]? s : S_-1;
      lfs[r]=lfc[sc+1]; mxs[r]=mxl[sc];
    }
    int npair=(qi+2)>>1;
    for (int tp=0; tp<npair; tp++){
#pragma unroll
      for (int half=0; half<2; half++){
        int ti=2*tp+half;
        f4_t aq={0,0,0,0};
        if (ti<=qi){
          int t0=ti*16;
          h8_t kb0=*(const h8_t*)&kt[(t0+lm)*72+quad*8];
          h8_t kb1=*(const h8_t*)&kt[(t0+lm)*72+32+quad*8];
          aq=__builtin_amdgcn_mfma_f32_16x16x32_f16(qf0,kb0,aq,0,0,0);
          aq=__builtin_amdgcn_mfma_f32_16x16x32_f16(qf1,kb1,aq,0,0,0);
        }
        int t=ti*16+lm;
        bool tv = (t<S_);
        float lfT = tv? lfc[t+1]:0.f;
        float igT = tv? igl[t]:0.f;
#pragma unroll
        for (int r=0;r<4;r++){
          float coef=0.f;
          if (tv && sv[r] && t<=srow+r){
            coef = aq[r]*0.125f*__expf(lfs[r]-lfT+igT-mxs[r]);
          }
          rsum[r]+=coef;
          ctw[(quad*4+r)*40 + half*16 + lm] = (_Float16)coef;
        }
      }
      asm volatile("s_waitcnt lgkmcnt(0)" ::: "memory");
      h8_t af=*(const h8_t*)&ctw[lm*40+quad*8];
      int tb=tp*32+quad*8;
      h8_t bv0=*(const h8_t*)&vT[(0*16+lm)*184+tb];
      h8_t bv1=*(const h8_t*)&vT[(1*16+lm)*184+tb];
      h8_t bv2=*(const h8_t*)&vT[(2*16+lm)*184+tb];
      h8_t bv3=*(const h8_t*)&vT[(3*16+lm)*184+tb];
      acc0=__builtin_amdgcn_mfma_f32_16x16x32_f16(af,bv0,acc0,0,0,0);
      acc1=__builtin_amdgcn_mfma_f32_16x16x32_f16(af,bv1,acc1,0,0,0);
      acc2=__builtin_amdgcn_mfma_f32_16x16x32_f16(af,bv2,acc2,0,0,0);
      acc3=__builtin_amdgcn_mfma_f32_16x16x32_f16(af,bv3,acc3,0,0,0);
    }
#pragma unroll
    for (int r=0;r<4;r++){
      float v_=rsum[r];
      v_+=__shfl_xor(v_,1,64); v_+=__shfl_xor(v_,2,64);
      v_+=__shfl_xor(v_,4,64); v_+=__shfl_xor(v_,8,64);
      rsum[r]=v_;
    }
    float nrm[4];
#pragma unroll
    for (int r=0;r<4;r++) nrm[r]=fmaxf(fabsf(rsum[r]), __expf(-mxs[r]))+1e-6f;
#pragma unroll
    for (int r=0;r<4;r++){
      if (!sv[r]) continue;
      int s=srow+r;
      float o0=acc0[r]/nrm[r], o1=acc1[r]/nrm[r], o2=acc2[r]/nrm[r], o3=acc3[r]/nrm[r];
      float ss=o0+o1+o2+o3;
      ss+=__shfl_xor(ss,1,64); ss+=__shfl_xor(ss,2,64); ss+=__shfl_xor(ss,4,64); ss+=__shfl_xor(ss,8,64);
      float mu=ss*(1.f/64.f);
      float d0=o0-mu,d1=o1-mu,d2=o2-mu,d3=o3-mu;
      float vv=d0*d0+d1*d1+d2*d2+d3*d3;
      vv+=__shfl_xor(vv,1,64); vv+=__shfl_xor(vv,2,64); vv+=__shfl_xor(vv,4,64); vv+=__shfl_xor(vv,8,64);
      float rs=rsqrtf(vv*(1.f/64.f)+1e-5f);
      size_t rowoff=(size_t)s*D_;
      float dd4[4]={d0,d1,d2,d3};
#pragma unroll
      for (int dt=0;dt<4;dt++){
        float hn = dd4[dt]*rs*nwv[dt];
        float xcv=(float)xcg[rowoff+dt*16+lm];
        float zv =(float)zg [rowoff+dt*16+lm];
        xcg[rowoff+dt*16+lm]=(_Float16)((hn+skv[dt]*xcv)*siluf_(zv));
      }
    }
  }
}

// ---------------- K5: h += hs @ m_down_w + b; 16 rows/block ----------------
// per-row math bit-identical to the 8-row version
__global__ __launch_bounds__(256) void k_down(const _Float16* __restrict__ hs, const float* __restrict__ w,
    const float* __restrict__ bb, float* __restrict__ h){
  __shared__ float hl[16*D_];
  int row0 = blockIdx.x*16; int tid = threadIdx.x;
  for (int i=tid;i<16*D_;i+=256) hl[i] = (float)hs[(size_t)row0*D_ + i];
  __syncthreads();
  int o = tid&127, rh = tid>>7;
  float acc[8]={0.f,0.f,0.f,0.f,0.f,0.f,0.f,0.f};
  for (int i=0;i<D_;i+=4){
    float wv[4];
#pragma unroll
    for (int ii=0;ii<4;ii++) wv[ii] = w[(i+ii)*E_ + o];
#pragma unroll
    for (int r=0;r<8;r++){
      float4 xv = *(const float4*)&hl[(rh+2*r)*D_ + i];
      acc[r] += xv.x*wv[0]+xv.y*wv[1]+xv.z*wv[2]+xv.w*wv[3];
    }
  }
  float bv = bb[o];
#pragma unroll
  for (int r=0;r<8;r++){
    size_t idx = (size_t)(row0+rh+2*r)*E_ + o;
    h[idx] += acc[r] + bv;
  }
}

// ---------------- K6: fused LN(h) + causal conv + silu -> xcs (fp16) ----------------
__global__ __launch_bounds__(256) void k_lnconv(const float* __restrict__ h, const float* __restrict__ lnw,
    const float* __restrict__ cw, const float* __restrict__ cb, _Float16* __restrict__ xcs){
  __shared__ float xn[19][E_];
  int b = blockIdx.x/10, chunk = blockIdx.x - b*10;
  int s0 = chunk*16;
  int tid=threadIdx.x, wave=tid>>6, lane=tid&63;
  for (int ii=wave; ii<19; ii+=4){
    int sg = s0-3+ii;
    if (sg>=0 && sg<S_){
      size_t off = (size_t)(b*S_+sg)*E_;
      float x0=h[off+lane], x1=h[off+lane+64];
      float mu=wsum(x0+x1)*(1.f/E_);
      float d0=x0-mu,d1=x1-mu;
      float var=wsum(d0*d0+d1*d1)*(1.f/E_);
      float rs=rsqrtf(var+1e-5f);
      xn[ii][lane]=d0*rs*lnw[lane];
      xn[ii][lane+64]=d1*rs*lnw[lane+64];
    } else { xn[ii][lane]=0.f; xn[ii][lane+64]=0.f; }
  }
  __syncthreads();
  int ch=tid&127, rh=tid>>7;
  float4 w4 = *(const float4*)&cw[ch*4];
  float bv = cb[ch];
  for (int r=rh; r<16; r+=2){
    int s=s0+r;
    if (s<S_){
      float acc = bv + w4.x*xn[r][ch] + w4.y*xn[r+1][ch] + w4.z*xn[r+2][ch] + w4.w*xn[r+3][ch];
      xcs[(size_t)(b*S_+s)*E_+ch] = (_Float16)siluf_(acc);
    }
  }
}

// ---------------- K7: sLSTM gates, 8 rows/block (bit-identical per-row math to r3 k_gates) ----------------
__global__ __launch_bounds__(128) void k_gates8(const _Float16* __restrict__ xcs, const float* __restrict__ h,
    const float* __restrict__ lnw, const float* __restrict__ gw,
    _Float16* __restrict__ gi, _Float16* __restrict__ gf,
    _Float16* __restrict__ gz, _Float16* __restrict__ go){
  __shared__ float xcl[E_], xnl[E_], red2[2];
  int row0 = blockIdx.x*8;
  int t = threadIdx.x;
  int hh = t>>5, o = t&31;
  const float* w0 = gw + (((0*4+hh)*32+o)<<5);
  const float* w1 = gw + (((1*4+hh)*32+o)<<5);
  const float* w2 = gw + (((2*4+hh)*32+o)<<5);
  const float* w3 = gw + (((3*4+hh)*32+o)<<5);
  float4 w0v[8], w1v[8], w2v[8], w3v[8];
#pragma unroll
  for (int d=0;d<8;d++){
    w0v[d]=*(const float4*)&w0[d*4]; w1v[d]=*(const float4*)&w1[d*4];
    w2v[d]=*(const float4*)&w2[d*4]; w3v[d]=*(const float4*)&w3[d*4];
  }
  float lnwv = lnw[t];
  for (int rr=0; rr<8; rr++){
    int row = row0+rr; int b = row/S_; int s = row - b*S_;
    float hv = h[(size_t)row*E_+t];
    float mu = bsum128(hv, red2)*(1.f/E_);
    float dd = hv-mu;
    float var = bsum128(dd*dd, red2)*(1.f/E_);
    xnl[t] = dd*rsqrtf(var+1e-5f)*lnwv;
    xcl[t] = (float)xcs[(size_t)row*E_+t];
    __syncthreads();
    float a0=0.f,a1=0.f,a2=0.f,a3=0.f;
    const float* xch = &xcl[hh*32]; const float* xnh = &xnl[hh*32];
#pragma unroll
    for (int d=0; d<8; d++){
      float4 xc4 = *(const float4*)&xch[d*4];
      float4 xn4 = *(const float4*)&xnh[d*4];
      a0 += dot4(w0v[d], xc4);
      a1 += dot4(w1v[d], xc4);
      a2 += dot4(w2v[d], xn4);
      a3 += dot4(w3v[d], xn4);
    }
    size_t oidx = ((size_t)s*B_ + b)*E_ + t;
    gi[oidx]=(_Float16)a0; gf[oidx]=(_Float16)a1; gz[oidx]=(_Float16)a2; go[oidx]=(_Float16)a3;
    __syncthreads();   // protect xnl/xcl before next row overwrites
  }
}

// ---------------- K8: sLSTM recurrent scan — LDS broadcast of y (values & FMA order identical to r11) ----------------
__global__ __launch_bounds__(64) void k_scan(const _Float16* __restrict__ gi, const _Float16* __restrict__ gf,
    const _Float16* __restrict__ gz, const _Float16* __restrict__ go,
    const float* __restrict__ sr, const float* __restrict__ sb, float* __restrict__ yl){
  __shared__ float ylds[32];
  int bh = blockIdx.x; int b = bh>>2; int hh = bh&3;
  int lane = threadIdx.x; int kk = lane&31; int half = lane>>5;
  int gA = half*2, gB = half*2+1;
  const float* srA = sr + (size_t)((gA*4+hh)*32)*32 + kk;
  const float* srB = sr + (size_t)((gB*4+hh)*32)*32 + kk;
  h4_t wAh[8], wBh[8];
#pragma unroll
  for (int d8=0; d8<8; d8++){
    h4_t a, bb_;
#pragma unroll
    for (int j=0;j<4;j++){
      a[j]   = (_Float16)srA[(d8*4+j)*32];
      bb_[j] = (_Float16)srB[(d8*4+j)*32];
    }
    wAh[d8]=a; wBh[d8]=bb_;
  }
  int c = hh*32 + kk;
  float sb0 = sb[c], sb1 = sb[128+c], sb2 = sb[256+c], sb3 = sb[384+c];
  float y=0.f,cst=0.f,nst=0.f,mst=-1e30f;
  size_t base0 = (size_t)b*E_ + c;
  float gc0 = (float)gi[base0], gc1 = (float)gf[base0], gc2 = (float)gz[base0], gc3 = (float)go[base0];
  for (int s=0;s<S_;s++){
    int sn = (s+1 < S_)? s+1 : s;
    size_t nidx = ((size_t)sn*B_ + b)*E_ + c;
    float n0 = (float)gi[nidx], n1 = (float)gf[nidx], n2 = (float)gz[nidx], n3 = (float)go[nidx];
    // broadcast y via LDS: paired lanes (l, l+32) hold identical y, write same value to same slot
    ylds[kk] = y;
    asm volatile("s_waitcnt lgkmcnt(0)" ::: "memory");
    float ryA=0.f, ryB=0.f;
#pragma unroll
    for (int d8=0; d8<8; d8++){
      float4 y4 = *(const float4*)&ylds[d8*4];
      ryA += y4.x*(float)wAh[d8][0];
      ryB += y4.x*(float)wBh[d8][0];
      ryA += y4.y*(float)wAh[d8][1];
      ryB += y4.y*(float)wBh[d8][1];
      ryA += y4.z*(float)wAh[d8][2];
      ryB += y4.z*(float)wBh[d8][2];
      ryA += y4.w*(float)wAh[d8][3];
      ryB += y4.w*(float)wBh[d8][3];
    }
    asm volatile("s_waitcnt lgkmcnt(0)" ::: "memory");  // drain reads before next step's write
    float oA = __shfl_xor(ryA, 32, 64);
    float oB = __shfl_xor(ryB, 32, 64);
    float ry0 = half? oA  : ryA;
    float ry1 = half? oB  : ryB;
    float ry2 = half? ryA : oA;
    float ry3 = half? ryB : oB;
    float ir = gc0 + ry0 + sb0;
    float fr = gc1 + ry1 + sb1;
    float zr = gc2 + ry2 + sb2;
    float orr= gc3 + ry3 + sb3;
    float lfm = mst + logsigf_(fr);
    float mn = fmaxf(ir, lfm);
    float igt = expf(ir - mn);
    float fgt = expf(lfm - mn);
    cst = fgt*cst + igt*tanhf(zr);
    nst = fgt*nst + igt;
    mst = mn;
    y = sigmoidf_(orr)*cst/nst;
    gc0=n0; gc1=n1; gc2=n2; gc3=n3;
  }
  if (half==0) yl[(size_t)b*E_ + c] = y;
}

// ---------------- K9: last-position head (mhln + FFN + post-LN + fc) ----------------
__global__ __launch_bounds__(128) void k_head(const float* __restrict__ h, const float* __restrict__ yl,
   const float* __restrict__ snw, const float* __restrict__ lnffw,
   const float* __restrict__ upw, const float* __restrict__ upb,
   const float* __restrict__ dww, const float* __restrict__ dwb,
   const float* __restrict__ postw, const float* __restrict__ fcw, const float* __restrict__ fcb,
   float* __restrict__ out){
  __shared__ float ylsh[E_], xnf[E_], up[2*FF_], gg[FF_], red2[2];
  int b = blockIdx.x; int t = threadIdx.x;
  float yv = yl[(size_t)b*E_+t];
  ylsh[t] = yv;
  __syncthreads();
  int base = (t>>5)<<5;
  float mu=0.f;
  for (int d=0;d<32;d++) mu += ylsh[base+d];
  mu *= (1.f/32.f);
  float var=0.f;
  for (int d=0;d<32;d++){ float dd = ylsh[base+d]-mu; var += dd*dd; }
  var *= (1.f/32.f);
  float hn = (yv-mu)*rsqrtf(var+1e-5f)*snw[t];
  float h1 = h[((size_t)b*S_ + (S_-1))*E_ + t] + hn;
  float mu1 = bsum128(h1, red2)*(1.f/E_);
  float d1 = h1-mu1;
  float var1 = bsum128(d1*d1, red2)*(1.f/E_);
  xnf[t] = d1*rsqrtf(var1+1e-5f)*lnffw[t];
  __syncthreads();
  float u0=upb[t], u1=upb[t+128], u2=upb[t+256];
  for (int i=0;i<E_;i++){
    float x = xnf[i];
    u0 += x*upw[i*384+t];
    u1 += x*upw[i*384+t+128];
    u2 += x*upw[i*384+t+256];
  }
  up[t]=u0; up[t+128]=u1; up[t+256]=u2;
  __syncthreads();
  for (int j=t;j<FF_;j+=128){
    float gp = up[j];
    gg[j] = 0.5f*gp*(1.f+erff(gp*0.70710678118f))*up[FF_+j];
  }
  __syncthreads();
  float acc = dwb[t];
  for (int j=0;j<FF_;j++) acc += gg[j]*dww[j*E_+t];
  float h2 = h1 + acc;
  float mu2 = bsum128(h2, red2)*(1.f/E_);
  float d2 = h2-mu2;
  float var2 = bsum128(d2*d2, red2)*(1.f/E_);
  float hp = d2*rsqrtf(var2+1e-5f)*postw[t];
  float pr = bsum128(hp*fcw[t], red2);
  if (t==0) out[b] = pr + fcb[0];
}

extern "C" void kernel_launch(void* const* d_in, const int* in_sizes, int n_in,
                              void* d_out, int out_size, void* d_ws, size_t ws_size,
                              hipStream_t stream){
  const float* x        = (const float*)d_in[0];
  const float* w_in     = (const float*)d_in[1];
  const float* b_in     = (const float*)d_in[2];
  const float* ln0_w    = (const float*)d_in[3];
  const float* m_up_w   = (const float*)d_in[4];
  const float* m_up_b   = (const float*)d_in[5];
  const float* m_conv_w = (const float*)d_in[6];
  const float* m_conv_b = (const float*)d_in[7];
  const float* m_q_w    = (const float*)d_in[8];
  const float* m_q_b    = (const float*)d_in[9];
  const float* m_k_w    = (const float*)d_in[10];
  const float* m_k_b    = (const float*)d_in[11];
  const float* m_v_w    = (const float*)d_in[12];
  const float* m_v_b    = (const float*)d_in[13];
  const float* m_ig_w   = (const float*)d_in[14];
  const float* m_ig_b   = (const float*)d_in[15];
  const float* m_fg_w   = (const float*)d_in[16];
  const float* m_fg_b   = (const float*)d_in[17];
  const float* m_norm_w = (const float*)d_in[18];
  const float* m_skip   = (const float*)d_in[19];
  const float* m_down_w = (const float*)d_in[20];
  const float* m_down_b = (const float*)d_in[21];
  const float* ln1_w    = (const float*)d_in[22];
  const float* s_conv_w = (const float*)d_in[23];
  const float* s_conv_b = (const float*)d_in[24];
  const float* s_gate_w = (const float*)d_in[25];
  const float* s_r      = (const float*)d_in[26];
  const float* s_b      = (const float*)d_in[27];
  const float* s_norm_w = (const float*)d_in[28];
  const float* ln_ff_w  = (const float*)d_in[29];
  const float* ff_up_w  = (const float*)d_in[30];
  const float* ff_up_b  = (const float*)d_in[31];
  const float* ff_down_w= (const float*)d_in[32];
  const float* ff_down_b= (const float*)d_in[33];
  const float* post_w   = (const float*)d_in[34];
  const float* fc_w     = (const float*)d_in[35];
  const float* fc_b     = (const float*)d_in[36];
  float* out = (float*)d_out;
  float* wsf = (float*)d_ws;

  // workspace layout (units = f32 slots): total 40,001,536 f32 = 152.6 MiB (r3-identical)
  float*     h  = wsf;                              // (B,S,E) f32
  _Float16*  A  = (_Float16*)(wsf + 9830400);       // x_m -> xcs | gz
  _Float16*  Bz = (_Float16*)(wsf + 19660800);      // z   -> gi | gf
  _Float16*  C  = (_Float16*)(wsf + 29491200);      // xc/hs -> go
  float*     ig = wsf + 39321600;
  float*     fg = wsf + 39628800;
  float*     yl = wsf + 39936000;

  k_inproj<<<ROWS_/16, 256, 0, stream>>>(x, w_in, b_in, h);
  k_ln_up<<<ROWS_/16, 256, 0, stream>>>(h, ln0_w, m_up_w, m_up_b, A, Bz);
  k_conv_qkv8<<<B_*19, 256, 0, stream>>>(A, m_conv_w, m_conv_b, m_q_w, m_q_b, m_k_w, m_k_b,
       m_v_w, m_v_b, m_ig_w, m_ig_b, m_fg_w, m_fg_b, C, ig, fg);
  k_mlstm<<<B_*4, 256, 0, stream>>>(C, A, Bz, m_q_w, m_q_b, m_k_w, m_k_b, m_v_w, m_v_b,
       ig, fg, m_norm_w, m_skip);
  k_down<<<ROWS_/16, 256, 0, stream>>>(C, m_down_w, m_down_b, h);
  _Float16* xcs = A;
  _Float16* gz  = A + 9830400;
  _Float16* gi  = Bz;
  _Float16* gf  = Bz + 9830400;
  _Float16* go  = C;
  k_lnconv<<<B_*10, 256, 0, stream>>>(h, ln1_w, s_conv_w, s_conv_b, xcs);
  k_gates8<<<ROWS_/8, 128, 0, stream>>>(xcs, h, ln1_w, s_gate_w, gi, gf, gz, go);
  k_scan<<<B_*4, 64, 0, stream>>>(gi, gf, gz, go, s_r, s_b, yl);
  k_head<<<B_, 128, 0, stream>>>(h, yl, s_norm_w, ln_ff_w, ff_up_w, ff_up_b,
       ff_down_w, ff_down_b, post_w, fc_w, fc_b, out);
}